// Round 6
// baseline (564.408 us; speedup 1.0000x reference)
//
#include <hip/hip_runtime.h>
#include <hip/hip_bf16.h>
#include <math.h>

#define N_NODES 50000
#define N_EDGES 1600000
#define NUM_GRAPHS 512
#define HIDDEN 128
#define NUM_CLASSES 10
#define STEPS 3

#define NB_SHIFT 6                      // 64 nodes per bucket
#define NODES_PER_B (1 << NB_SHIFT)
#define NBUK ((N_NODES + NODES_PER_B - 1) / NODES_PER_B)   // 782
#define EPB 8192                        // edges per block in the sort
#define NBLK ((N_EDGES + EPB - 1) / EPB)                   // 196
#define MAXR 144                        // attn LDS row cap (max graph ~132)
#define NCH 7                           // src chunks of 8192 nodes (2MB bf16 each)

__device__ inline float bf2f(unsigned short h) {
    union { unsigned int u; float f; } v; v.u = ((unsigned int)h) << 16; return v.f;
}
__device__ inline unsigned short f2bf(float f) {
    union { float f; unsigned int u; } v; v.f = f;
    unsigned int r = (v.u + 0x7FFFu + ((v.u >> 16) & 1u)) >> 16;
    return (unsigned short)r;
}

// ---------------- utility kernels ----------------

// Detect int64 vs int32 storage of index inputs.
__global__ void k_detect(const int* p, int* flag, int npairs) {
    int i = blockIdx.x * blockDim.x + threadIdx.x;
    if (i < npairs) {
        int v = p[2 * i + 1];
        if (v != 0) atomicOr(flag, 1);
    }
}

// batch is sorted: graph start offsets by boundary detection (reads raw dtype).
__global__ void k_goff(const void* batr, const int* flag, int* goff, int n, int ng) {
    int i = blockIdx.x * blockDim.x + threadIdx.x;
    if (i >= n) return;
    bool is32 = (*flag != 0);
    int b = is32 ? ((const int*)batr)[i] : (int)((const long long*)batr)[i];
    int prev = (i == 0) ? -1
             : (is32 ? ((const int*)batr)[i - 1] : (int)((const long long*)batr)[i - 1]);
    for (int g = prev + 1; g <= b; g++) goff[g] = i;
    if (i == n - 1) {
        for (int g = b + 1; g <= ng; g++) goff[g] = n;
    }
}

// Sort pass 1: pack edges + per-block LDS bucket histogram (no global atomics).
__global__ __launch_bounds__(256) void k_pack(const void* eidx, const int* flag,
                                              unsigned int* __restrict__ pdata,
                                              int* __restrict__ histg) {
    __shared__ int lh[NBUK];
    int b = blockIdx.x, t = threadIdx.x;
    for (int i = t; i < NBUK; i += 256) lh[i] = 0;
    __syncthreads();
    int base = b * EPB;
    int end = base + EPB; if (end > N_EDGES) end = N_EDGES;
    bool is32 = (*flag != 0);
    for (int i = base + t; i < end; i += 256) {
        int src, dst;
        if (is32) {
            const int* p = (const int*)eidx;
            src = p[i]; dst = p[N_EDGES + i];
        } else {
            const long long* p = (const long long*)eidx;
            src = (int)p[i]; dst = (int)p[N_EDGES + i];
        }
        pdata[i] = ((unsigned)src << 16) | (unsigned)dst;
        atomicAdd(&lh[dst >> NB_SHIFT], 1);
    }
    __syncthreads();
    for (int i = t; i < NBUK; i += 256) histg[(size_t)b * NBUK + i] = lh[i];
}

// Sort pass 2: per bucket, exclusive scan of counts across blocks + bucket total.
__global__ __launch_bounds__(256) void k_colscan(int* __restrict__ histg,
                                                 int* __restrict__ btot) {
    __shared__ int wsum[4];
    int k = blockIdx.x, t = threadIdx.x;
    int wid = t >> 6, lane = t & 63;
    int v = (t < NBLK) ? histg[(size_t)t * NBUK + k] : 0;
    int x = v;
#pragma unroll
    for (int o = 1; o < 64; o <<= 1) {
        int y = __shfl_up(x, o, 64);
        if (lane >= o) x += y;
    }
    if (lane == 63) wsum[wid] = x;
    __syncthreads();
    int add = 0;
    for (int w = 0; w < wid; w++) add += wsum[w];
    if (t < NBLK) histg[(size_t)t * NBUK + k] = add + x - v;
    if (t == NBLK - 1) btot[k] = add + x;
}

// Single-block exclusive scan via shfl wave-scans (generic n; used for 782 buckets).
__global__ __launch_bounds__(1024) void k_scan(const int* cnt, int* offs, int n) {
    __shared__ int wsum[16];
    __shared__ int carry_sh;
    int t = threadIdx.x, wid = t >> 6, lane = t & 63;
    if (t == 0) { carry_sh = 0; offs[0] = 0; }
    __syncthreads();
    for (int base = 0; base < n; base += 1024) {
        int i = base + t;
        int v = (i < n) ? cnt[i] : 0;
        int x = v;
#pragma unroll
        for (int o = 1; o < 64; o <<= 1) {
            int y = __shfl_up(x, o, 64);
            if (lane >= o) x += y;
        }
        if (lane == 63) wsum[wid] = x;
        __syncthreads();
        if (wid == 0 && lane < 16) {
            int w = wsum[lane];
#pragma unroll
            for (int o = 1; o < 16; o <<= 1) {
                int y = __shfl_up(w, o, 16);
                if (lane >= o) w += y;
            }
            wsum[lane] = w;
        }
        __syncthreads();
        int add = carry_sh + (wid > 0 ? wsum[wid - 1] : 0);
        if (i < n) offs[i + 1] = add + x;
        __syncthreads();
        if (t == 0) carry_sh += wsum[15];
        __syncthreads();
    }
}

// Sort pass 3: place packed edges into bucket-contiguous segments.
__global__ __launch_bounds__(256) void k_place(const unsigned int* __restrict__ pdata,
                                               const int* __restrict__ histg,
                                               const int* __restrict__ bbase,
                                               unsigned int* __restrict__ sdata) {
    __shared__ int lh[NBUK];
    __shared__ int lpre[NBUK];
    int b = blockIdx.x, t = threadIdx.x;
    for (int i = t; i < NBUK; i += 256) {
        lh[i] = 0;
        lpre[i] = bbase[i] + histg[(size_t)b * NBUK + i];
    }
    __syncthreads();
    int base = b * EPB;
    int end = base + EPB; if (end > N_EDGES) end = N_EDGES;
    for (int i = base + t; i < end; i += 256) {
        unsigned p = pdata[i];
        int k = (p & 0xFFFFu) >> NB_SHIFT;
        int pos = atomicAdd(&lh[k], 1);
        sdata[lpre[k] + pos] = p;
    }
}

// Fused CSR build per bucket: per-(node,chunk) counts, offs (bbase + wave scan),
// dinv, packed chunk counts, and chunk-ordered csr placement.
__global__ __launch_bounds__(256) void k_build(const unsigned int* __restrict__ sdata,
                                               const int* __restrict__ bbase,
                                               const int* __restrict__ btot,
                                               float* __restrict__ dinv,
                                               int* __restrict__ offs,
                                               unsigned int* __restrict__ ccnt,
                                               int* __restrict__ csr) {
    __shared__ int lc[NODES_PER_B][8];   // counts, then absolute cursors
    int b = blockIdx.x, t = threadIdx.x;
    for (int i = t; i < NODES_PER_B * 8; i += 256) ((int*)lc)[i] = 0;
    __syncthreads();
    int s0 = bbase[b], n = btot[b];
    const unsigned int* sd = sdata + s0;
    for (int e = t; e < n; e += 256) {
        unsigned p = sd[e];
        atomicAdd(&lc[p & (NODES_PER_B - 1)][(p >> 16) >> 13], 1);
    }
    __syncthreads();
    if (t < NODES_PER_B) {
        int cnts[NCH];
        int deg = 0;
#pragma unroll
        for (int c = 0; c < NCH; c++) { cnts[c] = lc[t][c]; deg += cnts[c]; }
        // exclusive scan of deg over the 64 slots (wave 0 only)
        int x = deg;
#pragma unroll
        for (int o = 1; o < 64; o <<= 1) {
            int y = __shfl_up(x, o, 64);
            if (t >= o) x += y;
        }
        int nodestart = s0 + x - deg;
        int node = b * NODES_PER_B + t;
        if (node < N_NODES) {
            offs[node] = nodestart;
            dinv[node] = rsqrtf((float)(deg + 1));
            unsigned w0 = (unsigned)cnts[0] | ((unsigned)cnts[1] << 8) |
                          ((unsigned)cnts[2] << 16) | ((unsigned)cnts[3] << 24);
            unsigned w1 = (unsigned)cnts[4] | ((unsigned)cnts[5] << 8) |
                          ((unsigned)cnts[6] << 16);
            ccnt[node * 2] = w0; ccnt[node * 2 + 1] = w1;
        }
        int run = nodestart;
#pragma unroll
        for (int c = 0; c < NCH; c++) { lc[t][c] = run; run += cnts[c]; }
    }
    if (b == 0 && t == 255) offs[N_NODES] = N_EDGES;
    __syncthreads();
    for (int e = t; e < n; e += 256) {
        unsigned p = sd[e];
        int src = (int)(p >> 16);
        int pos = atomicAdd(&lc[p & (NODES_PER_B - 1)][src >> 13], 1);
        csr[pos] = src;
    }
}

// ---------------- GEMM: H[n][j] = sum_k X[n][k] * W[k][j], K=N=128 ----------------
__global__ __launch_bounds__(256) void k_gemm64(const float* __restrict__ X,
                                                const float* __restrict__ W,
                                                float* __restrict__ H,
                                                unsigned short* __restrict__ Hb,
                                                int nrows) {
    __shared__ float xs[64][128];
    int t = threadIdx.x;
    int a = t >> 5;
    int j4 = t & 31;
    int row0 = blockIdx.x * 64;
    for (int i = t; i < 64 * 32; i += 256) {
        int rr = i >> 5;
        int c4 = i & 31;
        int r = row0 + rr; if (r >= nrows) r = nrows - 1;
        ((float4*)xs[rr])[c4] = ((const float4*)X)[(size_t)r * 32 + c4];
    }
    __syncthreads();
    float4 acc[8];
#pragma unroll
    for (int i = 0; i < 8; i++) acc[i] = {0.f, 0.f, 0.f, 0.f};
    const float4* wp = (const float4*)W;
#pragma unroll 4
    for (int k = 0; k < 128; k++) {
        float4 w4 = wp[k * 32 + j4];
#pragma unroll
        for (int i = 0; i < 8; i++) {
            float xv = xs[8 * a + i][k];
            acc[i].x = fmaf(xv, w4.x, acc[i].x);
            acc[i].y = fmaf(xv, w4.y, acc[i].y);
            acc[i].z = fmaf(xv, w4.z, acc[i].z);
            acc[i].w = fmaf(xv, w4.w, acc[i].w);
        }
    }
#pragma unroll
    for (int i = 0; i < 8; i++) {
        int r = row0 + 8 * a + i;
        if (r < nrows) {
            ((float4*)H)[(size_t)r * 32 + j4] = acc[i];
            ushort4 b4;
            b4.x = f2bf(acc[i].x); b4.y = f2bf(acc[i].y);
            b4.z = f2bf(acc[i].z); b4.w = f2bf(acc[i].w);
            ((ushort4*)Hb)[(size_t)r * 32 + j4] = b4;
        }
    }
}

// ---------------- GCN aggregate: chunk-major lockstep gather ----------------
// Wave owns 8 nodes (half-wave: 4, named accumulators). All waves resident;
// chunks (2MB bf16 src windows) swept in lockstep -> L2-hot gather.
__global__ __launch_bounds__(256) void k_agg(const float* __restrict__ H,
                                             const unsigned short* __restrict__ Hb,
                                             const float* __restrict__ dinv,
                                             const int* __restrict__ offs,
                                             const unsigned int* __restrict__ ccnt,
                                             const int* __restrict__ csr,
                                             const float* __restrict__ bias,
                                             float* __restrict__ out) {
    int wid = (blockIdx.x * blockDim.x + threadIdx.x) >> 6;
    int lane = threadIdx.x & 63;
    int half = lane >> 5;
    int l = lane & 31;
    int nb = wid * 8 + half * 4;
    const float4* bp = (const float4*)bias;
    float4 bb = bp[l];
    const ushort4* hbp = (const ushort4*)Hb;

#define NODE_INIT(k) \
    int n##k = nb + k; int v##k = (n##k < N_NODES); int vn##k = v##k ? n##k : 0; \
    float di##k = dinv[vn##k]; \
    int jb##k = offs[vn##k]; \
    unsigned w0_##k = v##k ? ccnt[vn##k * 2] : 0u; \
    unsigned w1_##k = v##k ? ccnt[vn##k * 2 + 1] : 0u; \
    float4 hn##k = ((const float4*)H)[(size_t)vn##k * 32 + l]; \
    float4 acc##k = {di##k * hn##k.x, di##k * hn##k.y, di##k * hn##k.z, di##k * hn##k.w};

    NODE_INIT(0) NODE_INIT(1) NODE_INIT(2) NODE_INIT(3)

#define GATHER(accv) { \
    int s = csr[j]; \
    float ds = dinv[s]; \
    ushort4 hv = hbp[(size_t)s * 32 + l]; \
    accv.x = fmaf(ds, bf2f(hv.x), accv.x); accv.y = fmaf(ds, bf2f(hv.y), accv.y); \
    accv.z = fmaf(ds, bf2f(hv.z), accv.z); accv.w = fmaf(ds, bf2f(hv.w), accv.w); }

#define GATHER4(accv) { \
    int s0 = csr[j], s1 = csr[j + 1], s2 = csr[j + 2], s3 = csr[j + 3]; \
    float e0 = dinv[s0], e1 = dinv[s1], e2 = dinv[s2], e3 = dinv[s3]; \
    ushort4 a0 = hbp[(size_t)s0 * 32 + l]; \
    ushort4 a1 = hbp[(size_t)s1 * 32 + l]; \
    ushort4 a2 = hbp[(size_t)s2 * 32 + l]; \
    ushort4 a3 = hbp[(size_t)s3 * 32 + l]; \
    accv.x = fmaf(e0, bf2f(a0.x), accv.x); accv.y = fmaf(e0, bf2f(a0.y), accv.y); \
    accv.z = fmaf(e0, bf2f(a0.z), accv.z); accv.w = fmaf(e0, bf2f(a0.w), accv.w); \
    accv.x = fmaf(e1, bf2f(a1.x), accv.x); accv.y = fmaf(e1, bf2f(a1.y), accv.y); \
    accv.z = fmaf(e1, bf2f(a1.z), accv.z); accv.w = fmaf(e1, bf2f(a1.w), accv.w); \
    accv.x = fmaf(e2, bf2f(a2.x), accv.x); accv.y = fmaf(e2, bf2f(a2.y), accv.y); \
    accv.z = fmaf(e2, bf2f(a2.z), accv.z); accv.w = fmaf(e2, bf2f(a2.w), accv.w); \
    accv.x = fmaf(e3, bf2f(a3.x), accv.x); accv.y = fmaf(e3, bf2f(a3.y), accv.y); \
    accv.z = fmaf(e3, bf2f(a3.z), accv.z); accv.w = fmaf(e3, bf2f(a3.w), accv.w); }

    for (int c = 0; c < NCH; c++) {
        int sh = (c < 4) ? c * 8 : (c - 4) * 8;
#define PROC(k) { \
        unsigned wsel = (c < 4) ? w0_##k : w1_##k; \
        int len = (int)((wsel >> sh) & 255u); \
        int je = jb##k + len; \
        int j = jb##k; \
        for (; j + 3 < je; j += 4) GATHER4(acc##k) \
        for (; j < je; j++) GATHER(acc##k) \
        jb##k = je; }
        PROC(0) PROC(1) PROC(2) PROC(3)
#undef PROC
    }

#define NODE_OUT(k) if (v##k) { \
    float4 o; \
    o.x = fmaxf(fmaf(di##k, acc##k.x, bb.x), 0.f); \
    o.y = fmaxf(fmaf(di##k, acc##k.y, bb.y), 0.f); \
    o.z = fmaxf(fmaf(di##k, acc##k.z, bb.z), 0.f); \
    o.w = fmaxf(fmaf(di##k, acc##k.w, bb.w), 0.f); \
    ((float4*)out)[(size_t)n##k * 32 + l] = o; }

    NODE_OUT(0) NODE_OUT(1) NODE_OUT(2) NODE_OUT(3)
#undef NODE_OUT
#undef NODE_INIT
#undef GATHER
#undef GATHER4
}

// ---------------- Set2Set LSTM step ----------------
#define GPB 8
__global__ __launch_bounds__(256) void k_lstm(const float* __restrict__ qstar,
                                              float* __restrict__ h, float* __restrict__ c,
                                              const float* __restrict__ Wih,
                                              const float* __restrict__ Whh,
                                              const float* __restrict__ bih,
                                              const float* __restrict__ bhh) {
    __shared__ float qs[GPB][256];
    __shared__ float hh[GPB][128];
    __shared__ float gates[GPB][512];
    int g0 = blockIdx.x * GPB;
    int t = threadIdx.x;
    for (int i = t; i < GPB * 256; i += 256) {
        int g = i >> 8, k = i & 255;
        qs[g][k] = qstar[(g0 + g) * 256 + k];
    }
    for (int i = t; i < GPB * 128; i += 256) {
        int g = i >> 7, k = i & 127;
        hh[g][k] = h[(g0 + g) * 128 + k];
    }
    __syncthreads();
    for (int jj = 0; jj < 2; jj++) {
        int j = t + jj * 256;
        float base = bih[j] + bhh[j];
        float acc[GPB];
#pragma unroll
        for (int g = 0; g < GPB; g++) acc[g] = base;
        const float* wi = Wih + j * 256;
        for (int k = 0; k < 256; k++) {
            float w = wi[k];
#pragma unroll
            for (int g = 0; g < GPB; g++) acc[g] = fmaf(w, qs[g][k], acc[g]);
        }
        const float* wh = Whh + j * 128;
        for (int k = 0; k < 128; k++) {
            float w = wh[k];
#pragma unroll
            for (int g = 0; g < GPB; g++) acc[g] = fmaf(w, hh[g][k], acc[g]);
        }
        for (int g = 0; g < GPB; g++) gates[g][j] = acc[g];
    }
    __syncthreads();
    for (int i = t; i < GPB * 128; i += 256) {
        int g = i >> 7, d = i & 127;
        int gg = g0 + g;
        float iv = gates[g][d], fv = gates[g][128 + d];
        float gv = gates[g][256 + d], ov = gates[g][384 + d];
        float si = 1.f / (1.f + expf(-iv));
        float sf = 1.f / (1.f + expf(-fv));
        float so = 1.f / (1.f + expf(-ov));
        float tg = tanhf(gv);
        float cn = sf * c[gg * 128 + d] + si * tg;
        float hn = so * tanhf(cn);
        c[gg * 128 + d] = cn;
        h[gg * 128 + d] = hn;
    }
}

// ---------------- attention: LDS-cached rows (fallback streams) ----------------
__global__ __launch_bounds__(256) void k_attn(const float* __restrict__ X,
                                              const int* __restrict__ goff,
                                              const float* __restrict__ h,
                                              float* __restrict__ eg,
                                              float* __restrict__ qstar) {
    int b = blockIdx.x;
    int t = threadIdx.x;
    int wv = t >> 6, l = t & 63;
    int n0 = goff[b], n1 = goff[b + 1];
    int cnt = n1 - n0;
    __shared__ float rows[MAXR][128];
    __shared__ float q[128];
    __shared__ float ebuf[MAXR];
    __shared__ float red[256];
    __shared__ float wm[4];
    if (t < 128) q[t] = h[b * 128 + t];
    if (cnt <= MAXR) {
        for (int i = t; i < cnt * 32; i += 256) {
            int r = i >> 5, c4 = i & 31;
            ((float4*)rows[r])[c4] = ((const float4*)(X + (size_t)(n0 + r) * 128))[c4];
        }
        __syncthreads();
        const float2* qp = (const float2*)q;
        float2 q2 = qp[l];
        float mloc = -INFINITY;
        for (int n = wv; n < cnt; n += 4) {
            const float2* xp = (const float2*)rows[n];
            float2 x2 = xp[l];
            float p = x2.x * q2.x + x2.y * q2.y;
#pragma unroll
            for (int o = 32; o > 0; o >>= 1) p += __shfl_xor(p, o, 64);
            if (l == 0) ebuf[n] = p;
            mloc = fmaxf(mloc, p);
        }
        if (l == 0) wm[wv] = mloc;
        __syncthreads();
        float m = fmaxf(fmaxf(wm[0], wm[1]), fmaxf(wm[2], wm[3]));
        if (isinf(m)) m = 0.f;
        float s = 0.f;
        for (int n = t; n < cnt; n += 256) {
            float z = expf(ebuf[n] - m);
            ebuf[n] = z;
            s += z;
        }
        red[t] = s;
        __syncthreads();
        for (int o = 128; o > 0; o >>= 1) {
            if (t < o) red[t] += red[t + o];
            __syncthreads();
        }
        float denom = red[0];
        float inv = (denom > 0.f) ? 1.f / denom : 0.f;
        __syncthreads();
        int g = t >> 7, col = t & 127;
        float acc = 0.f;
        for (int n = g; n < cnt; n += 2) {
            acc = fmaf(ebuf[n] * inv, rows[n][col], acc);
        }
        red[t] = acc;
        __syncthreads();
        if (t < 128) {
            float r = red[t] + red[t + 128];
            qstar[b * 256 + t] = q[t];
            qstar[b * 256 + 128 + t] = r;
        }
    } else {
        __syncthreads();
        const float2* qp = (const float2*)q;
        float2 q2 = qp[l];
        float mloc = -INFINITY;
        for (int n = n0 + wv; n < n1; n += 4) {
            const float2* xp = (const float2*)(X + (size_t)n * 128);
            float2 x2 = xp[l];
            float p = x2.x * q2.x + x2.y * q2.y;
#pragma unroll
            for (int o = 32; o > 0; o >>= 1) p += __shfl_xor(p, o, 64);
            if (l == 0) eg[n] = p;
            mloc = fmaxf(mloc, p);
        }
        if (l == 0) wm[wv] = mloc;
        __syncthreads();
        float m = fmaxf(fmaxf(wm[0], wm[1]), fmaxf(wm[2], wm[3]));
        if (isinf(m)) m = 0.f;
        float s = 0.f;
        for (int n = n0 + t; n < n1; n += 256) {
            float z = expf(eg[n] - m);
            eg[n] = z;
            s += z;
        }
        red[t] = s;
        __syncthreads();
        for (int o = 128; o > 0; o >>= 1) {
            if (t < o) red[t] += red[t + o];
            __syncthreads();
        }
        float denom = red[0];
        float inv = (denom > 0.f) ? 1.f / denom : 0.f;
        __syncthreads();
        int g = t >> 7, col = t & 127;
        float acc = 0.f;
        for (int n = n0 + g; n < n1; n += 2) {
            acc = fmaf(eg[n] * inv, X[(size_t)n * 128 + col], acc);
        }
        red[t] = acc;
        __syncthreads();
        if (t < 128) {
            float r = red[t] + red[t + 128];
            qstar[b * 256 + t] = q[t];
            qstar[b * 256 + 128 + t] = r;
        }
    }
}

// ---------------- final MLP head ----------------
__global__ __launch_bounds__(128) void k_mlp(const float* __restrict__ qstar,
                                             const float* __restrict__ Wl1,
                                             const float* __restrict__ bl1,
                                             const float* __restrict__ Wl2,
                                             const float* __restrict__ bl2,
                                             float* __restrict__ out) {
    int b = blockIdx.x, t = threadIdx.x;
    __shared__ float qs[256];
    __shared__ float hid[128];
    qs[t] = qstar[b * 256 + t];
    qs[128 + t] = qstar[b * 256 + 128 + t];
    __syncthreads();
    float acc = bl1[t];
#pragma unroll 4
    for (int k = 0; k < 256; k++) acc = fmaf(qs[k], Wl1[k * 128 + t], acc);
    hid[t] = fmaxf(acc, 0.f);
    __syncthreads();
    if (t < NUM_CLASSES) {
        float o = bl2[t];
#pragma unroll 4
        for (int k = 0; k < 128; k++) o = fmaf(hid[k], Wl2[k * 10 + t], o);
        out[b * 10 + t] = o;
    }
}

// ---------------- host ----------------

extern "C" void kernel_launch(void* const* d_in, const int* in_sizes, int n_in,
                              void* d_out, int out_size, void* d_ws, size_t ws_size,
                              hipStream_t stream) {
    const float* x    = (const float*)d_in[0];
    const void*  eidx = d_in[1];
    const void*  batr = d_in[2];
    const float* W1   = (const float*)d_in[3];
    const float* b1   = (const float*)d_in[4];
    const float* W2   = (const float*)d_in[5];
    const float* b2   = (const float*)d_in[6];
    const float* Wih  = (const float*)d_in[7];
    const float* Whh  = (const float*)d_in[8];
    const float* bih  = (const float*)d_in[9];
    const float* bhh  = (const float*)d_in[10];
    const float* Wl1  = (const float*)d_in[11];
    const float* bl1  = (const float*)d_in[12];
    const float* Wl2  = (const float*)d_in[13];
    const float* bl2  = (const float*)d_in[14];
    float* out = (float*)d_out;

    char* ws = (char*)d_ws;
    size_t off = 0;
    auto alloc = [&](size_t bytes) {
        size_t r = off;
        off = (off + bytes + 255) & ~(size_t)255;
        return r;
    };
    float* H        = (float*)(ws + alloc((size_t)N_NODES * 128 * 4));
    float* A        = (float*)(ws + alloc((size_t)N_NODES * 128 * 4));
    int*   csr      = (int*)(ws + alloc((size_t)N_EDGES * 4));
    unsigned int* edgebuf = (unsigned int*)(ws + alloc((size_t)2 * N_EDGES * 4));  // pdata+sdata; later Hb
    int*   histg    = (int*)(ws + alloc((size_t)NBLK * NBUK * 4));
    int*   btot     = (int*)(ws + alloc((size_t)NBUK * 4));
    int*   bbase    = (int*)(ws + alloc((size_t)(NBUK + 1) * 4));
    int*   offs     = (int*)(ws + alloc((size_t)(N_NODES + 1) * 4));
    unsigned int* ccnt = (unsigned int*)(ws + alloc((size_t)N_NODES * 2 * 4));
    float* dinv     = (float*)(ws + alloc((size_t)N_NODES * 4));
    float* e        = (float*)(ws + alloc((size_t)N_NODES * 4));
    int*   goff     = (int*)(ws + alloc((size_t)(NUM_GRAPHS + 1) * 4));
    float* state    = (float*)(ws + alloc((size_t)(NUM_GRAPHS * 128 * 2 + NUM_GRAPHS * 256) * 4));
    int*   flag     = (int*)(ws + alloc(4));
    if (off > ws_size) return;

    unsigned int* pdata = edgebuf;
    unsigned int* sdata = edgebuf + N_EDGES;
    // bf16 copy of gemm output; aliases edgebuf (dead after k_build).
    unsigned short* Hb = (unsigned short*)edgebuf;

    float* h_lstm = state;
    float* c_lstm = state + NUM_GRAPHS * 128;
    float* qstar  = state + NUM_GRAPHS * 256;

    const int B = 256;
    hipMemsetAsync(flag, 0, 4, stream);
    hipMemsetAsync(state, 0, (size_t)NUM_GRAPHS * 512 * 4, stream);
    k_detect<<<(4096 + B - 1) / B, B, 0, stream>>>((const int*)eidx, flag, 4096);
    k_goff<<<(N_NODES + B - 1) / B, B, 0, stream>>>(batr, flag, goff, N_NODES, NUM_GRAPHS);
    // CSR build: block-local counting sort, chunk-ordered adjacency
    k_pack<<<NBLK, 256, 0, stream>>>(eidx, flag, pdata, histg);
    k_colscan<<<NBUK, 256, 0, stream>>>(histg, btot);
    k_scan<<<1, 1024, 0, stream>>>(btot, bbase, NBUK);
    k_place<<<NBLK, 256, 0, stream>>>(pdata, histg, bbase, sdata);
    k_build<<<NBUK, 256, 0, stream>>>(sdata, bbase, btot, dinv, offs, ccnt, csr);
    // GCN conv 1
    k_gemm64<<<(N_NODES + 63) / 64, 256, 0, stream>>>(x, W1, H, Hb, N_NODES);
    k_agg<<<(N_NODES + 31) / 32, 256, 0, stream>>>(H, Hb, dinv, offs, ccnt, csr, b1, A);
    // GCN conv 2
    k_gemm64<<<(N_NODES + 63) / 64, 256, 0, stream>>>(A, W2, H, Hb, N_NODES);
    k_agg<<<(N_NODES + 31) / 32, 256, 0, stream>>>(H, Hb, dinv, offs, ccnt, csr, b2, A);
    // Set2Set
    for (int s = 0; s < STEPS; s++) {
        k_lstm<<<NUM_GRAPHS / GPB, 256, 0, stream>>>(qstar, h_lstm, c_lstm, Wih, Whh, bih, bhh);
        k_attn<<<NUM_GRAPHS, 256, 0, stream>>>(A, goff, h_lstm, e, qstar);
    }
    k_mlp<<<NUM_GRAPHS, 128, 0, stream>>>(qstar, Wl1, bl1, Wl2, bl2, out);
}

// Round 7
// 451.299 us; speedup vs baseline: 1.2506x; 1.2506x over previous
//
#include <hip/hip_runtime.h>
#include <hip/hip_bf16.h>
#include <math.h>

#define N_NODES 50000
#define N_EDGES 1600000
#define NUM_GRAPHS 512
#define HIDDEN 128
#define NUM_CLASSES 10
#define STEPS 3

#define NB_SHIFT 6                      // 64 nodes per bucket
#define NODES_PER_B (1 << NB_SHIFT)
#define NBUK ((N_NODES + NODES_PER_B - 1) / NODES_PER_B)   // 782
#define EPB 8192                        // edges per block in the sort
#define NBLK ((N_EDGES + EPB - 1) / EPB)                   // 196
#define MAXR 144                        // attn LDS row cap (max graph ~132)
#define NCH 7                           // src chunks of 8192 nodes (2MB bf16 each)

__device__ inline float bf2f(unsigned short h) {
    union { unsigned int u; float f; } v; v.u = ((unsigned int)h) << 16; return v.f;
}
__device__ inline unsigned short f2bf(float f) {
    union { float f; unsigned int u; } v; v.f = f;
    unsigned int r = (v.u + 0x7FFFu + ((v.u >> 16) & 1u)) >> 16;
    return (unsigned short)r;
}

// ---------------- utility kernels ----------------

// Detect int64 vs int32 storage of index inputs.
__global__ void k_detect(const int* p, int* flag, int npairs) {
    int i = blockIdx.x * blockDim.x + threadIdx.x;
    if (i < npairs) {
        int v = p[2 * i + 1];
        if (v != 0) atomicOr(flag, 1);
    }
}

// batch is sorted: graph start offsets by boundary detection (reads raw dtype).
__global__ void k_goff(const void* batr, const int* flag, int* goff, int n, int ng) {
    int i = blockIdx.x * blockDim.x + threadIdx.x;
    if (i >= n) return;
    bool is32 = (*flag != 0);
    int b = is32 ? ((const int*)batr)[i] : (int)((const long long*)batr)[i];
    int prev = (i == 0) ? -1
             : (is32 ? ((const int*)batr)[i - 1] : (int)((const long long*)batr)[i - 1]);
    for (int g = prev + 1; g <= b; g++) goff[g] = i;
    if (i == n - 1) {
        for (int g = b + 1; g <= ng; g++) goff[g] = n;
    }
}

// Sort pass 1: pack edges + per-block LDS bucket histogram (no global atomics).
__global__ __launch_bounds__(256) void k_pack(const void* eidx, const int* flag,
                                              unsigned int* __restrict__ pdata,
                                              int* __restrict__ histg) {
    __shared__ int lh[NBUK];
    int b = blockIdx.x, t = threadIdx.x;
    for (int i = t; i < NBUK; i += 256) lh[i] = 0;
    __syncthreads();
    int base = b * EPB;
    int end = base + EPB; if (end > N_EDGES) end = N_EDGES;
    bool is32 = (*flag != 0);
    for (int i = base + t; i < end; i += 256) {
        int src, dst;
        if (is32) {
            const int* p = (const int*)eidx;
            src = p[i]; dst = p[N_EDGES + i];
        } else {
            const long long* p = (const long long*)eidx;
            src = (int)p[i]; dst = (int)p[N_EDGES + i];
        }
        pdata[i] = ((unsigned)src << 16) | (unsigned)dst;
        atomicAdd(&lh[dst >> NB_SHIFT], 1);
    }
    __syncthreads();
    for (int i = t; i < NBUK; i += 256) histg[(size_t)b * NBUK + i] = lh[i];
}

// Sort pass 2: per bucket, exclusive scan of counts across blocks + bucket total.
__global__ __launch_bounds__(256) void k_colscan(int* __restrict__ histg,
                                                 int* __restrict__ btot) {
    __shared__ int wsum[4];
    int k = blockIdx.x, t = threadIdx.x;
    int wid = t >> 6, lane = t & 63;
    int v = (t < NBLK) ? histg[(size_t)t * NBUK + k] : 0;
    int x = v;
#pragma unroll
    for (int o = 1; o < 64; o <<= 1) {
        int y = __shfl_up(x, o, 64);
        if (lane >= o) x += y;
    }
    if (lane == 63) wsum[wid] = x;
    __syncthreads();
    int add = 0;
    for (int w = 0; w < wid; w++) add += wsum[w];
    if (t < NBLK) histg[(size_t)t * NBUK + k] = add + x - v;
    if (t == NBLK - 1) btot[k] = add + x;
}

// Single-block exclusive scan via shfl wave-scans (782 buckets).
__global__ __launch_bounds__(1024) void k_scan(const int* cnt, int* offs, int n) {
    __shared__ int wsum[16];
    __shared__ int carry_sh;
    int t = threadIdx.x, wid = t >> 6, lane = t & 63;
    if (t == 0) { carry_sh = 0; offs[0] = 0; }
    __syncthreads();
    for (int base = 0; base < n; base += 1024) {
        int i = base + t;
        int v = (i < n) ? cnt[i] : 0;
        int x = v;
#pragma unroll
        for (int o = 1; o < 64; o <<= 1) {
            int y = __shfl_up(x, o, 64);
            if (lane >= o) x += y;
        }
        if (lane == 63) wsum[wid] = x;
        __syncthreads();
        if (wid == 0 && lane < 16) {
            int w = wsum[lane];
#pragma unroll
            for (int o = 1; o < 16; o <<= 1) {
                int y = __shfl_up(w, o, 16);
                if (lane >= o) w += y;
            }
            wsum[lane] = w;
        }
        __syncthreads();
        int add = carry_sh + (wid > 0 ? wsum[wid - 1] : 0);
        if (i < n) offs[i + 1] = add + x;
        __syncthreads();
        if (t == 0) carry_sh += wsum[15];
        __syncthreads();
    }
}

// Sort pass 3: place packed edges into bucket-contiguous segments.
__global__ __launch_bounds__(256) void k_place(const unsigned int* __restrict__ pdata,
                                               const int* __restrict__ histg,
                                               const int* __restrict__ bbase,
                                               unsigned int* __restrict__ sdata) {
    __shared__ int lh[NBUK];
    __shared__ int lpre[NBUK];
    int b = blockIdx.x, t = threadIdx.x;
    for (int i = t; i < NBUK; i += 256) {
        lh[i] = 0;
        lpre[i] = bbase[i] + histg[(size_t)b * NBUK + i];
    }
    __syncthreads();
    int base = b * EPB;
    int end = base + EPB; if (end > N_EDGES) end = N_EDGES;
    for (int i = base + t; i < end; i += 256) {
        unsigned p = pdata[i];
        int k = (p & 0xFFFFu) >> NB_SHIFT;
        int pos = atomicAdd(&lh[k], 1);
        sdata[lpre[k] + pos] = p;
    }
}

// Fused CSR build per bucket: per-(node,chunk) counts, offs (bbase + wave scan),
// dinv, and chunk-ordered csr placement.
__global__ __launch_bounds__(256) void k_build(const unsigned int* __restrict__ sdata,
                                               const int* __restrict__ bbase,
                                               const int* __restrict__ btot,
                                               float* __restrict__ dinv,
                                               int* __restrict__ offs,
                                               int* __restrict__ csr) {
    __shared__ int lc[NODES_PER_B][8];   // counts, then absolute cursors
    int b = blockIdx.x, t = threadIdx.x;
    for (int i = t; i < NODES_PER_B * 8; i += 256) ((int*)lc)[i] = 0;
    __syncthreads();
    int s0 = bbase[b], n = btot[b];
    const unsigned int* sd = sdata + s0;
    for (int e = t; e < n; e += 256) {
        unsigned p = sd[e];
        atomicAdd(&lc[p & (NODES_PER_B - 1)][(p >> 16) >> 13], 1);
    }
    __syncthreads();
    if (t < NODES_PER_B) {
        int cnts[NCH];
        int deg = 0;
#pragma unroll
        for (int c = 0; c < NCH; c++) { cnts[c] = lc[t][c]; deg += cnts[c]; }
        int x = deg;
#pragma unroll
        for (int o = 1; o < 64; o <<= 1) {
            int y = __shfl_up(x, o, 64);
            if (t >= o) x += y;
        }
        int nodestart = s0 + x - deg;
        int node = b * NODES_PER_B + t;
        if (node < N_NODES) {
            offs[node] = nodestart;
            dinv[node] = rsqrtf((float)(deg + 1));
        }
        int run = nodestart;
#pragma unroll
        for (int c = 0; c < NCH; c++) { lc[t][c] = run; run += cnts[c]; }
    }
    if (b == 0 && t == 255) offs[N_NODES] = N_EDGES;
    __syncthreads();
    for (int e = t; e < n; e += 256) {
        unsigned p = sd[e];
        int src = (int)(p >> 16);
        int pos = atomicAdd(&lc[p & (NODES_PER_B - 1)][src >> 13], 1);
        csr[pos] = src;
    }
}

// ---------------- GEMM: H[n][j] = sum_k X[n][k] * W[k][j], K=N=128 ----------------
__global__ __launch_bounds__(256) void k_gemm64(const float* __restrict__ X,
                                                const float* __restrict__ W,
                                                float* __restrict__ H,
                                                unsigned short* __restrict__ Hb,
                                                int nrows) {
    __shared__ float xs[64][128];
    int t = threadIdx.x;
    int a = t >> 5;
    int j4 = t & 31;
    int row0 = blockIdx.x * 64;
    for (int i = t; i < 64 * 32; i += 256) {
        int rr = i >> 5;
        int c4 = i & 31;
        int r = row0 + rr; if (r >= nrows) r = nrows - 1;
        ((float4*)xs[rr])[c4] = ((const float4*)X)[(size_t)r * 32 + c4];
    }
    __syncthreads();
    float4 acc[8];
#pragma unroll
    for (int i = 0; i < 8; i++) acc[i] = {0.f, 0.f, 0.f, 0.f};
    const float4* wp = (const float4*)W;
#pragma unroll 4
    for (int k = 0; k < 128; k++) {
        float4 w4 = wp[k * 32 + j4];
#pragma unroll
        for (int i = 0; i < 8; i++) {
            float xv = xs[8 * a + i][k];
            acc[i].x = fmaf(xv, w4.x, acc[i].x);
            acc[i].y = fmaf(xv, w4.y, acc[i].y);
            acc[i].z = fmaf(xv, w4.z, acc[i].z);
            acc[i].w = fmaf(xv, w4.w, acc[i].w);
        }
    }
#pragma unroll
    for (int i = 0; i < 8; i++) {
        int r = row0 + 8 * a + i;
        if (r < nrows) {
            ((float4*)H)[(size_t)r * 32 + j4] = acc[i];
            ushort4 b4;
            b4.x = f2bf(acc[i].x); b4.y = f2bf(acc[i].y);
            b4.z = f2bf(acc[i].z); b4.w = f2bf(acc[i].w);
            ((ushort4*)Hb)[(size_t)r * 32 + j4] = b4;
        }
    }
}

// ---------------- GCN aggregate (round-5 structure, 8-deep gather unroll) ----
// One wave per node; half-waves process alternating edges; bf16 neighbor rows.
__global__ __launch_bounds__(256) void k_agg(const float* __restrict__ H,
                                             const unsigned short* __restrict__ Hb,
                                             const float* __restrict__ dinv,
                                             const int* __restrict__ offs,
                                             const int* __restrict__ csr,
                                             const float* __restrict__ b,
                                             float* __restrict__ out) {
    int wave = (blockIdx.x * blockDim.x + threadIdx.x) >> 6;
    int lane = threadIdx.x & 63;
    if (wave >= N_NODES) return;
    int n = wave;
    int half = lane >> 5;
    int l = lane & 31;
    float di = dinv[n];
    const ushort4* hbp = (const ushort4*)Hb;
    float4 acc = {0.f, 0.f, 0.f, 0.f};
    if (half == 0) {
        float4 hn = ((const float4*)H)[(size_t)n * 32 + l];
        acc.x = di * hn.x; acc.y = di * hn.y; acc.z = di * hn.z; acc.w = di * hn.w;
    }
    int e0 = offs[n], e1 = offs[n + 1];
    int j = e0 + half;
    // 8 edges per half-wave in flight
    for (; j + 14 < e1; j += 16) {
        int s[8]; float ds[8]; ushort4 a[8];
#pragma unroll
        for (int u = 0; u < 8; u++) s[u] = csr[j + 2 * u];
#pragma unroll
        for (int u = 0; u < 8; u++) ds[u] = dinv[s[u]];
#pragma unroll
        for (int u = 0; u < 8; u++) a[u] = hbp[(size_t)s[u] * 32 + l];
#pragma unroll
        for (int u = 0; u < 8; u++) {
            acc.x = fmaf(ds[u], bf2f(a[u].x), acc.x);
            acc.y = fmaf(ds[u], bf2f(a[u].y), acc.y);
            acc.z = fmaf(ds[u], bf2f(a[u].z), acc.z);
            acc.w = fmaf(ds[u], bf2f(a[u].w), acc.w);
        }
    }
    for (; j + 6 < e1; j += 8) {
        int s[4]; float ds[4]; ushort4 a[4];
#pragma unroll
        for (int u = 0; u < 4; u++) s[u] = csr[j + 2 * u];
#pragma unroll
        for (int u = 0; u < 4; u++) ds[u] = dinv[s[u]];
#pragma unroll
        for (int u = 0; u < 4; u++) a[u] = hbp[(size_t)s[u] * 32 + l];
#pragma unroll
        for (int u = 0; u < 4; u++) {
            acc.x = fmaf(ds[u], bf2f(a[u].x), acc.x);
            acc.y = fmaf(ds[u], bf2f(a[u].y), acc.y);
            acc.z = fmaf(ds[u], bf2f(a[u].z), acc.z);
            acc.w = fmaf(ds[u], bf2f(a[u].w), acc.w);
        }
    }
    for (; j < e1; j += 2) {
        int s = csr[j];
        float ds = dinv[s];
        ushort4 hs = hbp[(size_t)s * 32 + l];
        acc.x = fmaf(ds, bf2f(hs.x), acc.x); acc.y = fmaf(ds, bf2f(hs.y), acc.y);
        acc.z = fmaf(ds, bf2f(hs.z), acc.z); acc.w = fmaf(ds, bf2f(hs.w), acc.w);
    }
    acc.x += __shfl_xor(acc.x, 32, 64);
    acc.y += __shfl_xor(acc.y, 32, 64);
    acc.z += __shfl_xor(acc.z, 32, 64);
    acc.w += __shfl_xor(acc.w, 32, 64);
    if (half == 0) {
        const float4* bp = (const float4*)b;
        float4 bb = bp[l];
        float4 o4;
        o4.x = fmaxf(fmaf(di, acc.x, bb.x), 0.f);
        o4.y = fmaxf(fmaf(di, acc.y, bb.y), 0.f);
        o4.z = fmaxf(fmaf(di, acc.z, bb.z), 0.f);
        o4.w = fmaxf(fmaf(di, acc.w, bb.w), 0.f);
        ((float4*)out)[(size_t)n * 32 + l] = o4;
    }
}

// ---------------- Set2Set LSTM step ----------------
#define GPB 8
__global__ __launch_bounds__(256) void k_lstm(const float* __restrict__ qstar,
                                              float* __restrict__ h, float* __restrict__ c,
                                              const float* __restrict__ Wih,
                                              const float* __restrict__ Whh,
                                              const float* __restrict__ bih,
                                              const float* __restrict__ bhh) {
    __shared__ float qs[GPB][256];
    __shared__ float hh[GPB][128];
    __shared__ float gates[GPB][512];
    int g0 = blockIdx.x * GPB;
    int t = threadIdx.x;
    for (int i = t; i < GPB * 256; i += 256) {
        int g = i >> 8, k = i & 255;
        qs[g][k] = qstar[(g0 + g) * 256 + k];
    }
    for (int i = t; i < GPB * 128; i += 256) {
        int g = i >> 7, k = i & 127;
        hh[g][k] = h[(g0 + g) * 128 + k];
    }
    __syncthreads();
    for (int jj = 0; jj < 2; jj++) {
        int j = t + jj * 256;
        float base = bih[j] + bhh[j];
        float acc[GPB];
#pragma unroll
        for (int g = 0; g < GPB; g++) acc[g] = base;
        const float* wi = Wih + j * 256;
        for (int k = 0; k < 256; k++) {
            float w = wi[k];
#pragma unroll
            for (int g = 0; g < GPB; g++) acc[g] = fmaf(w, qs[g][k], acc[g]);
        }
        const float* wh = Whh + j * 128;
        for (int k = 0; k < 128; k++) {
            float w = wh[k];
#pragma unroll
            for (int g = 0; g < GPB; g++) acc[g] = fmaf(w, hh[g][k], acc[g]);
        }
        for (int g = 0; g < GPB; g++) gates[g][j] = acc[g];
    }
    __syncthreads();
    for (int i = t; i < GPB * 128; i += 256) {
        int g = i >> 7, d = i & 127;
        int gg = g0 + g;
        float iv = gates[g][d], fv = gates[g][128 + d];
        float gv = gates[g][256 + d], ov = gates[g][384 + d];
        float si = 1.f / (1.f + expf(-iv));
        float sf = 1.f / (1.f + expf(-fv));
        float so = 1.f / (1.f + expf(-ov));
        float tg = tanhf(gv);
        float cn = sf * c[gg * 128 + d] + si * tg;
        float hn = so * tanhf(cn);
        c[gg * 128 + d] = cn;
        h[gg * 128 + d] = hn;
    }
}

// ---------------- attention: LDS-cached rows (fallback streams) ----------------
__global__ __launch_bounds__(256) void k_attn(const float* __restrict__ X,
                                              const int* __restrict__ goff,
                                              const float* __restrict__ h,
                                              float* __restrict__ eg,
                                              float* __restrict__ qstar) {
    int b = blockIdx.x;
    int t = threadIdx.x;
    int wv = t >> 6, l = t & 63;
    int n0 = goff[b], n1 = goff[b + 1];
    int cnt = n1 - n0;
    __shared__ float rows[MAXR][128];
    __shared__ float q[128];
    __shared__ float ebuf[MAXR];
    __shared__ float red[256];
    __shared__ float wm[4];
    if (t < 128) q[t] = h[b * 128 + t];
    if (cnt <= MAXR) {
        for (int i = t; i < cnt * 32; i += 256) {
            int r = i >> 5, c4 = i & 31;
            ((float4*)rows[r])[c4] = ((const float4*)(X + (size_t)(n0 + r) * 128))[c4];
        }
        __syncthreads();
        const float2* qp = (const float2*)q;
        float2 q2 = qp[l];
        float mloc = -INFINITY;
        for (int n = wv; n < cnt; n += 4) {
            const float2* xp = (const float2*)rows[n];
            float2 x2 = xp[l];
            float p = x2.x * q2.x + x2.y * q2.y;
#pragma unroll
            for (int o = 32; o > 0; o >>= 1) p += __shfl_xor(p, o, 64);
            if (l == 0) ebuf[n] = p;
            mloc = fmaxf(mloc, p);
        }
        if (l == 0) wm[wv] = mloc;
        __syncthreads();
        float m = fmaxf(fmaxf(wm[0], wm[1]), fmaxf(wm[2], wm[3]));
        if (isinf(m)) m = 0.f;
        float s = 0.f;
        for (int n = t; n < cnt; n += 256) {
            float z = expf(ebuf[n] - m);
            ebuf[n] = z;
            s += z;
        }
        red[t] = s;
        __syncthreads();
        for (int o = 128; o > 0; o >>= 1) {
            if (t < o) red[t] += red[t + o];
            __syncthreads();
        }
        float denom = red[0];
        float inv = (denom > 0.f) ? 1.f / denom : 0.f;
        __syncthreads();
        int g = t >> 7, col = t & 127;
        float acc = 0.f;
        for (int n = g; n < cnt; n += 2) {
            acc = fmaf(ebuf[n] * inv, rows[n][col], acc);
        }
        red[t] = acc;
        __syncthreads();
        if (t < 128) {
            float r = red[t] + red[t + 128];
            qstar[b * 256 + t] = q[t];
            qstar[b * 256 + 128 + t] = r;
        }
    } else {
        __syncthreads();
        const float2* qp = (const float2*)q;
        float2 q2 = qp[l];
        float mloc = -INFINITY;
        for (int n = n0 + wv; n < n1; n += 4) {
            const float2* xp = (const float2*)(X + (size_t)n * 128);
            float2 x2 = xp[l];
            float p = x2.x * q2.x + x2.y * q2.y;
#pragma unroll
            for (int o = 32; o > 0; o >>= 1) p += __shfl_xor(p, o, 64);
            if (l == 0) eg[n] = p;
            mloc = fmaxf(mloc, p);
        }
        if (l == 0) wm[wv] = mloc;
        __syncthreads();
        float m = fmaxf(fmaxf(wm[0], wm[1]), fmaxf(wm[2], wm[3]));
        if (isinf(m)) m = 0.f;
        float s = 0.f;
        for (int n = n0 + t; n < n1; n += 256) {
            float z = expf(eg[n] - m);
            eg[n] = z;
            s += z;
        }
        red[t] = s;
        __syncthreads();
        for (int o = 128; o > 0; o >>= 1) {
            if (t < o) red[t] += red[t + o];
            __syncthreads();
        }
        float denom = red[0];
        float inv = (denom > 0.f) ? 1.f / denom : 0.f;
        __syncthreads();
        int g = t >> 7, col = t & 127;
        float acc = 0.f;
        for (int n = n0 + g; n < n1; n += 2) {
            acc = fmaf(eg[n] * inv, X[(size_t)n * 128 + col], acc);
        }
        red[t] = acc;
        __syncthreads();
        if (t < 128) {
            float r = red[t] + red[t + 128];
            qstar[b * 256 + t] = q[t];
            qstar[b * 256 + 128 + t] = r;
        }
    }
}

// ---------------- final MLP head ----------------
__global__ __launch_bounds__(128) void k_mlp(const float* __restrict__ qstar,
                                             const float* __restrict__ Wl1,
                                             const float* __restrict__ bl1,
                                             const float* __restrict__ Wl2,
                                             const float* __restrict__ bl2,
                                             float* __restrict__ out) {
    int b = blockIdx.x, t = threadIdx.x;
    __shared__ float qs[256];
    __shared__ float hid[128];
    qs[t] = qstar[b * 256 + t];
    qs[128 + t] = qstar[b * 256 + 128 + t];
    __syncthreads();
    float acc = bl1[t];
#pragma unroll 4
    for (int k = 0; k < 256; k++) acc = fmaf(qs[k], Wl1[k * 128 + t], acc);
    hid[t] = fmaxf(acc, 0.f);
    __syncthreads();
    if (t < NUM_CLASSES) {
        float o = bl2[t];
#pragma unroll 4
        for (int k = 0; k < 128; k++) o = fmaf(hid[k], Wl2[k * 10 + t], o);
        out[b * 10 + t] = o;
    }
}

// ---------------- host ----------------

extern "C" void kernel_launch(void* const* d_in, const int* in_sizes, int n_in,
                              void* d_out, int out_size, void* d_ws, size_t ws_size,
                              hipStream_t stream) {
    const float* x    = (const float*)d_in[0];
    const void*  eidx = d_in[1];
    const void*  batr = d_in[2];
    const float* W1   = (const float*)d_in[3];
    const float* b1   = (const float*)d_in[4];
    const float* W2   = (const float*)d_in[5];
    const float* b2   = (const float*)d_in[6];
    const float* Wih  = (const float*)d_in[7];
    const float* Whh  = (const float*)d_in[8];
    const float* bih  = (const float*)d_in[9];
    const float* bhh  = (const float*)d_in[10];
    const float* Wl1  = (const float*)d_in[11];
    const float* bl1  = (const float*)d_in[12];
    const float* Wl2  = (const float*)d_in[13];
    const float* bl2  = (const float*)d_in[14];
    float* out = (float*)d_out;

    char* ws = (char*)d_ws;
    size_t off = 0;
    auto alloc = [&](size_t bytes) {
        size_t r = off;
        off = (off + bytes + 255) & ~(size_t)255;
        return r;
    };
    float* H        = (float*)(ws + alloc((size_t)N_NODES * 128 * 4));
    float* A        = (float*)(ws + alloc((size_t)N_NODES * 128 * 4));
    int*   csr      = (int*)(ws + alloc((size_t)N_EDGES * 4));
    unsigned int* edgebuf = (unsigned int*)(ws + alloc((size_t)2 * N_EDGES * 4));  // pdata+sdata; later Hb
    int*   histg    = (int*)(ws + alloc((size_t)NBLK * NBUK * 4));
    int*   btot     = (int*)(ws + alloc((size_t)NBUK * 4));
    int*   bbase    = (int*)(ws + alloc((size_t)(NBUK + 1) * 4));
    int*   offs     = (int*)(ws + alloc((size_t)(N_NODES + 1) * 4));
    float* dinv     = (float*)(ws + alloc((size_t)N_NODES * 4));
    float* e        = (float*)(ws + alloc((size_t)N_NODES * 4));
    int*   goff     = (int*)(ws + alloc((size_t)(NUM_GRAPHS + 1) * 4));
    float* state    = (float*)(ws + alloc((size_t)(NUM_GRAPHS * 128 * 2 + NUM_GRAPHS * 256) * 4));
    int*   flag     = (int*)(ws + alloc(4));
    if (off > ws_size) return;

    unsigned int* pdata = edgebuf;
    unsigned int* sdata = edgebuf + N_EDGES;
    // bf16 copy of gemm output; aliases edgebuf (dead after k_build).
    unsigned short* Hb = (unsigned short*)edgebuf;

    float* h_lstm = state;
    float* c_lstm = state + NUM_GRAPHS * 128;
    float* qstar  = state + NUM_GRAPHS * 256;

    const int B = 256;
    hipMemsetAsync(flag, 0, 4, stream);
    hipMemsetAsync(state, 0, (size_t)NUM_GRAPHS * 512 * 4, stream);
    k_detect<<<(4096 + B - 1) / B, B, 0, stream>>>((const int*)eidx, flag, 4096);
    k_goff<<<(N_NODES + B - 1) / B, B, 0, stream>>>(batr, flag, goff, N_NODES, NUM_GRAPHS);
    // CSR build: block-local counting sort, chunk-ordered adjacency
    k_pack<<<NBLK, 256, 0, stream>>>(eidx, flag, pdata, histg);
    k_colscan<<<NBUK, 256, 0, stream>>>(histg, btot);
    k_scan<<<1, 1024, 0, stream>>>(btot, bbase, NBUK);
    k_place<<<NBLK, 256, 0, stream>>>(pdata, histg, bbase, sdata);
    k_build<<<NBUK, 256, 0, stream>>>(sdata, bbase, btot, dinv, offs, csr);
    // GCN conv 1
    k_gemm64<<<(N_NODES + 63) / 64, 256, 0, stream>>>(x, W1, H, Hb, N_NODES);
    k_agg<<<(N_NODES + 3) / 4, 256, 0, stream>>>(H, Hb, dinv, offs, csr, b1, A);
    // GCN conv 2
    k_gemm64<<<(N_NODES + 63) / 64, 256, 0, stream>>>(A, W2, H, Hb, N_NODES);
    k_agg<<<(N_NODES + 3) / 4, 256, 0, stream>>>(H, Hb, dinv, offs, csr, b2, A);
    // Set2Set
    for (int s = 0; s < STEPS; s++) {
        k_lstm<<<NUM_GRAPHS / GPB, 256, 0, stream>>>(qstar, h_lstm, c_lstm, Wih, Whh, bih, bhh);
        k_attn<<<NUM_GRAPHS, 256, 0, stream>>>(A, goff, h_lstm, e, qstar);
    }
    k_mlp<<<NUM_GRAPHS, 128, 0, stream>>>(qstar, Wl1, bl1, Wl2, bl2, out);
}

// Round 8
// 418.343 us; speedup vs baseline: 1.3492x; 1.0788x over previous
//
#include <hip/hip_runtime.h>
#include <hip/hip_bf16.h>
#include <math.h>

#define N_NODES 50000
#define N_EDGES 1600000
#define NUM_GRAPHS 512
#define HIDDEN 128
#define NUM_CLASSES 10
#define STEPS 3

#define NB_SHIFT 6                      // 64 nodes per bucket
#define NODES_PER_B (1 << NB_SHIFT)
#define NBUK ((N_NODES + NODES_PER_B - 1) / NODES_PER_B)   // 782
#define EPB 8192                        // edges per block in the sort
#define NBLK ((N_EDGES + EPB - 1) / EPB)                   // 196
#define MAXR 144                        // attn LDS row cap (max graph ~132)
#define NCH 7                           // src chunks of 8192 nodes

__device__ inline float bf2f(unsigned short h) {
    union { unsigned int u; float f; } v; v.u = ((unsigned int)h) << 16; return v.f;
}
__device__ inline unsigned short f2bf(float f) {
    union { float f; unsigned int u; } v; v.f = f;
    unsigned int r = (v.u + 0x7FFFu + ((v.u >> 16) & 1u)) >> 16;
    return (unsigned short)r;
}

// ---------------- utility kernels ----------------

// Detect int64 vs int32 storage of index inputs.
__global__ void k_detect(const int* p, int* flag, int npairs) {
    int i = blockIdx.x * blockDim.x + threadIdx.x;
    if (i < npairs) {
        int v = p[2 * i + 1];
        if (v != 0) atomicOr(flag, 1);
    }
}

// batch is sorted: graph start offsets by boundary detection (reads raw dtype).
__global__ void k_goff(const void* batr, const int* flag, int* goff, int n, int ng) {
    int i = blockIdx.x * blockDim.x + threadIdx.x;
    if (i >= n) return;
    bool is32 = (*flag != 0);
    int b = is32 ? ((const int*)batr)[i] : (int)((const long long*)batr)[i];
    int prev = (i == 0) ? -1
             : (is32 ? ((const int*)batr)[i - 1] : (int)((const long long*)batr)[i - 1]);
    for (int g = prev + 1; g <= b; g++) goff[g] = i;
    if (i == n - 1) {
        for (int g = b + 1; g <= ng; g++) goff[g] = n;
    }
}

// Sort pass 1: pack edges + per-block LDS bucket histogram (no global atomics).
__global__ __launch_bounds__(256) void k_pack(const void* eidx, const int* flag,
                                              unsigned int* __restrict__ pdata,
                                              int* __restrict__ histg) {
    __shared__ int lh[NBUK];
    int b = blockIdx.x, t = threadIdx.x;
    for (int i = t; i < NBUK; i += 256) lh[i] = 0;
    __syncthreads();
    int base = b * EPB;
    int end = base + EPB; if (end > N_EDGES) end = N_EDGES;
    bool is32 = (*flag != 0);
    for (int i = base + t; i < end; i += 256) {
        int src, dst;
        if (is32) {
            const int* p = (const int*)eidx;
            src = p[i]; dst = p[N_EDGES + i];
        } else {
            const long long* p = (const long long*)eidx;
            src = (int)p[i]; dst = (int)p[N_EDGES + i];
        }
        pdata[i] = ((unsigned)src << 16) | (unsigned)dst;
        atomicAdd(&lh[dst >> NB_SHIFT], 1);
    }
    __syncthreads();
    for (int i = t; i < NBUK; i += 256) histg[(size_t)b * NBUK + i] = lh[i];
}

// Sort pass 2: per bucket, exclusive scan of counts across blocks + bucket total.
__global__ __launch_bounds__(256) void k_colscan(int* __restrict__ histg,
                                                 int* __restrict__ btot) {
    __shared__ int wsum[4];
    int k = blockIdx.x, t = threadIdx.x;
    int wid = t >> 6, lane = t & 63;
    int v = (t < NBLK) ? histg[(size_t)t * NBUK + k] : 0;
    int x = v;
#pragma unroll
    for (int o = 1; o < 64; o <<= 1) {
        int y = __shfl_up(x, o, 64);
        if (lane >= o) x += y;
    }
    if (lane == 63) wsum[wid] = x;
    __syncthreads();
    int add = 0;
    for (int w = 0; w < wid; w++) add += wsum[w];
    if (t < NBLK) histg[(size_t)t * NBUK + k] = add + x - v;
    if (t == NBLK - 1) btot[k] = add + x;
}

// Single-block exclusive scan via shfl wave-scans (782 buckets).
__global__ __launch_bounds__(1024) void k_scan(const int* cnt, int* offs, int n) {
    __shared__ int wsum[16];
    __shared__ int carry_sh;
    int t = threadIdx.x, wid = t >> 6, lane = t & 63;
    if (t == 0) { carry_sh = 0; offs[0] = 0; }
    __syncthreads();
    for (int base = 0; base < n; base += 1024) {
        int i = base + t;
        int v = (i < n) ? cnt[i] : 0;
        int x = v;
#pragma unroll
        for (int o = 1; o < 64; o <<= 1) {
            int y = __shfl_up(x, o, 64);
            if (lane >= o) x += y;
        }
        if (lane == 63) wsum[wid] = x;
        __syncthreads();
        if (wid == 0 && lane < 16) {
            int w = wsum[lane];
#pragma unroll
            for (int o = 1; o < 16; o <<= 1) {
                int y = __shfl_up(w, o, 16);
                if (lane >= o) w += y;
            }
            wsum[lane] = w;
        }
        __syncthreads();
        int add = carry_sh + (wid > 0 ? wsum[wid - 1] : 0);
        if (i < n) offs[i + 1] = add + x;
        __syncthreads();
        if (t == 0) carry_sh += wsum[15];
        __syncthreads();
    }
}

// Sort pass 3: place packed edges into bucket-contiguous segments.
__global__ __launch_bounds__(256) void k_place(const unsigned int* __restrict__ pdata,
                                               const int* __restrict__ histg,
                                               const int* __restrict__ bbase,
                                               unsigned int* __restrict__ sdata) {
    __shared__ int lh[NBUK];
    __shared__ int lpre[NBUK];
    int b = blockIdx.x, t = threadIdx.x;
    for (int i = t; i < NBUK; i += 256) {
        lh[i] = 0;
        lpre[i] = bbase[i] + histg[(size_t)b * NBUK + i];
    }
    __syncthreads();
    int base = b * EPB;
    int end = base + EPB; if (end > N_EDGES) end = N_EDGES;
    for (int i = base + t; i < end; i += 256) {
        unsigned p = pdata[i];
        int k = (p & 0xFFFFu) >> NB_SHIFT;
        int pos = atomicAdd(&lh[k], 1);
        sdata[lpre[k] + pos] = p;
    }
}

// Fused CSR build per bucket: per-(node,chunk) counts, offs (bbase + wave scan),
// dinv, and chunk-ordered csr placement.
__global__ __launch_bounds__(256) void k_build(const unsigned int* __restrict__ sdata,
                                               const int* __restrict__ bbase,
                                               const int* __restrict__ btot,
                                               float* __restrict__ dinv,
                                               int* __restrict__ offs,
                                               int* __restrict__ csr) {
    __shared__ int lc[NODES_PER_B][8];   // counts, then absolute cursors
    int b = blockIdx.x, t = threadIdx.x;
    for (int i = t; i < NODES_PER_B * 8; i += 256) ((int*)lc)[i] = 0;
    __syncthreads();
    int s0 = bbase[b], n = btot[b];
    const unsigned int* sd = sdata + s0;
    for (int e = t; e < n; e += 256) {
        unsigned p = sd[e];
        atomicAdd(&lc[p & (NODES_PER_B - 1)][(p >> 16) >> 13], 1);
    }
    __syncthreads();
    if (t < NODES_PER_B) {
        int cnts[NCH];
        int deg = 0;
#pragma unroll
        for (int c = 0; c < NCH; c++) { cnts[c] = lc[t][c]; deg += cnts[c]; }
        int x = deg;
#pragma unroll
        for (int o = 1; o < 64; o <<= 1) {
            int y = __shfl_up(x, o, 64);
            if (t >= o) x += y;
        }
        int nodestart = s0 + x - deg;
        int node = b * NODES_PER_B + t;
        if (node < N_NODES) {
            offs[node] = nodestart;
            dinv[node] = rsqrtf((float)(deg + 1));
        }
        int run = nodestart;
#pragma unroll
        for (int c = 0; c < NCH; c++) { lc[t][c] = run; run += cnts[c]; }
    }
    if (b == 0 && t == 255) offs[N_NODES] = N_EDGES;
    __syncthreads();
    for (int e = t; e < n; e += 256) {
        unsigned p = sd[e];
        int src = (int)(p >> 16);
        int pos = atomicAdd(&lc[p & (NODES_PER_B - 1)][src >> 13], 1);
        csr[pos] = src;
    }
}

// ---------------- GEMM: Hb[n][j] = bf16(sum_k X[n][k] * W[k][j]), K=N=128 ----
// 64 rows/block, 256 threads; thread owns 8 rows x 4 cols; k-vectorized loads.
__global__ __launch_bounds__(256) void k_gemm64(const float* __restrict__ X,
                                                const float* __restrict__ W,
                                                unsigned short* __restrict__ Hb,
                                                int nrows) {
    __shared__ float xs[64][128];
    int t = threadIdx.x;
    int a = t >> 5;          // row group: rows 8a..8a+7
    int j4 = t & 31;         // float4 column group
    int row0 = blockIdx.x * 64;
    for (int i = t; i < 64 * 32; i += 256) {
        int rr = i >> 5;
        int c4 = i & 31;
        int r = row0 + rr; if (r >= nrows) r = nrows - 1;
        ((float4*)xs[rr])[c4] = ((const float4*)X)[(size_t)r * 32 + c4];
    }
    __syncthreads();
    float4 acc[8];
#pragma unroll
    for (int i = 0; i < 8; i++) acc[i] = {0.f, 0.f, 0.f, 0.f};
    const float4* wp = (const float4*)W;
#pragma unroll 2
    for (int k0 = 0; k0 < 128; k0 += 4) {
        float4 w0 = wp[(k0 + 0) * 32 + j4];
        float4 w1 = wp[(k0 + 1) * 32 + j4];
        float4 w2 = wp[(k0 + 2) * 32 + j4];
        float4 w3 = wp[(k0 + 3) * 32 + j4];
#pragma unroll
        for (int i = 0; i < 8; i++) {
            float4 xv = *(const float4*)&xs[8 * a + i][k0];
            acc[i].x = fmaf(xv.x, w0.x, acc[i].x); acc[i].y = fmaf(xv.x, w0.y, acc[i].y);
            acc[i].z = fmaf(xv.x, w0.z, acc[i].z); acc[i].w = fmaf(xv.x, w0.w, acc[i].w);
            acc[i].x = fmaf(xv.y, w1.x, acc[i].x); acc[i].y = fmaf(xv.y, w1.y, acc[i].y);
            acc[i].z = fmaf(xv.y, w1.z, acc[i].z); acc[i].w = fmaf(xv.y, w1.w, acc[i].w);
            acc[i].x = fmaf(xv.z, w2.x, acc[i].x); acc[i].y = fmaf(xv.z, w2.y, acc[i].y);
            acc[i].z = fmaf(xv.z, w2.z, acc[i].z); acc[i].w = fmaf(xv.z, w2.w, acc[i].w);
            acc[i].x = fmaf(xv.w, w3.x, acc[i].x); acc[i].y = fmaf(xv.w, w3.y, acc[i].y);
            acc[i].z = fmaf(xv.w, w3.z, acc[i].z); acc[i].w = fmaf(xv.w, w3.w, acc[i].w);
        }
    }
#pragma unroll
    for (int i = 0; i < 8; i++) {
        int r = row0 + 8 * a + i;
        if (r < nrows) {
            ushort4 b4;
            b4.x = f2bf(acc[i].x); b4.y = f2bf(acc[i].y);
            b4.z = f2bf(acc[i].z); b4.w = f2bf(acc[i].w);
            ((ushort4*)Hb)[(size_t)r * 32 + j4] = b4;
        }
    }
}

// ---------------- GCN aggregate (bf16 rows for self + gather) ----------------
__global__ __launch_bounds__(256) void k_agg(const unsigned short* __restrict__ Hb,
                                             const float* __restrict__ dinv,
                                             const int* __restrict__ offs,
                                             const int* __restrict__ csr,
                                             const float* __restrict__ b,
                                             float* __restrict__ out) {
    int wave = (blockIdx.x * blockDim.x + threadIdx.x) >> 6;
    int lane = threadIdx.x & 63;
    if (wave >= N_NODES) return;
    int n = wave;
    int half = lane >> 5;
    int l = lane & 31;
    float di = dinv[n];
    const ushort4* hbp = (const ushort4*)Hb;
    float4 acc = {0.f, 0.f, 0.f, 0.f};
    if (half == 0) {
        ushort4 hn = hbp[(size_t)n * 32 + l];
        acc.x = di * bf2f(hn.x); acc.y = di * bf2f(hn.y);
        acc.z = di * bf2f(hn.z); acc.w = di * bf2f(hn.w);
    }
    int e0 = offs[n], e1 = offs[n + 1];
    int j = e0 + half;
    for (; j + 14 < e1; j += 16) {
        int s[8]; float ds[8]; ushort4 a[8];
#pragma unroll
        for (int u = 0; u < 8; u++) s[u] = csr[j + 2 * u];
#pragma unroll
        for (int u = 0; u < 8; u++) ds[u] = dinv[s[u]];
#pragma unroll
        for (int u = 0; u < 8; u++) a[u] = hbp[(size_t)s[u] * 32 + l];
#pragma unroll
        for (int u = 0; u < 8; u++) {
            acc.x = fmaf(ds[u], bf2f(a[u].x), acc.x);
            acc.y = fmaf(ds[u], bf2f(a[u].y), acc.y);
            acc.z = fmaf(ds[u], bf2f(a[u].z), acc.z);
            acc.w = fmaf(ds[u], bf2f(a[u].w), acc.w);
        }
    }
    for (; j + 6 < e1; j += 8) {
        int s[4]; float ds[4]; ushort4 a[4];
#pragma unroll
        for (int u = 0; u < 4; u++) s[u] = csr[j + 2 * u];
#pragma unroll
        for (int u = 0; u < 4; u++) ds[u] = dinv[s[u]];
#pragma unroll
        for (int u = 0; u < 4; u++) a[u] = hbp[(size_t)s[u] * 32 + l];
#pragma unroll
        for (int u = 0; u < 4; u++) {
            acc.x = fmaf(ds[u], bf2f(a[u].x), acc.x);
            acc.y = fmaf(ds[u], bf2f(a[u].y), acc.y);
            acc.z = fmaf(ds[u], bf2f(a[u].z), acc.z);
            acc.w = fmaf(ds[u], bf2f(a[u].w), acc.w);
        }
    }
    for (; j < e1; j += 2) {
        int s = csr[j];
        float ds = dinv[s];
        ushort4 hs = hbp[(size_t)s * 32 + l];
        acc.x = fmaf(ds, bf2f(hs.x), acc.x); acc.y = fmaf(ds, bf2f(hs.y), acc.y);
        acc.z = fmaf(ds, bf2f(hs.z), acc.z); acc.w = fmaf(ds, bf2f(hs.w), acc.w);
    }
    acc.x += __shfl_xor(acc.x, 32, 64);
    acc.y += __shfl_xor(acc.y, 32, 64);
    acc.z += __shfl_xor(acc.z, 32, 64);
    acc.w += __shfl_xor(acc.w, 32, 64);
    if (half == 0) {
        const float4* bp = (const float4*)b;
        float4 bb = bp[l];
        float4 o4;
        o4.x = fmaxf(fmaf(di, acc.x, bb.x), 0.f);
        o4.y = fmaxf(fmaf(di, acc.y, bb.y), 0.f);
        o4.z = fmaxf(fmaf(di, acc.z, bb.z), 0.f);
        o4.w = fmaxf(fmaf(di, acc.w, bb.w), 0.f);
        ((float4*)out)[(size_t)n * 32 + l] = o4;
    }
}

// ---------------- Set2Set LSTM step (step-0 specialized, float4 loads) -------
#define GPB 8
__global__ __launch_bounds__(256) void k_lstm(const float* __restrict__ qstar,
                                              float* __restrict__ h, float* __restrict__ c,
                                              const float* __restrict__ Wih,
                                              const float* __restrict__ Whh,
                                              const float* __restrict__ bih,
                                              const float* __restrict__ bhh,
                                              int first) {
    __shared__ float qs[GPB][256];
    __shared__ float hh[GPB][128];
    __shared__ float gates[GPB][512];
    int g0 = blockIdx.x * GPB;
    int t = threadIdx.x;
    if (!first) {
        for (int i = t; i < GPB * 64; i += 256) {
            int g = i >> 6, k4 = i & 63;
            ((float4*)qs[g])[k4] = ((const float4*)(qstar + (size_t)(g0 + g) * 256))[k4];
        }
        for (int i = t; i < GPB * 32; i += 256) {
            int g = i >> 5, k4 = i & 31;
            ((float4*)hh[g])[k4] = ((const float4*)(h + (size_t)(g0 + g) * 128))[k4];
        }
    }
    __syncthreads();
    for (int jj = 0; jj < 2; jj++) {
        int j = t + jj * 256;
        float base = bih[j] + bhh[j];
        float acc[GPB];
#pragma unroll
        for (int g = 0; g < GPB; g++) acc[g] = base;
        if (!first) {
            const float4* wi4 = (const float4*)(Wih + (size_t)j * 256);
#pragma unroll 4
            for (int k4 = 0; k4 < 64; k4++) {
                float4 w = wi4[k4];
#pragma unroll
                for (int g = 0; g < GPB; g++) {
                    float4 q4 = ((const float4*)qs[g])[k4];
                    acc[g] = fmaf(w.x, q4.x, acc[g]);
                    acc[g] = fmaf(w.y, q4.y, acc[g]);
                    acc[g] = fmaf(w.z, q4.z, acc[g]);
                    acc[g] = fmaf(w.w, q4.w, acc[g]);
                }
            }
            const float4* wh4 = (const float4*)(Whh + (size_t)j * 128);
#pragma unroll 4
            for (int k4 = 0; k4 < 32; k4++) {
                float4 w = wh4[k4];
#pragma unroll
                for (int g = 0; g < GPB; g++) {
                    float4 h4 = ((const float4*)hh[g])[k4];
                    acc[g] = fmaf(w.x, h4.x, acc[g]);
                    acc[g] = fmaf(w.y, h4.y, acc[g]);
                    acc[g] = fmaf(w.z, h4.z, acc[g]);
                    acc[g] = fmaf(w.w, h4.w, acc[g]);
                }
            }
        }
        for (int g = 0; g < GPB; g++) gates[g][j] = acc[g];
    }
    __syncthreads();
    for (int i = t; i < GPB * 128; i += 256) {
        int g = i >> 7, d = i & 127;
        int gg = g0 + g;
        float iv = gates[g][d], fv = gates[g][128 + d];
        float gv = gates[g][256 + d], ov = gates[g][384 + d];
        float si = 1.f / (1.f + expf(-iv));
        float sf = 1.f / (1.f + expf(-fv));
        float so = 1.f / (1.f + expf(-ov));
        float tg = tanhf(gv);
        float cold = first ? 0.f : c[gg * 128 + d];
        float cn = sf * cold + si * tg;
        float hn = so * tanhf(cn);
        c[gg * 128 + d] = cn;
        h[gg * 128 + d] = hn;
    }
}

// ---------------- attention: LDS-cached rows (fallback streams) ----------------
__global__ __launch_bounds__(256) void k_attn(const float* __restrict__ X,
                                              const int* __restrict__ goff,
                                              const float* __restrict__ h,
                                              float* __restrict__ eg,
                                              float* __restrict__ qstar) {
    int b = blockIdx.x;
    int t = threadIdx.x;
    int wv = t >> 6, l = t & 63;
    int n0 = goff[b], n1 = goff[b + 1];
    int cnt = n1 - n0;
    __shared__ float rows[MAXR][128];
    __shared__ float q[128];
    __shared__ float ebuf[MAXR];
    __shared__ float red[256];
    __shared__ float wm[4];
    if (t < 128) q[t] = h[b * 128 + t];
    if (cnt <= MAXR) {
        for (int i = t; i < cnt * 32; i += 256) {
            int r = i >> 5, c4 = i & 31;
            ((float4*)rows[r])[c4] = ((const float4*)(X + (size_t)(n0 + r) * 128))[c4];
        }
        __syncthreads();
        const float2* qp = (const float2*)q;
        float2 q2 = qp[l];
        float mloc = -INFINITY;
        for (int n = wv; n < cnt; n += 4) {
            const float2* xp = (const float2*)rows[n];
            float2 x2 = xp[l];
            float p = x2.x * q2.x + x2.y * q2.y;
#pragma unroll
            for (int o = 32; o > 0; o >>= 1) p += __shfl_xor(p, o, 64);
            if (l == 0) ebuf[n] = p;
            mloc = fmaxf(mloc, p);
        }
        if (l == 0) wm[wv] = mloc;
        __syncthreads();
        float m = fmaxf(fmaxf(wm[0], wm[1]), fmaxf(wm[2], wm[3]));
        if (isinf(m)) m = 0.f;
        float s = 0.f;
        for (int n = t; n < cnt; n += 256) {
            float z = expf(ebuf[n] - m);
            ebuf[n] = z;
            s += z;
        }
        red[t] = s;
        __syncthreads();
        for (int o = 128; o > 0; o >>= 1) {
            if (t < o) red[t] += red[t + o];
            __syncthreads();
        }
        float denom = red[0];
        float inv = (denom > 0.f) ? 1.f / denom : 0.f;
        __syncthreads();
        int g = t >> 7, col = t & 127;
        float acc = 0.f;
        for (int n = g; n < cnt; n += 2) {
            acc = fmaf(ebuf[n] * inv, rows[n][col], acc);
        }
        red[t] = acc;
        __syncthreads();
        if (t < 128) {
            float r = red[t] + red[t + 128];
            qstar[b * 256 + t] = q[t];
            qstar[b * 256 + 128 + t] = r;
        }
    } else {
        __syncthreads();
        const float2* qp = (const float2*)q;
        float2 q2 = qp[l];
        float mloc = -INFINITY;
        for (int n = n0 + wv; n < n1; n += 4) {
            const float2* xp = (const float2*)(X + (size_t)n * 128);
            float2 x2 = xp[l];
            float p = x2.x * q2.x + x2.y * q2.y;
#pragma unroll
            for (int o = 32; o > 0; o >>= 1) p += __shfl_xor(p, o, 64);
            if (l == 0) eg[n] = p;
            mloc = fmaxf(mloc, p);
        }
        if (l == 0) wm[wv] = mloc;
        __syncthreads();
        float m = fmaxf(fmaxf(wm[0], wm[1]), fmaxf(wm[2], wm[3]));
        if (isinf(m)) m = 0.f;
        float s = 0.f;
        for (int n = n0 + t; n < n1; n += 256) {
            float z = expf(eg[n] - m);
            eg[n] = z;
            s += z;
        }
        red[t] = s;
        __syncthreads();
        for (int o = 128; o > 0; o >>= 1) {
            if (t < o) red[t] += red[t + o];
            __syncthreads();
        }
        float denom = red[0];
        float inv = (denom > 0.f) ? 1.f / denom : 0.f;
        __syncthreads();
        int g = t >> 7, col = t & 127;
        float acc = 0.f;
        for (int n = n0 + g; n < n1; n += 2) {
            acc = fmaf(eg[n] * inv, X[(size_t)n * 128 + col], acc);
        }
        red[t] = acc;
        __syncthreads();
        if (t < 128) {
            float r = red[t] + red[t + 128];
            qstar[b * 256 + t] = q[t];
            qstar[b * 256 + 128 + t] = r;
        }
    }
}

// ---------------- final MLP head ----------------
__global__ __launch_bounds__(128) void k_mlp(const float* __restrict__ qstar,
                                             const float* __restrict__ Wl1,
                                             const float* __restrict__ bl1,
                                             const float* __restrict__ Wl2,
                                             const float* __restrict__ bl2,
                                             float* __restrict__ out) {
    int b = blockIdx.x, t = threadIdx.x;
    __shared__ float qs[256];
    __shared__ float hid[128];
    qs[t] = qstar[b * 256 + t];
    qs[128 + t] = qstar[b * 256 + 128 + t];
    __syncthreads();
    float acc = bl1[t];
#pragma unroll 4
    for (int k = 0; k < 256; k++) acc = fmaf(qs[k], Wl1[k * 128 + t], acc);
    hid[t] = fmaxf(acc, 0.f);
    __syncthreads();
    if (t < NUM_CLASSES) {
        float o = bl2[t];
#pragma unroll 4
        for (int k = 0; k < 128; k++) o = fmaf(hid[k], Wl2[k * 10 + t], o);
        out[b * 10 + t] = o;
    }
}

// ---------------- host ----------------

extern "C" void kernel_launch(void* const* d_in, const int* in_sizes, int n_in,
                              void* d_out, int out_size, void* d_ws, size_t ws_size,
                              hipStream_t stream) {
    const float* x    = (const float*)d_in[0];
    const void*  eidx = d_in[1];
    const void*  batr = d_in[2];
    const float* W1   = (const float*)d_in[3];
    const float* b1   = (const float*)d_in[4];
    const float* W2   = (const float*)d_in[5];
    const float* b2   = (const float*)d_in[6];
    const float* Wih  = (const float*)d_in[7];
    const float* Whh  = (const float*)d_in[8];
    const float* bih  = (const float*)d_in[9];
    const float* bhh  = (const float*)d_in[10];
    const float* Wl1  = (const float*)d_in[11];
    const float* bl1  = (const float*)d_in[12];
    const float* Wl2  = (const float*)d_in[13];
    const float* bl2  = (const float*)d_in[14];
    float* out = (float*)d_out;

    char* ws = (char*)d_ws;
    size_t off = 0;
    auto alloc = [&](size_t bytes) {
        size_t r = off;
        off = (off + bytes + 255) & ~(size_t)255;
        return r;
    };
    float* A        = (float*)(ws + alloc((size_t)N_NODES * 128 * 4));
    int*   csr      = (int*)(ws + alloc((size_t)N_EDGES * 4));
    unsigned int* edgebuf = (unsigned int*)(ws + alloc((size_t)2 * N_EDGES * 4));  // pdata+sdata; later Hb
    int*   histg    = (int*)(ws + alloc((size_t)NBLK * NBUK * 4));
    int*   btot     = (int*)(ws + alloc((size_t)NBUK * 4));
    int*   bbase    = (int*)(ws + alloc((size_t)(NBUK + 1) * 4));
    int*   offs     = (int*)(ws + alloc((size_t)(N_NODES + 1) * 4));
    float* dinv     = (float*)(ws + alloc((size_t)N_NODES * 4));
    float* e        = (float*)(ws + alloc((size_t)N_NODES * 4));
    int*   goff     = (int*)(ws + alloc((size_t)(NUM_GRAPHS + 1) * 4));
    float* state    = (float*)(ws + alloc((size_t)(NUM_GRAPHS * 128 * 2 + NUM_GRAPHS * 256) * 4));
    int*   flag     = (int*)(ws + alloc(4));
    if (off > ws_size) return;

    unsigned int* pdata = edgebuf;
    unsigned int* sdata = edgebuf + N_EDGES;
    // bf16 gemm output; aliases edgebuf (dead after k_build).
    unsigned short* Hb = (unsigned short*)edgebuf;

    float* h_lstm = state;
    float* c_lstm = state + NUM_GRAPHS * 128;
    float* qstar  = state + NUM_GRAPHS * 256;

    const int B = 256;
    hipMemsetAsync(flag, 0, 4, stream);
    k_detect<<<(4096 + B - 1) / B, B, 0, stream>>>((const int*)eidx, flag, 4096);
    k_goff<<<(N_NODES + B - 1) / B, B, 0, stream>>>(batr, flag, goff, N_NODES, NUM_GRAPHS);
    // CSR build: block-local counting sort, chunk-ordered adjacency
    k_pack<<<NBLK, 256, 0, stream>>>(eidx, flag, pdata, histg);
    k_colscan<<<NBUK, 256, 0, stream>>>(histg, btot);
    k_scan<<<1, 1024, 0, stream>>>(btot, bbase, NBUK);
    k_place<<<NBLK, 256, 0, stream>>>(pdata, histg, bbase, sdata);
    k_build<<<NBUK, 256, 0, stream>>>(sdata, bbase, btot, dinv, offs, csr);
    // GCN conv 1
    k_gemm64<<<(N_NODES + 63) / 64, 256, 0, stream>>>(x, W1, Hb, N_NODES);
    k_agg<<<(N_NODES + 3) / 4, 256, 0, stream>>>(Hb, dinv, offs, csr, b1, A);
    // GCN conv 2
    k_gemm64<<<(N_NODES + 63) / 64, 256, 0, stream>>>(A, W2, Hb, N_NODES);
    k_agg<<<(N_NODES + 3) / 4, 256, 0, stream>>>(Hb, dinv, offs, csr, b2, A);
    // Set2Set
    for (int s = 0; s < STEPS; s++) {
        k_lstm<<<NUM_GRAPHS / GPB, 256, 0, stream>>>(qstar, h_lstm, c_lstm, Wih, Whh, bih, bhh, s == 0);
        k_attn<<<NUM_GRAPHS, 256, 0, stream>>>(A, goff, h_lstm, e, qstar);
    }
    k_mlp<<<NUM_GRAPHS, 128, 0, stream>>>(qstar, Wl1, bl1, Wl2, bl2, out);
}

// Round 9
// 394.719 us; speedup vs baseline: 1.4299x; 1.0598x over previous
//
#include <hip/hip_runtime.h>
#include <hip/hip_bf16.h>
#include <math.h>

#define N_NODES 50000
#define N_EDGES 1600000
#define NUM_GRAPHS 512
#define HIDDEN 128
#define NUM_CLASSES 10
#define STEPS 3

#define NB_SHIFT 6                      // 64 nodes per bucket
#define NODES_PER_B (1 << NB_SHIFT)
#define NBUK ((N_NODES + NODES_PER_B - 1) / NODES_PER_B)   // 782
#define EPB 8192                        // edges per block in the sort
#define NBLK ((N_EDGES + EPB - 1) / EPB)                   // 196
#define MAXR 144                        // attn LDS row cap (max graph ~132)
#define NCH 7                           // src chunks of 8192 nodes

__device__ inline float bf2f(unsigned short h) {
    union { unsigned int u; float f; } v; v.u = ((unsigned int)h) << 16; return v.f;
}
__device__ inline unsigned short f2bf(float f) {
    union { float f; unsigned int u; } v; v.f = f;
    unsigned int r = (v.u + 0x7FFFu + ((v.u >> 16) & 1u)) >> 16;
    return (unsigned short)r;
}

// ---------------- utility kernels ----------------

// Detect int64 vs int32 storage of index inputs.
__global__ void k_detect(const int* p, int* flag, int npairs) {
    int i = blockIdx.x * blockDim.x + threadIdx.x;
    if (i < npairs) {
        int v = p[2 * i + 1];
        if (v != 0) atomicOr(flag, 1);
    }
}

// batch is sorted: graph start offsets by boundary detection (reads raw dtype).
__global__ void k_goff(const void* batr, const int* flag, int* goff, int n, int ng) {
    int i = blockIdx.x * blockDim.x + threadIdx.x;
    if (i >= n) return;
    bool is32 = (*flag != 0);
    int b = is32 ? ((const int*)batr)[i] : (int)((const long long*)batr)[i];
    int prev = (i == 0) ? -1
             : (is32 ? ((const int*)batr)[i - 1] : (int)((const long long*)batr)[i - 1]);
    for (int g = prev + 1; g <= b; g++) goff[g] = i;
    if (i == n - 1) {
        for (int g = b + 1; g <= ng; g++) goff[g] = n;
    }
}

// Sort pass 1: pack edges + per-block LDS bucket histogram (no global atomics).
__global__ __launch_bounds__(256) void k_pack(const void* eidx, const int* flag,
                                              unsigned int* __restrict__ pdata,
                                              int* __restrict__ histg) {
    __shared__ int lh[NBUK];
    int b = blockIdx.x, t = threadIdx.x;
    for (int i = t; i < NBUK; i += 256) lh[i] = 0;
    __syncthreads();
    int base = b * EPB;
    int end = base + EPB; if (end > N_EDGES) end = N_EDGES;
    bool is32 = (*flag != 0);
    for (int i = base + t; i < end; i += 256) {
        int src, dst;
        if (is32) {
            const int* p = (const int*)eidx;
            src = p[i]; dst = p[N_EDGES + i];
        } else {
            const long long* p = (const long long*)eidx;
            src = (int)p[i]; dst = (int)p[N_EDGES + i];
        }
        pdata[i] = ((unsigned)src << 16) | (unsigned)dst;
        atomicAdd(&lh[dst >> NB_SHIFT], 1);
    }
    __syncthreads();
    for (int i = t; i < NBUK; i += 256) histg[(size_t)b * NBUK + i] = lh[i];
}

// Sort pass 2: per bucket, exclusive scan of counts across blocks + bucket total.
__global__ __launch_bounds__(256) void k_colscan(int* __restrict__ histg,
                                                 int* __restrict__ btot) {
    __shared__ int wsum[4];
    int k = blockIdx.x, t = threadIdx.x;
    int wid = t >> 6, lane = t & 63;
    int v = (t < NBLK) ? histg[(size_t)t * NBUK + k] : 0;
    int x = v;
#pragma unroll
    for (int o = 1; o < 64; o <<= 1) {
        int y = __shfl_up(x, o, 64);
        if (lane >= o) x += y;
    }
    if (lane == 63) wsum[wid] = x;
    __syncthreads();
    int add = 0;
    for (int w = 0; w < wid; w++) add += wsum[w];
    if (t < NBLK) histg[(size_t)t * NBUK + k] = add + x - v;
    if (t == NBLK - 1) btot[k] = add + x;
}

// Single-block exclusive scan via shfl wave-scans (782 buckets).
__global__ __launch_bounds__(1024) void k_scan(const int* cnt, int* offs, int n) {
    __shared__ int wsum[16];
    __shared__ int carry_sh;
    int t = threadIdx.x, wid = t >> 6, lane = t & 63;
    if (t == 0) { carry_sh = 0; offs[0] = 0; }
    __syncthreads();
    for (int base = 0; base < n; base += 1024) {
        int i = base + t;
        int v = (i < n) ? cnt[i] : 0;
        int x = v;
#pragma unroll
        for (int o = 1; o < 64; o <<= 1) {
            int y = __shfl_up(x, o, 64);
            if (lane >= o) x += y;
        }
        if (lane == 63) wsum[wid] = x;
        __syncthreads();
        if (wid == 0 && lane < 16) {
            int w = wsum[lane];
#pragma unroll
            for (int o = 1; o < 16; o <<= 1) {
                int y = __shfl_up(w, o, 16);
                if (lane >= o) w += y;
            }
            wsum[lane] = w;
        }
        __syncthreads();
        int add = carry_sh + (wid > 0 ? wsum[wid - 1] : 0);
        if (i < n) offs[i + 1] = add + x;
        __syncthreads();
        if (t == 0) carry_sh += wsum[15];
        __syncthreads();
    }
}

// Sort pass 3: place packed edges into bucket-contiguous segments.
__global__ __launch_bounds__(256) void k_place(const unsigned int* __restrict__ pdata,
                                               const int* __restrict__ histg,
                                               const int* __restrict__ bbase,
                                               unsigned int* __restrict__ sdata) {
    __shared__ int lh[NBUK];
    __shared__ int lpre[NBUK];
    int b = blockIdx.x, t = threadIdx.x;
    for (int i = t; i < NBUK; i += 256) {
        lh[i] = 0;
        lpre[i] = bbase[i] + histg[(size_t)b * NBUK + i];
    }
    __syncthreads();
    int base = b * EPB;
    int end = base + EPB; if (end > N_EDGES) end = N_EDGES;
    for (int i = base + t; i < end; i += 256) {
        unsigned p = pdata[i];
        int k = (p & 0xFFFFu) >> NB_SHIFT;
        int pos = atomicAdd(&lh[k], 1);
        sdata[lpre[k] + pos] = p;
    }
}

// Fused CSR build per bucket: per-(node,chunk) counts, offs (bbase + wave scan),
// dinv, and chunk-ordered csr placement.
__global__ __launch_bounds__(256) void k_build(const unsigned int* __restrict__ sdata,
                                               const int* __restrict__ bbase,
                                               const int* __restrict__ btot,
                                               float* __restrict__ dinv,
                                               int* __restrict__ offs,
                                               int* __restrict__ csr) {
    __shared__ int lc[NODES_PER_B][8];   // counts, then absolute cursors
    int b = blockIdx.x, t = threadIdx.x;
    for (int i = t; i < NODES_PER_B * 8; i += 256) ((int*)lc)[i] = 0;
    __syncthreads();
    int s0 = bbase[b], n = btot[b];
    const unsigned int* sd = sdata + s0;
    for (int e = t; e < n; e += 256) {
        unsigned p = sd[e];
        atomicAdd(&lc[p & (NODES_PER_B - 1)][(p >> 16) >> 13], 1);
    }
    __syncthreads();
    if (t < NODES_PER_B) {
        int cnts[NCH];
        int deg = 0;
#pragma unroll
        for (int c = 0; c < NCH; c++) { cnts[c] = lc[t][c]; deg += cnts[c]; }
        int x = deg;
#pragma unroll
        for (int o = 1; o < 64; o <<= 1) {
            int y = __shfl_up(x, o, 64);
            if (t >= o) x += y;
        }
        int nodestart = s0 + x - deg;
        int node = b * NODES_PER_B + t;
        if (node < N_NODES) {
            offs[node] = nodestart;
            dinv[node] = rsqrtf((float)(deg + 1));
        }
        int run = nodestart;
#pragma unroll
        for (int c = 0; c < NCH; c++) { lc[t][c] = run; run += cnts[c]; }
    }
    if (b == 0 && t == 255) offs[N_NODES] = N_EDGES;
    __syncthreads();
    for (int e = t; e < n; e += 256) {
        unsigned p = sd[e];
        int src = (int)(p >> 16);
        int pos = atomicAdd(&lc[p & (NODES_PER_B - 1)][src >> 13], 1);
        csr[pos] = src;
    }
}

// ---------------- GEMM: Hb[n][j] = bf16(sum_k X[n][k] * W[k][j]), K=N=128 ----
__global__ __launch_bounds__(256) void k_gemm64(const float* __restrict__ X,
                                                const float* __restrict__ W,
                                                unsigned short* __restrict__ Hb,
                                                int nrows) {
    __shared__ float xs[64][128];
    int t = threadIdx.x;
    int a = t >> 5;          // row group: rows 8a..8a+7
    int j4 = t & 31;         // float4 column group
    int row0 = blockIdx.x * 64;
    for (int i = t; i < 64 * 32; i += 256) {
        int rr = i >> 5;
        int c4 = i & 31;
        int r = row0 + rr; if (r >= nrows) r = nrows - 1;
        ((float4*)xs[rr])[c4] = ((const float4*)X)[(size_t)r * 32 + c4];
    }
    __syncthreads();
    float4 acc[8];
#pragma unroll
    for (int i = 0; i < 8; i++) acc[i] = {0.f, 0.f, 0.f, 0.f};
    const float4* wp = (const float4*)W;
#pragma unroll 2
    for (int k0 = 0; k0 < 128; k0 += 4) {
        float4 w0 = wp[(k0 + 0) * 32 + j4];
        float4 w1 = wp[(k0 + 1) * 32 + j4];
        float4 w2 = wp[(k0 + 2) * 32 + j4];
        float4 w3 = wp[(k0 + 3) * 32 + j4];
#pragma unroll
        for (int i = 0; i < 8; i++) {
            float4 xv = *(const float4*)&xs[8 * a + i][k0];
            acc[i].x = fmaf(xv.x, w0.x, acc[i].x); acc[i].y = fmaf(xv.x, w0.y, acc[i].y);
            acc[i].z = fmaf(xv.x, w0.z, acc[i].z); acc[i].w = fmaf(xv.x, w0.w, acc[i].w);
            acc[i].x = fmaf(xv.y, w1.x, acc[i].x); acc[i].y = fmaf(xv.y, w1.y, acc[i].y);
            acc[i].z = fmaf(xv.y, w1.z, acc[i].z); acc[i].w = fmaf(xv.y, w1.w, acc[i].w);
            acc[i].x = fmaf(xv.z, w2.x, acc[i].x); acc[i].y = fmaf(xv.z, w2.y, acc[i].y);
            acc[i].z = fmaf(xv.z, w2.z, acc[i].z); acc[i].w = fmaf(xv.z, w2.w, acc[i].w);
            acc[i].x = fmaf(xv.w, w3.x, acc[i].x); acc[i].y = fmaf(xv.w, w3.y, acc[i].y);
            acc[i].z = fmaf(xv.w, w3.z, acc[i].z); acc[i].w = fmaf(xv.w, w3.w, acc[i].w);
        }
    }
#pragma unroll
    for (int i = 0; i < 8; i++) {
        int r = row0 + 8 * a + i;
        if (r < nrows) {
            ushort4 b4;
            b4.x = f2bf(acc[i].x); b4.y = f2bf(acc[i].y);
            b4.z = f2bf(acc[i].z); b4.w = f2bf(acc[i].w);
            ((ushort4*)Hb)[(size_t)r * 32 + j4] = b4;
        }
    }
}

// ---------------- GCN aggregate (bf16 rows for self + gather) ----------------
__global__ __launch_bounds__(256) void k_agg(const unsigned short* __restrict__ Hb,
                                             const float* __restrict__ dinv,
                                             const int* __restrict__ offs,
                                             const int* __restrict__ csr,
                                             const float* __restrict__ b,
                                             float* __restrict__ out) {
    int wave = (blockIdx.x * blockDim.x + threadIdx.x) >> 6;
    int lane = threadIdx.x & 63;
    if (wave >= N_NODES) return;
    int n = wave;
    int half = lane >> 5;
    int l = lane & 31;
    float di = dinv[n];
    const ushort4* hbp = (const ushort4*)Hb;
    float4 acc = {0.f, 0.f, 0.f, 0.f};
    if (half == 0) {
        ushort4 hn = hbp[(size_t)n * 32 + l];
        acc.x = di * bf2f(hn.x); acc.y = di * bf2f(hn.y);
        acc.z = di * bf2f(hn.z); acc.w = di * bf2f(hn.w);
    }
    int e0 = offs[n], e1 = offs[n + 1];
    int j = e0 + half;
    for (; j + 14 < e1; j += 16) {
        int s[8]; float ds[8]; ushort4 a[8];
#pragma unroll
        for (int u = 0; u < 8; u++) s[u] = csr[j + 2 * u];
#pragma unroll
        for (int u = 0; u < 8; u++) ds[u] = dinv[s[u]];
#pragma unroll
        for (int u = 0; u < 8; u++) a[u] = hbp[(size_t)s[u] * 32 + l];
#pragma unroll
        for (int u = 0; u < 8; u++) {
            acc.x = fmaf(ds[u], bf2f(a[u].x), acc.x);
            acc.y = fmaf(ds[u], bf2f(a[u].y), acc.y);
            acc.z = fmaf(ds[u], bf2f(a[u].z), acc.z);
            acc.w = fmaf(ds[u], bf2f(a[u].w), acc.w);
        }
    }
    for (; j + 6 < e1; j += 8) {
        int s[4]; float ds[4]; ushort4 a[4];
#pragma unroll
        for (int u = 0; u < 4; u++) s[u] = csr[j + 2 * u];
#pragma unroll
        for (int u = 0; u < 4; u++) ds[u] = dinv[s[u]];
#pragma unroll
        for (int u = 0; u < 4; u++) a[u] = hbp[(size_t)s[u] * 32 + l];
#pragma unroll
        for (int u = 0; u < 4; u++) {
            acc.x = fmaf(ds[u], bf2f(a[u].x), acc.x);
            acc.y = fmaf(ds[u], bf2f(a[u].y), acc.y);
            acc.z = fmaf(ds[u], bf2f(a[u].z), acc.z);
            acc.w = fmaf(ds[u], bf2f(a[u].w), acc.w);
        }
    }
    for (; j < e1; j += 2) {
        int s = csr[j];
        float ds = dinv[s];
        ushort4 hs = hbp[(size_t)s * 32 + l];
        acc.x = fmaf(ds, bf2f(hs.x), acc.x); acc.y = fmaf(ds, bf2f(hs.y), acc.y);
        acc.z = fmaf(ds, bf2f(hs.z), acc.z); acc.w = fmaf(ds, bf2f(hs.w), acc.w);
    }
    acc.x += __shfl_xor(acc.x, 32, 64);
    acc.y += __shfl_xor(acc.y, 32, 64);
    acc.z += __shfl_xor(acc.z, 32, 64);
    acc.w += __shfl_xor(acc.w, 32, 64);
    if (half == 0) {
        const float4* bp = (const float4*)b;
        float4 bb = bp[l];
        float4 o4;
        o4.x = fmaxf(fmaf(di, acc.x, bb.x), 0.f);
        o4.y = fmaxf(fmaf(di, acc.y, bb.y), 0.f);
        o4.z = fmaxf(fmaf(di, acc.z, bb.z), 0.f);
        o4.w = fmaxf(fmaf(di, acc.w, bb.w), 0.f);
        ((float4*)out)[(size_t)n * 32 + l] = o4;
    }
}

// ---------------- LSTM gates GEMM-NT: gates[b][j] = A[b,:]·B[j,:] + bias ------
// A[b][k] = k<256 ? qstar[b][k] : h[b][k-256];  B[j][k] = k<256 ? Wih[j][k] : Whh[j][k-256]
// 64x64 tile / block, grid 8x8; thread owns 4x4.
__global__ __launch_bounds__(256) void k_gates(const float* __restrict__ qstar,
                                               const float* __restrict__ h,
                                               const float* __restrict__ Wih,
                                               const float* __restrict__ Whh,
                                               const float* __restrict__ bih,
                                               const float* __restrict__ bhh,
                                               float* __restrict__ gates) {
    __shared__ float As[64][33];
    __shared__ float Bs[64][33];
    int t = threadIdx.x;
    int tx = t & 15, ty = t >> 4;
    int gb = blockIdx.y * 64;   // graph base
    int jb = blockIdx.x * 64;   // gate base
    float acc[4][4];
#pragma unroll
    for (int i = 0; i < 4; i++)
#pragma unroll
        for (int j = 0; j < 4; j++) acc[i][j] = 0.f;
    for (int k0 = 0; k0 < 384; k0 += 32) {
        for (int i = t; i < 64 * 8; i += 256) {
            int r = i >> 3, c4 = i & 7;
            int k = k0 + c4 * 4;
            const float* srcA = (k < 256) ? (qstar + (size_t)(gb + r) * 256 + k)
                                          : (h + (size_t)(gb + r) * 128 + (k - 256));
            float4 va = *(const float4*)srcA;
            As[r][c4 * 4 + 0] = va.x; As[r][c4 * 4 + 1] = va.y;
            As[r][c4 * 4 + 2] = va.z; As[r][c4 * 4 + 3] = va.w;
            const float* srcB = (k < 256) ? (Wih + (size_t)(jb + r) * 256 + k)
                                          : (Whh + (size_t)(jb + r) * 128 + (k - 256));
            float4 vb = *(const float4*)srcB;
            Bs[r][c4 * 4 + 0] = vb.x; Bs[r][c4 * 4 + 1] = vb.y;
            Bs[r][c4 * 4 + 2] = vb.z; Bs[r][c4 * 4 + 3] = vb.w;
        }
        __syncthreads();
#pragma unroll 8
        for (int kk = 0; kk < 32; kk++) {
            float a[4], b[4];
#pragma unroll
            for (int i = 0; i < 4; i++) a[i] = As[ty * 4 + i][kk];
#pragma unroll
            for (int i = 0; i < 4; i++) b[i] = Bs[tx * 4 + i][kk];
#pragma unroll
            for (int i = 0; i < 4; i++)
#pragma unroll
                for (int j = 0; j < 4; j++) acc[i][j] = fmaf(a[i], b[j], acc[i][j]);
        }
        __syncthreads();
    }
#pragma unroll
    for (int j = 0; j < 4; j++) {
        int jj = jb + tx * 4 + j;
        float bias = bih[jj] + bhh[jj];
#pragma unroll
        for (int i = 0; i < 4; i++) {
            gates[(size_t)(gb + ty * 4 + i) * 512 + jj] = acc[i][j] + bias;
        }
    }
}

// ---------------- LSTM elementwise ----------------
__global__ __launch_bounds__(256) void k_lstmel(const float* __restrict__ gates,
                                                const float* __restrict__ bih,
                                                const float* __restrict__ bhh,
                                                float* __restrict__ h,
                                                float* __restrict__ c,
                                                int first) {
    int i = blockIdx.x * 256 + threadIdx.x;
    if (i >= NUM_GRAPHS * 128) return;
    int b = i >> 7, d = i & 127;
    float iv, fv, gv, ov;
    if (first) {
        iv = bih[d] + bhh[d];
        fv = bih[128 + d] + bhh[128 + d];
        gv = bih[256 + d] + bhh[256 + d];
        ov = bih[384 + d] + bhh[384 + d];
    } else {
        const float* g = gates + (size_t)b * 512;
        iv = g[d]; fv = g[128 + d]; gv = g[256 + d]; ov = g[384 + d];
    }
    float si = 1.f / (1.f + expf(-iv));
    float sf = 1.f / (1.f + expf(-fv));
    float so = 1.f / (1.f + expf(-ov));
    float tg = tanhf(gv);
    float cold = first ? 0.f : c[i];
    float cn = sf * cold + si * tg;
    float hn = so * tanhf(cn);
    c[i] = cn;
    h[i] = hn;
}

// ---------------- attention: LDS-cached rows (fallback streams) ----------------
__global__ __launch_bounds__(256) void k_attn(const float* __restrict__ X,
                                              const int* __restrict__ goff,
                                              const float* __restrict__ h,
                                              float* __restrict__ eg,
                                              float* __restrict__ qstar) {
    int b = blockIdx.x;
    int t = threadIdx.x;
    int wv = t >> 6, l = t & 63;
    int n0 = goff[b], n1 = goff[b + 1];
    int cnt = n1 - n0;
    __shared__ float rows[MAXR][128];
    __shared__ float q[128];
    __shared__ float ebuf[MAXR];
    __shared__ float red[256];
    __shared__ float wm[4];
    if (t < 128) q[t] = h[b * 128 + t];
    if (cnt <= MAXR) {
        for (int i = t; i < cnt * 32; i += 256) {
            int r = i >> 5, c4 = i & 31;
            ((float4*)rows[r])[c4] = ((const float4*)(X + (size_t)(n0 + r) * 128))[c4];
        }
        __syncthreads();
        const float2* qp = (const float2*)q;
        float2 q2 = qp[l];
        float mloc = -INFINITY;
        for (int n = wv; n < cnt; n += 4) {
            const float2* xp = (const float2*)rows[n];
            float2 x2 = xp[l];
            float p = x2.x * q2.x + x2.y * q2.y;
#pragma unroll
            for (int o = 32; o > 0; o >>= 1) p += __shfl_xor(p, o, 64);
            if (l == 0) ebuf[n] = p;
            mloc = fmaxf(mloc, p);
        }
        if (l == 0) wm[wv] = mloc;
        __syncthreads();
        float m = fmaxf(fmaxf(wm[0], wm[1]), fmaxf(wm[2], wm[3]));
        if (isinf(m)) m = 0.f;
        float s = 0.f;
        for (int n = t; n < cnt; n += 256) {
            float z = expf(ebuf[n] - m);
            ebuf[n] = z;
            s += z;
        }
        red[t] = s;
        __syncthreads();
        for (int o = 128; o > 0; o >>= 1) {
            if (t < o) red[t] += red[t + o];
            __syncthreads();
        }
        float denom = red[0];
        float inv = (denom > 0.f) ? 1.f / denom : 0.f;
        __syncthreads();
        int g = t >> 7, col = t & 127;
        float acc = 0.f;
        for (int n = g; n < cnt; n += 2) {
            acc = fmaf(ebuf[n] * inv, rows[n][col], acc);
        }
        red[t] = acc;
        __syncthreads();
        if (t < 128) {
            float r = red[t] + red[t + 128];
            qstar[b * 256 + t] = q[t];
            qstar[b * 256 + 128 + t] = r;
        }
    } else {
        __syncthreads();
        const float2* qp = (const float2*)q;
        float2 q2 = qp[l];
        float mloc = -INFINITY;
        for (int n = n0 + wv; n < n1; n += 4) {
            const float2* xp = (const float2*)(X + (size_t)n * 128);
            float2 x2 = xp[l];
            float p = x2.x * q2.x + x2.y * q2.y;
#pragma unroll
            for (int o = 32; o > 0; o >>= 1) p += __shfl_xor(p, o, 64);
            if (l == 0) eg[n] = p;
            mloc = fmaxf(mloc, p);
        }
        if (l == 0) wm[wv] = mloc;
        __syncthreads();
        float m = fmaxf(fmaxf(wm[0], wm[1]), fmaxf(wm[2], wm[3]));
        if (isinf(m)) m = 0.f;
        float s = 0.f;
        for (int n = n0 + t; n < n1; n += 256) {
            float z = expf(eg[n] - m);
            eg[n] = z;
            s += z;
        }
        red[t] = s;
        __syncthreads();
        for (int o = 128; o > 0; o >>= 1) {
            if (t < o) red[t] += red[t + o];
            __syncthreads();
        }
        float denom = red[0];
        float inv = (denom > 0.f) ? 1.f / denom : 0.f;
        __syncthreads();
        int g = t >> 7, col = t & 127;
        float acc = 0.f;
        for (int n = n0 + g; n < n1; n += 2) {
            acc = fmaf(eg[n] * inv, X[(size_t)n * 128 + col], acc);
        }
        red[t] = acc;
        __syncthreads();
        if (t < 128) {
            float r = red[t] + red[t + 128];
            qstar[b * 256 + t] = q[t];
            qstar[b * 256 + 128 + t] = r;
        }
    }
}

// ---------------- final MLP head ----------------
__global__ __launch_bounds__(128) void k_mlp(const float* __restrict__ qstar,
                                             const float* __restrict__ Wl1,
                                             const float* __restrict__ bl1,
                                             const float* __restrict__ Wl2,
                                             const float* __restrict__ bl2,
                                             float* __restrict__ out) {
    int b = blockIdx.x, t = threadIdx.x;
    __shared__ float qs[256];
    __shared__ float hid[128];
    qs[t] = qstar[b * 256 + t];
    qs[128 + t] = qstar[b * 256 + 128 + t];
    __syncthreads();
    float acc = bl1[t];
#pragma unroll 4
    for (int k = 0; k < 256; k++) acc = fmaf(qs[k], Wl1[k * 128 + t], acc);
    hid[t] = fmaxf(acc, 0.f);
    __syncthreads();
    if (t < NUM_CLASSES) {
        float o = bl2[t];
#pragma unroll 4
        for (int k = 0; k < 128; k++) o = fmaf(hid[k], Wl2[k * 10 + t], o);
        out[b * 10 + t] = o;
    }
}

// ---------------- host ----------------

extern "C" void kernel_launch(void* const* d_in, const int* in_sizes, int n_in,
                              void* d_out, int out_size, void* d_ws, size_t ws_size,
                              hipStream_t stream) {
    const float* x    = (const float*)d_in[0];
    const void*  eidx = d_in[1];
    const void*  batr = d_in[2];
    const float* W1   = (const float*)d_in[3];
    const float* b1   = (const float*)d_in[4];
    const float* W2   = (const float*)d_in[5];
    const float* b2   = (const float*)d_in[6];
    const float* Wih  = (const float*)d_in[7];
    const float* Whh  = (const float*)d_in[8];
    const float* bih  = (const float*)d_in[9];
    const float* bhh  = (const float*)d_in[10];
    const float* Wl1  = (const float*)d_in[11];
    const float* bl1  = (const float*)d_in[12];
    const float* Wl2  = (const float*)d_in[13];
    const float* bl2  = (const float*)d_in[14];
    float* out = (float*)d_out;

    char* ws = (char*)d_ws;
    size_t off = 0;
    auto alloc = [&](size_t bytes) {
        size_t r = off;
        off = (off + bytes + 255) & ~(size_t)255;
        return r;
    };
    float* A        = (float*)(ws + alloc((size_t)N_NODES * 128 * 4));
    int*   csr      = (int*)(ws + alloc((size_t)N_EDGES * 4));
    unsigned int* edgebuf = (unsigned int*)(ws + alloc((size_t)2 * N_EDGES * 4));  // pdata+sdata; later Hb
    int*   histg    = (int*)(ws + alloc((size_t)NBLK * NBUK * 4));
    int*   btot     = (int*)(ws + alloc((size_t)NBUK * 4));
    int*   bbase    = (int*)(ws + alloc((size_t)(NBUK + 1) * 4));
    int*   offs     = (int*)(ws + alloc((size_t)(N_NODES + 1) * 4));
    float* dinv     = (float*)(ws + alloc((size_t)N_NODES * 4));
    float* e        = (float*)(ws + alloc((size_t)N_NODES * 4));
    int*   goff     = (int*)(ws + alloc((size_t)(NUM_GRAPHS + 1) * 4));
    float* state    = (float*)(ws + alloc((size_t)(NUM_GRAPHS * 128 * 2 + NUM_GRAPHS * 256) * 4));
    float* gates    = (float*)(ws + alloc((size_t)NUM_GRAPHS * 512 * 4));
    int*   flag     = (int*)(ws + alloc(4));
    if (off > ws_size) return;

    unsigned int* pdata = edgebuf;
    unsigned int* sdata = edgebuf + N_EDGES;
    // bf16 gemm output; aliases edgebuf (dead after k_build).
    unsigned short* Hb = (unsigned short*)edgebuf;

    float* h_lstm = state;
    float* c_lstm = state + NUM_GRAPHS * 128;
    float* qstar  = state + NUM_GRAPHS * 256;

    const int B = 256;
    hipMemsetAsync(flag, 0, 4, stream);
    k_detect<<<(4096 + B - 1) / B, B, 0, stream>>>((const int*)eidx, flag, 4096);
    k_goff<<<(N_NODES + B - 1) / B, B, 0, stream>>>(batr, flag, goff, N_NODES, NUM_GRAPHS);
    // CSR build: block-local counting sort, chunk-ordered adjacency
    k_pack<<<NBLK, 256, 0, stream>>>(eidx, flag, pdata, histg);
    k_colscan<<<NBUK, 256, 0, stream>>>(histg, btot);
    k_scan<<<1, 1024, 0, stream>>>(btot, bbase, NBUK);
    k_place<<<NBLK, 256, 0, stream>>>(pdata, histg, bbase, sdata);
    k_build<<<NBUK, 256, 0, stream>>>(sdata, bbase, btot, dinv, offs, csr);
    // GCN conv 1
    k_gemm64<<<(N_NODES + 63) / 64, 256, 0, stream>>>(x, W1, Hb, N_NODES);
    k_agg<<<(N_NODES + 3) / 4, 256, 0, stream>>>(Hb, dinv, offs, csr, b1, A);
    // GCN conv 2
    k_gemm64<<<(N_NODES + 63) / 64, 256, 0, stream>>>(A, W2, Hb, N_NODES);
    k_agg<<<(N_NODES + 3) / 4, 256, 0, stream>>>(Hb, dinv, offs, csr, b2, A);
    // Set2Set
    for (int s = 0; s < STEPS; s++) {
        if (s > 0) {
            dim3 gg(8, 8);
            k_gates<<<gg, 256, 0, stream>>>(qstar, h_lstm, Wih, Whh, bih, bhh, gates);
        }
        k_lstmel<<<NUM_GRAPHS * 128 / 256, 256, 0, stream>>>(gates, bih, bhh, h_lstm, c_lstm, s == 0);
        k_attn<<<NUM_GRAPHS, 256, 0, stream>>>(A, goff, h_lstm, e, qstar);
    }
    k_mlp<<<NUM_GRAPHS, 128, 0, stream>>>(qstar, Wl1, bl1, Wl2, bl2, out);
}

// Round 10
// 361.813 us; speedup vs baseline: 1.5599x; 1.0909x over previous
//
#include <hip/hip_runtime.h>
#include <hip/hip_bf16.h>
#include <math.h>

#define N_NODES 50000
#define N_EDGES 1600000
#define NUM_GRAPHS 512
#define HIDDEN 128
#define NUM_CLASSES 10
#define STEPS 3

#define NB_SHIFT 6                      // 64 nodes per bucket
#define NODES_PER_B (1 << NB_SHIFT)
#define NBUK ((N_NODES + NODES_PER_B - 1) / NODES_PER_B)   // 782
#define EPB 8192                        // edges per block in the sort
#define NBLK ((N_EDGES + EPB - 1) / EPB)                   // 196
#define MAXR 144                        // attn LDS row cap (max graph ~132)
#define NCH 7                           // src chunks of 8192 nodes

typedef __attribute__((ext_vector_type(8))) short bf16x8;
typedef __attribute__((ext_vector_type(4))) float f32x4;

__device__ inline float bf2f(unsigned short h) {
    union { unsigned int u; float f; } v; v.u = ((unsigned int)h) << 16; return v.f;
}
__device__ inline unsigned short f2bf(float f) {
    union { float f; unsigned int u; } v; v.f = f;
    unsigned int r = (v.u + 0x7FFFu + ((v.u >> 16) & 1u)) >> 16;
    return (unsigned short)r;
}

// ---------------- utility kernels ----------------

__global__ void k_detect(const int* p, int* flag, int npairs) {
    int i = blockIdx.x * blockDim.x + threadIdx.x;
    if (i < npairs) {
        int v = p[2 * i + 1];
        if (v != 0) atomicOr(flag, 1);
    }
}

__global__ void k_goff(const void* batr, const int* flag, int* goff, int n, int ng) {
    int i = blockIdx.x * blockDim.x + threadIdx.x;
    if (i >= n) return;
    bool is32 = (*flag != 0);
    int b = is32 ? ((const int*)batr)[i] : (int)((const long long*)batr)[i];
    int prev = (i == 0) ? -1
             : (is32 ? ((const int*)batr)[i - 1] : (int)((const long long*)batr)[i - 1]);
    for (int g = prev + 1; g <= b; g++) goff[g] = i;
    if (i == n - 1) {
        for (int g = b + 1; g <= ng; g++) goff[g] = n;
    }
}

// Sort pass 1: pack edges + per-block LDS bucket histogram.
__global__ __launch_bounds__(256) void k_pack(const void* eidx, const int* flag,
                                              unsigned int* __restrict__ pdata,
                                              int* __restrict__ histg) {
    __shared__ int lh[NBUK];
    int b = blockIdx.x, t = threadIdx.x;
    for (int i = t; i < NBUK; i += 256) lh[i] = 0;
    __syncthreads();
    int base = b * EPB;
    int end = base + EPB; if (end > N_EDGES) end = N_EDGES;
    bool is32 = (*flag != 0);
    for (int i = base + t; i < end; i += 256) {
        int src, dst;
        if (is32) {
            const int* p = (const int*)eidx;
            src = p[i]; dst = p[N_EDGES + i];
        } else {
            const long long* p = (const long long*)eidx;
            src = (int)p[i]; dst = (int)p[N_EDGES + i];
        }
        pdata[i] = ((unsigned)src << 16) | (unsigned)dst;
        atomicAdd(&lh[dst >> NB_SHIFT], 1);
    }
    __syncthreads();
    for (int i = t; i < NBUK; i += 256) histg[(size_t)b * NBUK + i] = lh[i];
}

// Sort pass 2: per-bucket exclusive scan across blocks.
__global__ __launch_bounds__(256) void k_colscan(int* __restrict__ histg,
                                                 int* __restrict__ btot) {
    __shared__ int wsum[4];
    int k = blockIdx.x, t = threadIdx.x;
    int wid = t >> 6, lane = t & 63;
    int v = (t < NBLK) ? histg[(size_t)t * NBUK + k] : 0;
    int x = v;
#pragma unroll
    for (int o = 1; o < 64; o <<= 1) {
        int y = __shfl_up(x, o, 64);
        if (lane >= o) x += y;
    }
    if (lane == 63) wsum[wid] = x;
    __syncthreads();
    int add = 0;
    for (int w = 0; w < wid; w++) add += wsum[w];
    if (t < NBLK) histg[(size_t)t * NBUK + k] = add + x - v;
    if (t == NBLK - 1) btot[k] = add + x;
}

__global__ __launch_bounds__(1024) void k_scan(const int* cnt, int* offs, int n) {
    __shared__ int wsum[16];
    __shared__ int carry_sh;
    int t = threadIdx.x, wid = t >> 6, lane = t & 63;
    if (t == 0) { carry_sh = 0; offs[0] = 0; }
    __syncthreads();
    for (int base = 0; base < n; base += 1024) {
        int i = base + t;
        int v = (i < n) ? cnt[i] : 0;
        int x = v;
#pragma unroll
        for (int o = 1; o < 64; o <<= 1) {
            int y = __shfl_up(x, o, 64);
            if (lane >= o) x += y;
        }
        if (lane == 63) wsum[wid] = x;
        __syncthreads();
        if (wid == 0 && lane < 16) {
            int w = wsum[lane];
#pragma unroll
            for (int o = 1; o < 16; o <<= 1) {
                int y = __shfl_up(w, o, 16);
                if (lane >= o) w += y;
            }
            wsum[lane] = w;
        }
        __syncthreads();
        int add = carry_sh + (wid > 0 ? wsum[wid - 1] : 0);
        if (i < n) offs[i + 1] = add + x;
        __syncthreads();
        if (t == 0) carry_sh += wsum[15];
        __syncthreads();
    }
}

// Sort pass 3: place packed edges into bucket-contiguous segments.
__global__ __launch_bounds__(256) void k_place(const unsigned int* __restrict__ pdata,
                                               const int* __restrict__ histg,
                                               const int* __restrict__ bbase,
                                               unsigned int* __restrict__ sdata) {
    __shared__ int lh[NBUK];
    __shared__ int lpre[NBUK];
    int b = blockIdx.x, t = threadIdx.x;
    for (int i = t; i < NBUK; i += 256) {
        lh[i] = 0;
        lpre[i] = bbase[i] + histg[(size_t)b * NBUK + i];
    }
    __syncthreads();
    int base = b * EPB;
    int end = base + EPB; if (end > N_EDGES) end = N_EDGES;
    for (int i = base + t; i < end; i += 256) {
        unsigned p = pdata[i];
        int k = (p & 0xFFFFu) >> NB_SHIFT;
        int pos = atomicAdd(&lh[k], 1);
        sdata[lpre[k] + pos] = p;
    }
}

// Fused CSR build per bucket.
__global__ __launch_bounds__(256) void k_build(const unsigned int* __restrict__ sdata,
                                               const int* __restrict__ bbase,
                                               const int* __restrict__ btot,
                                               float* __restrict__ dinv,
                                               int* __restrict__ offs,
                                               int* __restrict__ csr) {
    __shared__ int lc[NODES_PER_B][8];
    int b = blockIdx.x, t = threadIdx.x;
    for (int i = t; i < NODES_PER_B * 8; i += 256) ((int*)lc)[i] = 0;
    __syncthreads();
    int s0 = bbase[b], n = btot[b];
    const unsigned int* sd = sdata + s0;
    for (int e = t; e < n; e += 256) {
        unsigned p = sd[e];
        atomicAdd(&lc[p & (NODES_PER_B - 1)][(p >> 16) >> 13], 1);
    }
    __syncthreads();
    if (t < NODES_PER_B) {
        int cnts[NCH];
        int deg = 0;
#pragma unroll
        for (int c = 0; c < NCH; c++) { cnts[c] = lc[t][c]; deg += cnts[c]; }
        int x = deg;
#pragma unroll
        for (int o = 1; o < 64; o <<= 1) {
            int y = __shfl_up(x, o, 64);
            if (t >= o) x += y;
        }
        int nodestart = s0 + x - deg;
        int node = b * NODES_PER_B + t;
        if (node < N_NODES) {
            offs[node] = nodestart;
            dinv[node] = rsqrtf((float)(deg + 1));
        }
        int run = nodestart;
#pragma unroll
        for (int c = 0; c < NCH; c++) { lc[t][c] = run; run += cnts[c]; }
    }
    if (b == 0 && t == 255) offs[N_NODES] = N_EDGES;
    __syncthreads();
    for (int e = t; e < n; e += 256) {
        unsigned p = sd[e];
        int src = (int)(p >> 16);
        int pos = atomicAdd(&lc[p & (NODES_PER_B - 1)][src >> 13], 1);
        csr[pos] = src;
    }
}

// ---------------- W convert+transpose: fp32 W[k][j] -> bf16 hi/lo Wt[j][k] ----
__global__ void k_cvtw(const float* __restrict__ W,
                       unsigned short* __restrict__ Wth,
                       unsigned short* __restrict__ Wtl) {
    int i = blockIdx.x * 256 + threadIdx.x;
    if (i >= 128 * 128) return;
    int k = i >> 7, j = i & 127;
    float w = W[i];
    unsigned short h = f2bf(w);
    float lo = w - bf2f(h);
    Wth[j * 128 + k] = h;
    Wtl[j * 128 + k] = f2bf(lo);
}

// ---------------- MFMA GEMM: Hb = bf16(X @ W), split-bf16 exact ----
// 64 rows/block, 4 waves; wave owns 16 rows x 128 cols = 8 col-tiles.
// A from global fp32 (converted hi/lo in-register), B (W^T) staged in LDS
// with XOR-swizzled 16B slots. 3 MFMA per tile: ah*bh + ah*bl + al*bh.
__global__ __launch_bounds__(256) void k_gemm_mfma(const float* __restrict__ X,
                                                   const unsigned short* __restrict__ Wth,
                                                   const unsigned short* __restrict__ Wtl,
                                                   unsigned short* __restrict__ Hb,
                                                   int nrows) {
    __shared__ bf16x8 wh[2048];   // [n=128][k8=16] 16B slots, swizzled
    __shared__ bf16x8 wl[2048];
    int t = threadIdx.x;
    for (int i = t; i < 2048; i += 256) {
        int n = i >> 4;
        int slot = i ^ (n & 7);
        wh[slot] = ((const bf16x8*)Wth)[i];
        wl[slot] = ((const bf16x8*)Wtl)[i];
    }
    __syncthreads();
    int w = t >> 6, l = t & 63;
    int lrow = l & 15, lk = l >> 4;
    int arow = blockIdx.x * 64 + w * 16 + lrow;
    int rr = (arow < nrows) ? arow : nrows - 1;
    const float* xrow = X + (size_t)rr * 128;
    f32x4 acc[8];
#pragma unroll
    for (int nt = 0; nt < 8; nt++) acc[nt] = (f32x4){0.f, 0.f, 0.f, 0.f};
#pragma unroll
    for (int kk = 0; kk < 4; kk++) {
        int k = kk * 32 + lk * 8;
        float4 x0 = *(const float4*)(xrow + k);
        float4 x1 = *(const float4*)(xrow + k + 4);
        float xv[8] = {x0.x, x0.y, x0.z, x0.w, x1.x, x1.y, x1.z, x1.w};
        union { bf16x8 v; unsigned short s[8]; } ah, al;
#pragma unroll
        for (int i = 0; i < 8; i++) {
            unsigned u = __float_as_uint(xv[i]);
            unsigned short hi = (unsigned short)(u >> 16);   // trunc split
            ah.s[i] = hi;
            float lo = xv[i] - __uint_as_float((unsigned)hi << 16);
            al.s[i] = (unsigned short)(__float_as_uint(lo) >> 16);
        }
#pragma unroll
        for (int nt = 0; nt < 8; nt++) {
            int n = nt * 16 + lrow;
            int slot = (n * 16 + kk * 4 + lk) ^ (n & 7);
            bf16x8 bh = wh[slot];
            bf16x8 bl = wl[slot];
            acc[nt] = __builtin_amdgcn_mfma_f32_16x16x32_bf16(ah.v, bh, acc[nt], 0, 0, 0);
            acc[nt] = __builtin_amdgcn_mfma_f32_16x16x32_bf16(ah.v, bl, acc[nt], 0, 0, 0);
            acc[nt] = __builtin_amdgcn_mfma_f32_16x16x32_bf16(al.v, bh, acc[nt], 0, 0, 0);
        }
    }
    // C: row = (lane>>4)*4 + r, col = lane&15 (verified mapping)
    int obase = blockIdx.x * 64 + w * 16 + lk * 4;
#pragma unroll
    for (int r = 0; r < 4; r++) {
        int orow = obase + r;
        if (orow < nrows) {
            unsigned short* dst = Hb + (size_t)orow * 128 + lrow;
#pragma unroll
            for (int nt = 0; nt < 8; nt++) dst[nt * 16] = f2bf(acc[nt][r]);
        }
    }
}

// ---------------- GCN aggregate (bf16 rows for self + gather) ----------------
__global__ __launch_bounds__(256) void k_agg(const unsigned short* __restrict__ Hb,
                                             const float* __restrict__ dinv,
                                             const int* __restrict__ offs,
                                             const int* __restrict__ csr,
                                             const float* __restrict__ b,
                                             float* __restrict__ out) {
    int wave = (blockIdx.x * blockDim.x + threadIdx.x) >> 6;
    int lane = threadIdx.x & 63;
    if (wave >= N_NODES) return;
    int n = wave;
    int half = lane >> 5;
    int l = lane & 31;
    float di = dinv[n];
    const ushort4* hbp = (const ushort4*)Hb;
    float4 acc = {0.f, 0.f, 0.f, 0.f};
    if (half == 0) {
        ushort4 hn = hbp[(size_t)n * 32 + l];
        acc.x = di * bf2f(hn.x); acc.y = di * bf2f(hn.y);
        acc.z = di * bf2f(hn.z); acc.w = di * bf2f(hn.w);
    }
    int e0 = offs[n], e1 = offs[n + 1];
    int j = e0 + half;
    for (; j + 14 < e1; j += 16) {
        int s[8]; float ds[8]; ushort4 a[8];
#pragma unroll
        for (int u = 0; u < 8; u++) s[u] = csr[j + 2 * u];
#pragma unroll
        for (int u = 0; u < 8; u++) ds[u] = dinv[s[u]];
#pragma unroll
        for (int u = 0; u < 8; u++) a[u] = hbp[(size_t)s[u] * 32 + l];
#pragma unroll
        for (int u = 0; u < 8; u++) {
            acc.x = fmaf(ds[u], bf2f(a[u].x), acc.x);
            acc.y = fmaf(ds[u], bf2f(a[u].y), acc.y);
            acc.z = fmaf(ds[u], bf2f(a[u].z), acc.z);
            acc.w = fmaf(ds[u], bf2f(a[u].w), acc.w);
        }
    }
    for (; j + 6 < e1; j += 8) {
        int s[4]; float ds[4]; ushort4 a[4];
#pragma unroll
        for (int u = 0; u < 4; u++) s[u] = csr[j + 2 * u];
#pragma unroll
        for (int u = 0; u < 4; u++) ds[u] = dinv[s[u]];
#pragma unroll
        for (int u = 0; u < 4; u++) a[u] = hbp[(size_t)s[u] * 32 + l];
#pragma unroll
        for (int u = 0; u < 4; u++) {
            acc.x = fmaf(ds[u], bf2f(a[u].x), acc.x);
            acc.y = fmaf(ds[u], bf2f(a[u].y), acc.y);
            acc.z = fmaf(ds[u], bf2f(a[u].z), acc.z);
            acc.w = fmaf(ds[u], bf2f(a[u].w), acc.w);
        }
    }
    for (; j < e1; j += 2) {
        int s = csr[j];
        float ds = dinv[s];
        ushort4 hs = hbp[(size_t)s * 32 + l];
        acc.x = fmaf(ds, bf2f(hs.x), acc.x); acc.y = fmaf(ds, bf2f(hs.y), acc.y);
        acc.z = fmaf(ds, bf2f(hs.z), acc.z); acc.w = fmaf(ds, bf2f(hs.w), acc.w);
    }
    acc.x += __shfl_xor(acc.x, 32, 64);
    acc.y += __shfl_xor(acc.y, 32, 64);
    acc.z += __shfl_xor(acc.z, 32, 64);
    acc.w += __shfl_xor(acc.w, 32, 64);
    if (half == 0) {
        const float4* bp = (const float4*)b;
        float4 bb = bp[l];
        float4 o4;
        o4.x = fmaxf(fmaf(di, acc.x, bb.x), 0.f);
        o4.y = fmaxf(fmaf(di, acc.y, bb.y), 0.f);
        o4.z = fmaxf(fmaf(di, acc.z, bb.z), 0.f);
        o4.w = fmaxf(fmaf(di, acc.w, bb.w), 0.f);
        ((float4*)out)[(size_t)n * 32 + l] = o4;
    }
}

// ---------------- LSTM gates GEMM-NT ----------------
__global__ __launch_bounds__(256) void k_gates(const float* __restrict__ qstar,
                                               const float* __restrict__ h,
                                               const float* __restrict__ Wih,
                                               const float* __restrict__ Whh,
                                               const float* __restrict__ bih,
                                               const float* __restrict__ bhh,
                                               float* __restrict__ gates) {
    __shared__ float As[64][33];
    __shared__ float Bs[64][33];
    int t = threadIdx.x;
    int tx = t & 15, ty = t >> 4;
    int gb = blockIdx.y * 64;
    int jb = blockIdx.x * 64;
    float acc[4][4];
#pragma unroll
    for (int i = 0; i < 4; i++)
#pragma unroll
        for (int j = 0; j < 4; j++) acc[i][j] = 0.f;
    for (int k0 = 0; k0 < 384; k0 += 32) {
        for (int i = t; i < 64 * 8; i += 256) {
            int r = i >> 3, c4 = i & 7;
            int k = k0 + c4 * 4;
            const float* srcA = (k < 256) ? (qstar + (size_t)(gb + r) * 256 + k)
                                          : (h + (size_t)(gb + r) * 128 + (k - 256));
            float4 va = *(const float4*)srcA;
            As[r][c4 * 4 + 0] = va.x; As[r][c4 * 4 + 1] = va.y;
            As[r][c4 * 4 + 2] = va.z; As[r][c4 * 4 + 3] = va.w;
            const float* srcB = (k < 256) ? (Wih + (size_t)(jb + r) * 256 + k)
                                          : (Whh + (size_t)(jb + r) * 128 + (k - 256));
            float4 vb = *(const float4*)srcB;
            Bs[r][c4 * 4 + 0] = vb.x; Bs[r][c4 * 4 + 1] = vb.y;
            Bs[r][c4 * 4 + 2] = vb.z; Bs[r][c4 * 4 + 3] = vb.w;
        }
        __syncthreads();
#pragma unroll 8
        for (int kk = 0; kk < 32; kk++) {
            float a[4], b[4];
#pragma unroll
            for (int i = 0; i < 4; i++) a[i] = As[ty * 4 + i][kk];
#pragma unroll
            for (int i = 0; i < 4; i++) b[i] = Bs[tx * 4 + i][kk];
#pragma unroll
            for (int i = 0; i < 4; i++)
#pragma unroll
                for (int j = 0; j < 4; j++) acc[i][j] = fmaf(a[i], b[j], acc[i][j]);
        }
        __syncthreads();
    }
#pragma unroll
    for (int j = 0; j < 4; j++) {
        int jj = jb + tx * 4 + j;
        float bias = bih[jj] + bhh[jj];
#pragma unroll
        for (int i = 0; i < 4; i++) {
            gates[(size_t)(gb + ty * 4 + i) * 512 + jj] = acc[i][j] + bias;
        }
    }
}

// ---------------- attention with fused LSTM elementwise ----------------
__global__ __launch_bounds__(256) void k_attn(const float* __restrict__ X,
                                              const int* __restrict__ goff,
                                              const float* __restrict__ gates,
                                              const float* __restrict__ bih,
                                              const float* __restrict__ bhh,
                                              float* __restrict__ h,
                                              float* __restrict__ c,
                                              float* __restrict__ eg,
                                              float* __restrict__ qstar,
                                              int first) {
    int b = blockIdx.x;
    int t = threadIdx.x;
    int wv = t >> 6, l = t & 63;
    int n0 = goff[b], n1 = goff[b + 1];
    int cnt = n1 - n0;
    __shared__ float rows[MAXR][128];
    __shared__ float q[128];
    __shared__ float ebuf[MAXR];
    __shared__ float red[256];
    __shared__ float wm[4];
    // fused LSTM elementwise: update c, produce h -> q
    if (t < 128) {
        float iv, fv, gv, ov;
        if (first) {
            iv = bih[t] + bhh[t];
            fv = bih[128 + t] + bhh[128 + t];
            gv = bih[256 + t] + bhh[256 + t];
            ov = bih[384 + t] + bhh[384 + t];
        } else {
            const float* g = gates + (size_t)b * 512;
            iv = g[t]; fv = g[128 + t]; gv = g[256 + t]; ov = g[384 + t];
        }
        float si = 1.f / (1.f + expf(-iv));
        float sf = 1.f / (1.f + expf(-fv));
        float so = 1.f / (1.f + expf(-ov));
        float tg = tanhf(gv);
        float cold = first ? 0.f : c[b * 128 + t];
        float cn = sf * cold + si * tg;
        float hn = so * tanhf(cn);
        c[b * 128 + t] = cn;
        h[b * 128 + t] = hn;
        q[t] = hn;
    }
    if (cnt <= MAXR) {
        for (int i = t; i < cnt * 32; i += 256) {
            int r = i >> 5, c4 = i & 31;
            ((float4*)rows[r])[c4] = ((const float4*)(X + (size_t)(n0 + r) * 128))[c4];
        }
        __syncthreads();
        const float2* qp = (const float2*)q;
        float2 q2 = qp[l];
        float mloc = -INFINITY;
        for (int n = wv; n < cnt; n += 4) {
            const float2* xp = (const float2*)rows[n];
            float2 x2 = xp[l];
            float p = x2.x * q2.x + x2.y * q2.y;
#pragma unroll
            for (int o = 32; o > 0; o >>= 1) p += __shfl_xor(p, o, 64);
            if (l == 0) ebuf[n] = p;
            mloc = fmaxf(mloc, p);
        }
        if (l == 0) wm[wv] = mloc;
        __syncthreads();
        float m = fmaxf(fmaxf(wm[0], wm[1]), fmaxf(wm[2], wm[3]));
        if (isinf(m)) m = 0.f;
        float s = 0.f;
        for (int n = t; n < cnt; n += 256) {
            float z = expf(ebuf[n] - m);
            ebuf[n] = z;
            s += z;
        }
        red[t] = s;
        __syncthreads();
        for (int o = 128; o > 0; o >>= 1) {
            if (t < o) red[t] += red[t + o];
            __syncthreads();
        }
        float denom = red[0];
        float inv = (denom > 0.f) ? 1.f / denom : 0.f;
        __syncthreads();
        int g = t >> 7, col = t & 127;
        float acc = 0.f;
        for (int n = g; n < cnt; n += 2) {
            acc = fmaf(ebuf[n] * inv, rows[n][col], acc);
        }
        red[t] = acc;
        __syncthreads();
        if (t < 128) {
            float r = red[t] + red[t + 128];
            qstar[b * 256 + t] = q[t];
            qstar[b * 256 + 128 + t] = r;
        }
    } else {
        __syncthreads();
        const float2* qp = (const float2*)q;
        float2 q2 = qp[l];
        float mloc = -INFINITY;
        for (int n = n0 + wv; n < n1; n += 4) {
            const float2* xp = (const float2*)(X + (size_t)n * 128);
            float2 x2 = xp[l];
            float p = x2.x * q2.x + x2.y * q2.y;
#pragma unroll
            for (int o = 32; o > 0; o >>= 1) p += __shfl_xor(p, o, 64);
            if (l == 0) eg[n] = p;
            mloc = fmaxf(mloc, p);
        }
        if (l == 0) wm[wv] = mloc;
        __syncthreads();
        float m = fmaxf(fmaxf(wm[0], wm[1]), fmaxf(wm[2], wm[3]));
        if (isinf(m)) m = 0.f;
        float s = 0.f;
        for (int n = n0 + t; n < n1; n += 256) {
            float z = expf(eg[n] - m);
            eg[n] = z;
            s += z;
        }
        red[t] = s;
        __syncthreads();
        for (int o = 128; o > 0; o >>= 1) {
            if (t < o) red[t] += red[t + o];
            __syncthreads();
        }
        float denom = red[0];
        float inv = (denom > 0.f) ? 1.f / denom : 0.f;
        __syncthreads();
        int g = t >> 7, col = t & 127;
        float acc = 0.f;
        for (int n = n0 + g; n < n1; n += 2) {
            acc = fmaf(eg[n] * inv, X[(size_t)n * 128 + col], acc);
        }
        red[t] = acc;
        __syncthreads();
        if (t < 128) {
            float r = red[t] + red[t + 128];
            qstar[b * 256 + t] = q[t];
            qstar[b * 256 + 128 + t] = r;
        }
    }
}

// ---------------- final MLP head ----------------
__global__ __launch_bounds__(128) void k_mlp(const float* __restrict__ qstar,
                                             const float* __restrict__ Wl1,
                                             const float* __restrict__ bl1,
                                             const float* __restrict__ Wl2,
                                             const float* __restrict__ bl2,
                                             float* __restrict__ out) {
    int b = blockIdx.x, t = threadIdx.x;
    __shared__ float qs[256];
    __shared__ float hid[128];
    qs[t] = qstar[b * 256 + t];
    qs[128 + t] = qstar[b * 256 + 128 + t];
    __syncthreads();
    float acc = bl1[t];
#pragma unroll 4
    for (int k = 0; k < 256; k++) acc = fmaf(qs[k], Wl1[k * 128 + t], acc);
    hid[t] = fmaxf(acc, 0.f);
    __syncthreads();
    if (t < NUM_CLASSES) {
        float o = bl2[t];
#pragma unroll 4
        for (int k = 0; k < 128; k++) o = fmaf(hid[k], Wl2[k * 10 + t], o);
        out[b * 10 + t] = o;
    }
}

// ---------------- host ----------------

extern "C" void kernel_launch(void* const* d_in, const int* in_sizes, int n_in,
                              void* d_out, int out_size, void* d_ws, size_t ws_size,
                              hipStream_t stream) {
    const float* x    = (const float*)d_in[0];
    const void*  eidx = d_in[1];
    const void*  batr = d_in[2];
    const float* W1   = (const float*)d_in[3];
    const float* b1   = (const float*)d_in[4];
    const float* W2   = (const float*)d_in[5];
    const float* b2   = (const float*)d_in[6];
    const float* Wih  = (const float*)d_in[7];
    const float* Whh  = (const float*)d_in[8];
    const float* bih  = (const float*)d_in[9];
    const float* bhh  = (const float*)d_in[10];
    const float* Wl1  = (const float*)d_in[11];
    const float* bl1  = (const float*)d_in[12];
    const float* Wl2  = (const float*)d_in[13];
    const float* bl2  = (const float*)d_in[14];
    float* out = (float*)d_out;

    char* ws = (char*)d_ws;
    size_t off = 0;
    auto alloc = [&](size_t bytes) {
        size_t r = off;
        off = (off + bytes + 255) & ~(size_t)255;
        return r;
    };
    float* A        = (float*)(ws + alloc((size_t)N_NODES * 128 * 4));
    int*   csr      = (int*)(ws + alloc((size_t)N_EDGES * 4));
    unsigned int* edgebuf = (unsigned int*)(ws + alloc((size_t)2 * N_EDGES * 4));  // pdata+sdata; later Hb
    int*   histg    = (int*)(ws + alloc((size_t)NBLK * NBUK * 4));
    int*   btot     = (int*)(ws + alloc((size_t)NBUK * 4));
    int*   bbase    = (int*)(ws + alloc((size_t)(NBUK + 1) * 4));
    int*   offs     = (int*)(ws + alloc((size_t)(N_NODES + 1) * 4));
    float* dinv     = (float*)(ws + alloc((size_t)N_NODES * 4));
    float* e        = (float*)(ws + alloc((size_t)N_NODES * 4));
    int*   goff     = (int*)(ws + alloc((size_t)(NUM_GRAPHS + 1) * 4));
    float* state    = (float*)(ws + alloc((size_t)(NUM_GRAPHS * 128 * 2 + NUM_GRAPHS * 256) * 4));
    float* gates    = (float*)(ws + alloc((size_t)NUM_GRAPHS * 512 * 4));
    unsigned short* Wth1 = (unsigned short*)(ws + alloc((size_t)128 * 128 * 2));
    unsigned short* Wtl1 = (unsigned short*)(ws + alloc((size_t)128 * 128 * 2));
    unsigned short* Wth2 = (unsigned short*)(ws + alloc((size_t)128 * 128 * 2));
    unsigned short* Wtl2 = (unsigned short*)(ws + alloc((size_t)128 * 128 * 2));
    int*   flag     = (int*)(ws + alloc(4));
    if (off > ws_size) return;

    unsigned int* pdata = edgebuf;
    unsigned int* sdata = edgebuf + N_EDGES;
    // bf16 gemm output; aliases edgebuf (dead after k_build).
    unsigned short* Hb = (unsigned short*)edgebuf;

    float* h_lstm = state;
    float* c_lstm = state + NUM_GRAPHS * 128;
    float* qstar  = state + NUM_GRAPHS * 256;

    const int B = 256;
    hipMemsetAsync(flag, 0, 4, stream);
    k_detect<<<(4096 + B - 1) / B, B, 0, stream>>>((const int*)eidx, flag, 4096);
    k_goff<<<(N_NODES + B - 1) / B, B, 0, stream>>>(batr, flag, goff, N_NODES, NUM_GRAPHS);
    // CSR build
    k_pack<<<NBLK, 256, 0, stream>>>(eidx, flag, pdata, histg);
    k_colscan<<<NBUK, 256, 0, stream>>>(histg, btot);
    k_scan<<<1, 1024, 0, stream>>>(btot, bbase, NBUK);
    k_place<<<NBLK, 256, 0, stream>>>(pdata, histg, bbase, sdata);
    k_build<<<NBUK, 256, 0, stream>>>(sdata, bbase, btot, dinv, offs, csr);
    // weight conversion
    k_cvtw<<<64, 256, 0, stream>>>(W1, Wth1, Wtl1);
    k_cvtw<<<64, 256, 0, stream>>>(W2, Wth2, Wtl2);
    // GCN conv 1
    k_gemm_mfma<<<(N_NODES + 63) / 64, 256, 0, stream>>>(x, Wth1, Wtl1, Hb, N_NODES);
    k_agg<<<(N_NODES + 3) / 4, 256, 0, stream>>>(Hb, dinv, offs, csr, b1, A);
    // GCN conv 2
    k_gemm_mfma<<<(N_NODES + 63) / 64, 256, 0, stream>>>(A, Wth2, Wtl2, Hb, N_NODES);
    k_agg<<<(N_NODES + 3) / 4, 256, 0, stream>>>(Hb, dinv, offs, csr, b2, A);
    // Set2Set (lstm elementwise fused into attn)
    for (int s = 0; s < STEPS; s++) {
        if (s > 0) {
            dim3 gg(8, 8);
            k_gates<<<gg, 256, 0, stream>>>(qstar, h_lstm, Wih, Whh, bih, bhh, gates);
        }
        k_attn<<<NUM_GRAPHS, 256, 0, stream>>>(A, goff, gates, bih, bhh,
                                               h_lstm, c_lstm, e, qstar, s == 0);
    }
    k_mlp<<<NUM_GRAPHS, 128, 0, stream>>>(qstar, Wl1, bl1, Wl2, bl2, out);
}

// Round 11
// 356.670 us; speedup vs baseline: 1.5824x; 1.0144x over previous
//
#include <hip/hip_runtime.h>
#include <hip/hip_bf16.h>
#include <math.h>

#define N_NODES 50000
#define N_EDGES 1600000
#define NUM_GRAPHS 512
#define HIDDEN 128
#define NUM_CLASSES 10
#define STEPS 3

#define NB_SHIFT 6                      // 64 nodes per bucket
#define NODES_PER_B (1 << NB_SHIFT)
#define NBUK ((N_NODES + NODES_PER_B - 1) / NODES_PER_B)   // 782
#define EPB 8192                        // edges per block in the sort
#define NBLK ((N_EDGES + EPB - 1) / EPB)                   // 196
#define MAXR 144                        // attn LDS row cap (max graph ~132)
#define NCH 7                           // src chunks of 8192 nodes

typedef __attribute__((ext_vector_type(8))) short bf16x8;
typedef __attribute__((ext_vector_type(8))) unsigned short u16x8;
typedef __attribute__((ext_vector_type(4))) float f32x4;

__device__ inline float bf2f(unsigned short h) {
    union { unsigned int u; float f; } v; v.u = ((unsigned int)h) << 16; return v.f;
}
__device__ inline unsigned short f2bf(float f) {
    union { float f; unsigned int u; } v; v.f = f;
    unsigned int r = (v.u + 0x7FFFu + ((v.u >> 16) & 1u)) >> 16;
    return (unsigned short)r;
}

// ---------------- utility kernels ----------------

__global__ void k_detect(const int* p, int* flag, int npairs) {
    int i = blockIdx.x * blockDim.x + threadIdx.x;
    if (i < npairs) {
        int v = p[2 * i + 1];
        if (v != 0) atomicOr(flag, 1);
    }
}

__global__ void k_goff(const void* batr, const int* flag, int* goff, int n, int ng) {
    int i = blockIdx.x * blockDim.x + threadIdx.x;
    if (i >= n) return;
    bool is32 = (*flag != 0);
    int b = is32 ? ((const int*)batr)[i] : (int)((const long long*)batr)[i];
    int prev = (i == 0) ? -1
             : (is32 ? ((const int*)batr)[i - 1] : (int)((const long long*)batr)[i - 1]);
    for (int g = prev + 1; g <= b; g++) goff[g] = i;
    if (i == n - 1) {
        for (int g = b + 1; g <= ng; g++) goff[g] = n;
    }
}

// Sort pass 1: pack edges + per-block LDS bucket histogram.
__global__ __launch_bounds__(256) void k_pack(const void* eidx, const int* flag,
                                              unsigned int* __restrict__ pdata,
                                              int* __restrict__ histg) {
    __shared__ int lh[NBUK];
    int b = blockIdx.x, t = threadIdx.x;
    for (int i = t; i < NBUK; i += 256) lh[i] = 0;
    __syncthreads();
    int base = b * EPB;
    int end = base + EPB; if (end > N_EDGES) end = N_EDGES;
    bool is32 = (*flag != 0);
    for (int i = base + t; i < end; i += 256) {
        int src, dst;
        if (is32) {
            const int* p = (const int*)eidx;
            src = p[i]; dst = p[N_EDGES + i];
        } else {
            const long long* p = (const long long*)eidx;
            src = (int)p[i]; dst = (int)p[N_EDGES + i];
        }
        pdata[i] = ((unsigned)src << 16) | (unsigned)dst;
        atomicAdd(&lh[dst >> NB_SHIFT], 1);
    }
    __syncthreads();
    for (int i = t; i < NBUK; i += 256) histg[(size_t)b * NBUK + i] = lh[i];
}

// Sort pass 2: per-bucket exclusive scan across blocks.
__global__ __launch_bounds__(256) void k_colscan(int* __restrict__ histg,
                                                 int* __restrict__ btot) {
    __shared__ int wsum[4];
    int k = blockIdx.x, t = threadIdx.x;
    int wid = t >> 6, lane = t & 63;
    int v = (t < NBLK) ? histg[(size_t)t * NBUK + k] : 0;
    int x = v;
#pragma unroll
    for (int o = 1; o < 64; o <<= 1) {
        int y = __shfl_up(x, o, 64);
        if (lane >= o) x += y;
    }
    if (lane == 63) wsum[wid] = x;
    __syncthreads();
    int add = 0;
    for (int w = 0; w < wid; w++) add += wsum[w];
    if (t < NBLK) histg[(size_t)t * NBUK + k] = add + x - v;
    if (t == NBLK - 1) btot[k] = add + x;
}

__global__ __launch_bounds__(1024) void k_scan(const int* cnt, int* offs, int n) {
    __shared__ int wsum[16];
    __shared__ int carry_sh;
    int t = threadIdx.x, wid = t >> 6, lane = t & 63;
    if (t == 0) { carry_sh = 0; offs[0] = 0; }
    __syncthreads();
    for (int base = 0; base < n; base += 1024) {
        int i = base + t;
        int v = (i < n) ? cnt[i] : 0;
        int x = v;
#pragma unroll
        for (int o = 1; o < 64; o <<= 1) {
            int y = __shfl_up(x, o, 64);
            if (lane >= o) x += y;
        }
        if (lane == 63) wsum[wid] = x;
        __syncthreads();
        if (wid == 0 && lane < 16) {
            int w = wsum[lane];
#pragma unroll
            for (int o = 1; o < 16; o <<= 1) {
                int y = __shfl_up(w, o, 16);
                if (lane >= o) w += y;
            }
            wsum[lane] = w;
        }
        __syncthreads();
        int add = carry_sh + (wid > 0 ? wsum[wid - 1] : 0);
        if (i < n) offs[i + 1] = add + x;
        __syncthreads();
        if (t == 0) carry_sh += wsum[15];
        __syncthreads();
    }
}

// Sort pass 3: place packed edges into bucket-contiguous segments.
__global__ __launch_bounds__(256) void k_place(const unsigned int* __restrict__ pdata,
                                               const int* __restrict__ histg,
                                               const int* __restrict__ bbase,
                                               unsigned int* __restrict__ sdata) {
    __shared__ int lh[NBUK];
    __shared__ int lpre[NBUK];
    int b = blockIdx.x, t = threadIdx.x;
    for (int i = t; i < NBUK; i += 256) {
        lh[i] = 0;
        lpre[i] = bbase[i] + histg[(size_t)b * NBUK + i];
    }
    __syncthreads();
    int base = b * EPB;
    int end = base + EPB; if (end > N_EDGES) end = N_EDGES;
    for (int i = base + t; i < end; i += 256) {
        unsigned p = pdata[i];
        int k = (p & 0xFFFFu) >> NB_SHIFT;
        int pos = atomicAdd(&lh[k], 1);
        sdata[lpre[k] + pos] = p;
    }
}

// Fused CSR build per bucket (csr stored as ushort: src < 65536).
__global__ __launch_bounds__(256) void k_build(const unsigned int* __restrict__ sdata,
                                               const int* __restrict__ bbase,
                                               const int* __restrict__ btot,
                                               float* __restrict__ dinv,
                                               int* __restrict__ offs,
                                               unsigned short* __restrict__ csr) {
    __shared__ int lc[NODES_PER_B][8];
    int b = blockIdx.x, t = threadIdx.x;
    for (int i = t; i < NODES_PER_B * 8; i += 256) ((int*)lc)[i] = 0;
    __syncthreads();
    int s0 = bbase[b], n = btot[b];
    const unsigned int* sd = sdata + s0;
    for (int e = t; e < n; e += 256) {
        unsigned p = sd[e];
        atomicAdd(&lc[p & (NODES_PER_B - 1)][(p >> 16) >> 13], 1);
    }
    __syncthreads();
    if (t < NODES_PER_B) {
        int cnts[NCH];
        int deg = 0;
#pragma unroll
        for (int c = 0; c < NCH; c++) { cnts[c] = lc[t][c]; deg += cnts[c]; }
        int x = deg;
#pragma unroll
        for (int o = 1; o < 64; o <<= 1) {
            int y = __shfl_up(x, o, 64);
            if (t >= o) x += y;
        }
        int nodestart = s0 + x - deg;
        int node = b * NODES_PER_B + t;
        if (node < N_NODES) {
            offs[node] = nodestart;
            dinv[node] = rsqrtf((float)(deg + 1));
        }
        int run = nodestart;
#pragma unroll
        for (int c = 0; c < NCH; c++) { lc[t][c] = run; run += cnts[c]; }
    }
    if (b == 0 && t == 255) offs[N_NODES] = N_EDGES;
    __syncthreads();
    for (int e = t; e < n; e += 256) {
        unsigned p = sd[e];
        int src = (int)(p >> 16);
        int pos = atomicAdd(&lc[p & (NODES_PER_B - 1)][src >> 13], 1);
        csr[pos] = (unsigned short)src;
    }
}

// ---------------- W convert+transpose: fp32 W[k][j] -> bf16 hi/lo Wt[j][k] ----
__global__ void k_cvtw(const float* __restrict__ W,
                       unsigned short* __restrict__ Wth,
                       unsigned short* __restrict__ Wtl) {
    int i = blockIdx.x * 256 + threadIdx.x;
    if (i >= 128 * 128) return;
    int k = i >> 7, j = i & 127;
    float w = W[i];
    unsigned short h = f2bf(w);
    float lo = w - bf2f(h);
    Wth[j * 128 + k] = h;
    Wtl[j * 128 + k] = f2bf(lo);
}

// ---------------- MFMA GEMM: Hbs[n] = bf16(dinv[n] * (X[n] @ W)) ----
__global__ __launch_bounds__(256) void k_gemm_mfma(const float* __restrict__ X,
                                                   const unsigned short* __restrict__ Wth,
                                                   const unsigned short* __restrict__ Wtl,
                                                   const float* __restrict__ dinv,
                                                   unsigned short* __restrict__ Hb,
                                                   int nrows) {
    __shared__ bf16x8 wh[2048];   // [n=128][k8=16] 16B slots, swizzled
    __shared__ bf16x8 wl[2048];
    int t = threadIdx.x;
    for (int i = t; i < 2048; i += 256) {
        int n = i >> 4;
        int slot = i ^ (n & 7);
        wh[slot] = ((const bf16x8*)Wth)[i];
        wl[slot] = ((const bf16x8*)Wtl)[i];
    }
    __syncthreads();
    int w = t >> 6, l = t & 63;
    int lrow = l & 15, lk = l >> 4;
    int arow = blockIdx.x * 64 + w * 16 + lrow;
    int rr = (arow < nrows) ? arow : nrows - 1;
    const float* xrow = X + (size_t)rr * 128;
    f32x4 acc[8];
#pragma unroll
    for (int nt = 0; nt < 8; nt++) acc[nt] = (f32x4){0.f, 0.f, 0.f, 0.f};
#pragma unroll
    for (int kk = 0; kk < 4; kk++) {
        int k = kk * 32 + lk * 8;
        float4 x0 = *(const float4*)(xrow + k);
        float4 x1 = *(const float4*)(xrow + k + 4);
        float xv[8] = {x0.x, x0.y, x0.z, x0.w, x1.x, x1.y, x1.z, x1.w};
        union { bf16x8 v; unsigned short s[8]; } ah, al;
#pragma unroll
        for (int i = 0; i < 8; i++) {
            unsigned u = __float_as_uint(xv[i]);
            unsigned short hi = (unsigned short)(u >> 16);   // trunc split
            ah.s[i] = hi;
            float lo = xv[i] - __uint_as_float((unsigned)hi << 16);
            al.s[i] = (unsigned short)(__float_as_uint(lo) >> 16);
        }
#pragma unroll
        for (int nt = 0; nt < 8; nt++) {
            int n = nt * 16 + lrow;
            int slot = (n * 16 + kk * 4 + lk) ^ (n & 7);
            bf16x8 bh = wh[slot];
            bf16x8 bl = wl[slot];
            acc[nt] = __builtin_amdgcn_mfma_f32_16x16x32_bf16(ah.v, bh, acc[nt], 0, 0, 0);
            acc[nt] = __builtin_amdgcn_mfma_f32_16x16x32_bf16(ah.v, bl, acc[nt], 0, 0, 0);
            acc[nt] = __builtin_amdgcn_mfma_f32_16x16x32_bf16(al.v, bh, acc[nt], 0, 0, 0);
        }
    }
    // C: row = (lane>>4)*4 + r, col = lane&15; prescale by dinv[row]
    int obase = blockIdx.x * 64 + w * 16 + lk * 4;
#pragma unroll
    for (int r = 0; r < 4; r++) {
        int orow = obase + r;
        if (orow < nrows) {
            float di = dinv[orow];
            unsigned short* dst = Hb + (size_t)orow * 128 + lrow;
#pragma unroll
            for (int nt = 0; nt < 8; nt++) dst[nt * 16] = f2bf(di * acc[nt][r]);
        }
    }
}

// ---------------- GCN aggregate: quarter-wave, prescaled rows, pure adds -----
// out[n] = relu(dinv[n]*(Hbs[n] + sum_e Hbs[s]) + b);  Hbs[v] = bf16(dinv[v]*H[v])
__global__ __launch_bounds__(256) void k_agg(const unsigned short* __restrict__ Hbs,
                                             const float* __restrict__ dinv,
                                             const int* __restrict__ offs,
                                             const unsigned short* __restrict__ csr,
                                             const float* __restrict__ b,
                                             float* __restrict__ out) {
    int wave = (blockIdx.x * blockDim.x + threadIdx.x) >> 6;
    int lane = threadIdx.x & 63;
    if (wave >= N_NODES) return;
    int n = wave;
    int qr = lane >> 4;   // quarter 0..3: edge subgroup
    int l = lane & 15;    // 16B col group (8 bf16)
    const u16x8* hp = (const u16x8*)Hbs;
    float acc[8];
    if (qr == 0) {
        u16x8 hv = hp[(size_t)n * 16 + l];
#pragma unroll
        for (int i = 0; i < 8; i++) acc[i] = bf2f(hv[i]);
    } else {
#pragma unroll
        for (int i = 0; i < 8; i++) acc[i] = 0.f;
    }
    int e0 = offs[n], e1 = offs[n + 1];
    int j = e0 + qr;
    for (; j + 12 < e1; j += 16) {
        int s0 = csr[j], s1 = csr[j + 4], s2 = csr[j + 8], s3 = csr[j + 12];
        u16x8 a0 = hp[(size_t)s0 * 16 + l];
        u16x8 a1 = hp[(size_t)s1 * 16 + l];
        u16x8 a2 = hp[(size_t)s2 * 16 + l];
        u16x8 a3 = hp[(size_t)s3 * 16 + l];
#pragma unroll
        for (int i = 0; i < 8; i++) acc[i] += bf2f(a0[i]);
#pragma unroll
        for (int i = 0; i < 8; i++) acc[i] += bf2f(a1[i]);
#pragma unroll
        for (int i = 0; i < 8; i++) acc[i] += bf2f(a2[i]);
#pragma unroll
        for (int i = 0; i < 8; i++) acc[i] += bf2f(a3[i]);
    }
    for (; j < e1; j += 4) {
        int s = csr[j];
        u16x8 a = hp[(size_t)s * 16 + l];
#pragma unroll
        for (int i = 0; i < 8; i++) acc[i] += bf2f(a[i]);
    }
#pragma unroll
    for (int i = 0; i < 8; i++) {
        acc[i] += __shfl_xor(acc[i], 16, 64);
        acc[i] += __shfl_xor(acc[i], 32, 64);
    }
    if (qr == 0) {
        float di = dinv[n];
        float4 b0 = *(const float4*)(b + l * 8);
        float4 b1 = *(const float4*)(b + l * 8 + 4);
        float4 o0, o1;
        o0.x = fmaxf(fmaf(di, acc[0], b0.x), 0.f);
        o0.y = fmaxf(fmaf(di, acc[1], b0.y), 0.f);
        o0.z = fmaxf(fmaf(di, acc[2], b0.z), 0.f);
        o0.w = fmaxf(fmaf(di, acc[3], b0.w), 0.f);
        o1.x = fmaxf(fmaf(di, acc[4], b1.x), 0.f);
        o1.y = fmaxf(fmaf(di, acc[5], b1.y), 0.f);
        o1.z = fmaxf(fmaf(di, acc[6], b1.z), 0.f);
        o1.w = fmaxf(fmaf(di, acc[7], b1.w), 0.f);
        float* dst = out + (size_t)n * 128 + l * 8;
        *(float4*)dst = o0;
        *(float4*)(dst + 4) = o1;
    }
}

// ---------------- LSTM gates GEMM-NT ----------------
__global__ __launch_bounds__(256) void k_gates(const float* __restrict__ qstar,
                                               const float* __restrict__ h,
                                               const float* __restrict__ Wih,
                                               const float* __restrict__ Whh,
                                               const float* __restrict__ bih,
                                               const float* __restrict__ bhh,
                                               float* __restrict__ gates) {
    __shared__ float As[64][33];
    __shared__ float Bs[64][33];
    int t = threadIdx.x;
    int tx = t & 15, ty = t >> 4;
    int gb = blockIdx.y * 64;
    int jb = blockIdx.x * 64;
    float acc[4][4];
#pragma unroll
    for (int i = 0; i < 4; i++)
#pragma unroll
        for (int j = 0; j < 4; j++) acc[i][j] = 0.f;
    for (int k0 = 0; k0 < 384; k0 += 32) {
        for (int i = t; i < 64 * 8; i += 256) {
            int r = i >> 3, c4 = i & 7;
            int k = k0 + c4 * 4;
            const float* srcA = (k < 256) ? (qstar + (size_t)(gb + r) * 256 + k)
                                          : (h + (size_t)(gb + r) * 128 + (k - 256));
            float4 va = *(const float4*)srcA;
            As[r][c4 * 4 + 0] = va.x; As[r][c4 * 4 + 1] = va.y;
            As[r][c4 * 4 + 2] = va.z; As[r][c4 * 4 + 3] = va.w;
            const float* srcB = (k < 256) ? (Wih + (size_t)(jb + r) * 256 + k)
                                          : (Whh + (size_t)(jb + r) * 128 + (k - 256));
            float4 vb = *(const float4*)srcB;
            Bs[r][c4 * 4 + 0] = vb.x; Bs[r][c4 * 4 + 1] = vb.y;
            Bs[r][c4 * 4 + 2] = vb.z; Bs[r][c4 * 4 + 3] = vb.w;
        }
        __syncthreads();
#pragma unroll 8
        for (int kk = 0; kk < 32; kk++) {
            float a[4], b[4];
#pragma unroll
            for (int i = 0; i < 4; i++) a[i] = As[ty * 4 + i][kk];
#pragma unroll
            for (int i = 0; i < 4; i++) b[i] = Bs[tx * 4 + i][kk];
#pragma unroll
            for (int i = 0; i < 4; i++)
#pragma unroll
                for (int j = 0; j < 4; j++) acc[i][j] = fmaf(a[i], b[j], acc[i][j]);
        }
        __syncthreads();
    }
#pragma unroll
    for (int j = 0; j < 4; j++) {
        int jj = jb + tx * 4 + j;
        float bias = bih[jj] + bhh[jj];
#pragma unroll
        for (int i = 0; i < 4; i++) {
            gates[(size_t)(gb + ty * 4 + i) * 512 + jj] = acc[i][j] + bias;
        }
    }
}

// ---------------- attention with fused LSTM elementwise ----------------
__global__ __launch_bounds__(256) void k_attn(const float* __restrict__ X,
                                              const int* __restrict__ goff,
                                              const float* __restrict__ gates,
                                              const float* __restrict__ bih,
                                              const float* __restrict__ bhh,
                                              float* __restrict__ h,
                                              float* __restrict__ c,
                                              float* __restrict__ eg,
                                              float* __restrict__ qstar,
                                              int first) {
    int b = blockIdx.x;
    int t = threadIdx.x;
    int wv = t >> 6, l = t & 63;
    int n0 = goff[b], n1 = goff[b + 1];
    int cnt = n1 - n0;
    __shared__ float rows[MAXR][128];
    __shared__ float q[128];
    __shared__ float ebuf[MAXR];
    __shared__ float red[256];
    __shared__ float wm[4];
    if (t < 128) {
        float iv, fv, gv, ov;
        if (first) {
            iv = bih[t] + bhh[t];
            fv = bih[128 + t] + bhh[128 + t];
            gv = bih[256 + t] + bhh[256 + t];
            ov = bih[384 + t] + bhh[384 + t];
        } else {
            const float* g = gates + (size_t)b * 512;
            iv = g[t]; fv = g[128 + t]; gv = g[256 + t]; ov = g[384 + t];
        }
        float si = 1.f / (1.f + expf(-iv));
        float sf = 1.f / (1.f + expf(-fv));
        float so = 1.f / (1.f + expf(-ov));
        float tg = tanhf(gv);
        float cold = first ? 0.f : c[b * 128 + t];
        float cn = sf * cold + si * tg;
        float hn = so * tanhf(cn);
        c[b * 128 + t] = cn;
        h[b * 128 + t] = hn;
        q[t] = hn;
    }
    if (cnt <= MAXR) {
        for (int i = t; i < cnt * 32; i += 256) {
            int r = i >> 5, c4 = i & 31;
            ((float4*)rows[r])[c4] = ((const float4*)(X + (size_t)(n0 + r) * 128))[c4];
        }
        __syncthreads();
        const float2* qp = (const float2*)q;
        float2 q2 = qp[l];
        float mloc = -INFINITY;
        for (int n = wv; n < cnt; n += 4) {
            const float2* xp = (const float2*)rows[n];
            float2 x2 = xp[l];
            float p = x2.x * q2.x + x2.y * q2.y;
#pragma unroll
            for (int o = 32; o > 0; o >>= 1) p += __shfl_xor(p, o, 64);
            if (l == 0) ebuf[n] = p;
            mloc = fmaxf(mloc, p);
        }
        if (l == 0) wm[wv] = mloc;
        __syncthreads();
        float m = fmaxf(fmaxf(wm[0], wm[1]), fmaxf(wm[2], wm[3]));
        if (isinf(m)) m = 0.f;
        float s = 0.f;
        for (int n = t; n < cnt; n += 256) {
            float z = expf(ebuf[n] - m);
            ebuf[n] = z;
            s += z;
        }
        red[t] = s;
        __syncthreads();
        for (int o = 128; o > 0; o >>= 1) {
            if (t < o) red[t] += red[t + o];
            __syncthreads();
        }
        float denom = red[0];
        float inv = (denom > 0.f) ? 1.f / denom : 0.f;
        __syncthreads();
        int g = t >> 7, col = t & 127;
        float acc = 0.f;
        for (int n = g; n < cnt; n += 2) {
            acc = fmaf(ebuf[n] * inv, rows[n][col], acc);
        }
        red[t] = acc;
        __syncthreads();
        if (t < 128) {
            float r = red[t] + red[t + 128];
            qstar[b * 256 + t] = q[t];
            qstar[b * 256 + 128 + t] = r;
        }
    } else {
        __syncthreads();
        const float2* qp = (const float2*)q;
        float2 q2 = qp[l];
        float mloc = -INFINITY;
        for (int n = n0 + wv; n < n1; n += 4) {
            const float2* xp = (const float2*)(X + (size_t)n * 128);
            float2 x2 = xp[l];
            float p = x2.x * q2.x + x2.y * q2.y;
#pragma unroll
            for (int o = 32; o > 0; o >>= 1) p += __shfl_xor(p, o, 64);
            if (l == 0) eg[n] = p;
            mloc = fmaxf(mloc, p);
        }
        if (l == 0) wm[wv] = mloc;
        __syncthreads();
        float m = fmaxf(fmaxf(wm[0], wm[1]), fmaxf(wm[2], wm[3]));
        if (isinf(m)) m = 0.f;
        float s = 0.f;
        for (int n = n0 + t; n < n1; n += 256) {
            float z = expf(eg[n] - m);
            eg[n] = z;
            s += z;
        }
        red[t] = s;
        __syncthreads();
        for (int o = 128; o > 0; o >>= 1) {
            if (t < o) red[t] += red[t + o];
            __syncthreads();
        }
        float denom = red[0];
        float inv = (denom > 0.f) ? 1.f / denom : 0.f;
        __syncthreads();
        int g = t >> 7, col = t & 127;
        float acc = 0.f;
        for (int n = n0 + g; n < n1; n += 2) {
            acc = fmaf(eg[n] * inv, X[(size_t)n * 128 + col], acc);
        }
        red[t] = acc;
        __syncthreads();
        if (t < 128) {
            float r = red[t] + red[t + 128];
            qstar[b * 256 + t] = q[t];
            qstar[b * 256 + 128 + t] = r;
        }
    }
}

// ---------------- final MLP head ----------------
__global__ __launch_bounds__(128) void k_mlp(const float* __restrict__ qstar,
                                             const float* __restrict__ Wl1,
                                             const float* __restrict__ bl1,
                                             const float* __restrict__ Wl2,
                                             const float* __restrict__ bl2,
                                             float* __restrict__ out) {
    int b = blockIdx.x, t = threadIdx.x;
    __shared__ float qs[256];
    __shared__ float hid[128];
    qs[t] = qstar[b * 256 + t];
    qs[128 + t] = qstar[b * 256 + 128 + t];
    __syncthreads();
    float acc = bl1[t];
#pragma unroll 4
    for (int k = 0; k < 256; k++) acc = fmaf(qs[k], Wl1[k * 128 + t], acc);
    hid[t] = fmaxf(acc, 0.f);
    __syncthreads();
    if (t < NUM_CLASSES) {
        float o = bl2[t];
#pragma unroll 4
        for (int k = 0; k < 128; k++) o = fmaf(hid[k], Wl2[k * 10 + t], o);
        out[b * 10 + t] = o;
    }
}

// ---------------- host ----------------

extern "C" void kernel_launch(void* const* d_in, const int* in_sizes, int n_in,
                              void* d_out, int out_size, void* d_ws, size_t ws_size,
                              hipStream_t stream) {
    const float* x    = (const float*)d_in[0];
    const void*  eidx = d_in[1];
    const void*  batr = d_in[2];
    const float* W1   = (const float*)d_in[3];
    const float* b1   = (const float*)d_in[4];
    const float* W2   = (const float*)d_in[5];
    const float* b2   = (const float*)d_in[6];
    const float* Wih  = (const float*)d_in[7];
    const float* Whh  = (const float*)d_in[8];
    const float* bih  = (const float*)d_in[9];
    const float* bhh  = (const float*)d_in[10];
    const float* Wl1  = (const float*)d_in[11];
    const float* bl1  = (const float*)d_in[12];
    const float* Wl2  = (const float*)d_in[13];
    const float* bl2  = (const float*)d_in[14];
    float* out = (float*)d_out;

    char* ws = (char*)d_ws;
    size_t off = 0;
    auto alloc = [&](size_t bytes) {
        size_t r = off;
        off = (off + bytes + 255) & ~(size_t)255;
        return r;
    };
    float* A        = (float*)(ws + alloc((size_t)N_NODES * 128 * 4));
    unsigned short* csr = (unsigned short*)(ws + alloc((size_t)N_EDGES * 2));
    unsigned int* edgebuf = (unsigned int*)(ws + alloc((size_t)2 * N_EDGES * 4));  // pdata+sdata; later Hbs
    int*   histg    = (int*)(ws + alloc((size_t)NBLK * NBUK * 4));
    int*   btot     = (int*)(ws + alloc((size_t)NBUK * 4));
    int*   bbase    = (int*)(ws + alloc((size_t)(NBUK + 1) * 4));
    int*   offs     = (int*)(ws + alloc((size_t)(N_NODES + 1) * 4));
    float* dinv     = (float*)(ws + alloc((size_t)N_NODES * 4));
    float* e        = (float*)(ws + alloc((size_t)N_NODES * 4));
    int*   goff     = (int*)(ws + alloc((size_t)(NUM_GRAPHS + 1) * 4));
    float* state    = (float*)(ws + alloc((size_t)(NUM_GRAPHS * 128 * 2 + NUM_GRAPHS * 256) * 4));
    float* gates    = (float*)(ws + alloc((size_t)NUM_GRAPHS * 512 * 4));
    unsigned short* Wth1 = (unsigned short*)(ws + alloc((size_t)128 * 128 * 2));
    unsigned short* Wtl1 = (unsigned short*)(ws + alloc((size_t)128 * 128 * 2));
    unsigned short* Wth2 = (unsigned short*)(ws + alloc((size_t)128 * 128 * 2));
    unsigned short* Wtl2 = (unsigned short*)(ws + alloc((size_t)128 * 128 * 2));
    int*   flag     = (int*)(ws + alloc(4));
    if (off > ws_size) return;

    unsigned int* pdata = edgebuf;
    unsigned int* sdata = edgebuf + N_EDGES;
    // bf16 prescaled gemm output; aliases edgebuf (dead after k_build).
    unsigned short* Hbs = (unsigned short*)edgebuf;

    float* h_lstm = state;
    float* c_lstm = state + NUM_GRAPHS * 128;
    float* qstar  = state + NUM_GRAPHS * 256;

    const int B = 256;
    hipMemsetAsync(flag, 0, 4, stream);
    k_detect<<<(4096 + B - 1) / B, B, 0, stream>>>((const int*)eidx, flag, 4096);
    k_goff<<<(N_NODES + B - 1) / B, B, 0, stream>>>(batr, flag, goff, N_NODES, NUM_GRAPHS);
    // CSR build
    k_pack<<<NBLK, 256, 0, stream>>>(eidx, flag, pdata, histg);
    k_colscan<<<NBUK, 256, 0, stream>>>(histg, btot);
    k_scan<<<1, 1024, 0, stream>>>(btot, bbase, NBUK);
    k_place<<<NBLK, 256, 0, stream>>>(pdata, histg, bbase, sdata);
    k_build<<<NBUK, 256, 0, stream>>>(sdata, bbase, btot, dinv, offs, csr);
    // weight conversion
    k_cvtw<<<64, 256, 0, stream>>>(W1, Wth1, Wtl1);
    k_cvtw<<<64, 256, 0, stream>>>(W2, Wth2, Wtl2);
    // GCN conv 1
    k_gemm_mfma<<<(N_NODES + 63) / 64, 256, 0, stream>>>(x, Wth1, Wtl1, dinv, Hbs, N_NODES);
    k_agg<<<(N_NODES + 3) / 4, 256, 0, stream>>>(Hbs, dinv, offs, csr, b1, A);
    // GCN conv 2
    k_gemm_mfma<<<(N_NODES + 63) / 64, 256, 0, stream>>>(A, Wth2, Wtl2, dinv, Hbs, N_NODES);
    k_agg<<<(N_NODES + 3) / 4, 256, 0, stream>>>(Hbs, dinv, offs, csr, b2, A);
    // Set2Set (lstm elementwise fused into attn)
    for (int s = 0; s < STEPS; s++) {
        if (s > 0) {
            dim3 gg(8, 8);
            k_gates<<<gg, 256, 0, stream>>>(qstar, h_lstm, Wih, Whh, bih, bhh, gates);
        }
        k_attn<<<NUM_GRAPHS, 256, 0, stream>>>(A, goff, gates, bih, bhh,
                                               h_lstm, c_lstm, e, qstar, s == 0);
    }
    k_mlp<<<NUM_GRAPHS, 128, 0, stream>>>(qstar, Wl1, bl1, Wl2, bl2, out);
}

// Round 12
// 350.040 us; speedup vs baseline: 1.6124x; 1.0189x over previous
//
#include <hip/hip_runtime.h>
#include <hip/hip_bf16.h>
#include <math.h>

#define N_NODES 50000
#define N_EDGES 1600000
#define NUM_GRAPHS 512
#define HIDDEN 128
#define NUM_CLASSES 10
#define STEPS 3

#define NB_SHIFT 6                      // 64 nodes per bucket
#define NODES_PER_B (1 << NB_SHIFT)
#define NBUK ((N_NODES + NODES_PER_B - 1) / NODES_PER_B)   // 782
#define EPB 8192                        // edges per block in the sort
#define NBLK ((N_EDGES + EPB - 1) / EPB)                   // 196
#define MAXR 144                        // attn LDS row cap (max graph ~132)
#define NCH 7                           // src chunks of 8192 nodes

typedef __attribute__((ext_vector_type(8))) short bf16x8;
typedef __attribute__((ext_vector_type(4))) unsigned int u32x4;
typedef __attribute__((ext_vector_type(4))) float f32x4;

__device__ inline float bf2f(unsigned short h) {
    union { unsigned int u; float f; } v; v.u = ((unsigned int)h) << 16; return v.f;
}
__device__ inline unsigned short f2bf(float f) {
    union { float f; unsigned int u; } v; v.f = f;
    unsigned int r = (v.u + 0x7FFFu + ((v.u >> 16) & 1u)) >> 16;
    return (unsigned short)r;
}

// ---------------- utility kernels ----------------

__global__ void k_detect(const int* p, int* flag, int npairs) {
    int i = blockIdx.x * blockDim.x + threadIdx.x;
    if (i < npairs) {
        int v = p[2 * i + 1];
        if (v != 0) atomicOr(flag, 1);
    }
}

__global__ void k_goff(const void* batr, const int* flag, int* goff, int n, int ng) {
    int i = blockIdx.x * blockDim.x + threadIdx.x;
    if (i >= n) return;
    bool is32 = (*flag != 0);
    int b = is32 ? ((const int*)batr)[i] : (int)((const long long*)batr)[i];
    int prev = (i == 0) ? -1
             : (is32 ? ((const int*)batr)[i - 1] : (int)((const long long*)batr)[i - 1]);
    for (int g = prev + 1; g <= b; g++) goff[g] = i;
    if (i == n - 1) {
        for (int g = b + 1; g <= ng; g++) goff[g] = n;
    }
}

// Sort pass 1: pack edges + per-block LDS bucket histogram.
__global__ __launch_bounds__(256) void k_pack(const void* eidx, const int* flag,
                                              unsigned int* __restrict__ pdata,
                                              int* __restrict__ histg) {
    __shared__ int lh[NBUK];
    int b = blockIdx.x, t = threadIdx.x;
    for (int i = t; i < NBUK; i += 256) lh[i] = 0;
    __syncthreads();
    int base = b * EPB;
    int end = base + EPB; if (end > N_EDGES) end = N_EDGES;
    bool is32 = (*flag != 0);
    for (int i = base + t; i < end; i += 256) {
        int src, dst;
        if (is32) {
            const int* p = (const int*)eidx;
            src = p[i]; dst = p[N_EDGES + i];
        } else {
            const long long* p = (const long long*)eidx;
            src = (int)p[i]; dst = (int)p[N_EDGES + i];
        }
        pdata[i] = ((unsigned)src << 16) | (unsigned)dst;
        atomicAdd(&lh[dst >> NB_SHIFT], 1);
    }
    __syncthreads();
    for (int i = t; i < NBUK; i += 256) histg[(size_t)b * NBUK + i] = lh[i];
}

// Sort pass 2: per-bucket exclusive scan across blocks.
__global__ __launch_bounds__(256) void k_colscan(int* __restrict__ histg,
                                                 int* __restrict__ btot) {
    __shared__ int wsum[4];
    int k = blockIdx.x, t = threadIdx.x;
    int wid = t >> 6, lane = t & 63;
    int v = (t < NBLK) ? histg[(size_t)t * NBUK + k] : 0;
    int x = v;
#pragma unroll
    for (int o = 1; o < 64; o <<= 1) {
        int y = __shfl_up(x, o, 64);
        if (lane >= o) x += y;
    }
    if (lane == 63) wsum[wid] = x;
    __syncthreads();
    int add = 0;
    for (int w = 0; w < wid; w++) add += wsum[w];
    if (t < NBLK) histg[(size_t)t * NBUK + k] = add + x - v;
    if (t == NBLK - 1) btot[k] = add + x;
}

__global__ __launch_bounds__(1024) void k_scan(const int* cnt, int* offs, int n) {
    __shared__ int wsum[16];
    __shared__ int carry_sh;
    int t = threadIdx.x, wid = t >> 6, lane = t & 63;
    if (t == 0) { carry_sh = 0; offs[0] = 0; }
    __syncthreads();
    for (int base = 0; base < n; base += 1024) {
        int i = base + t;
        int v = (i < n) ? cnt[i] : 0;
        int x = v;
#pragma unroll
        for (int o = 1; o < 64; o <<= 1) {
            int y = __shfl_up(x, o, 64);
            if (lane >= o) x += y;
        }
        if (lane == 63) wsum[wid] = x;
        __syncthreads();
        if (wid == 0 && lane < 16) {
            int w = wsum[lane];
#pragma unroll
            for (int o = 1; o < 16; o <<= 1) {
                int y = __shfl_up(w, o, 16);
                if (lane >= o) w += y;
            }
            wsum[lane] = w;
        }
        __syncthreads();
        int add = carry_sh + (wid > 0 ? wsum[wid - 1] : 0);
        if (i < n) offs[i + 1] = add + x;
        __syncthreads();
        if (t == 0) carry_sh += wsum[15];
        __syncthreads();
    }
}

// Sort pass 3: place packed edges into bucket-contiguous segments.
__global__ __launch_bounds__(256) void k_place(const unsigned int* __restrict__ pdata,
                                               const int* __restrict__ histg,
                                               const int* __restrict__ bbase,
                                               unsigned int* __restrict__ sdata) {
    __shared__ int lh[NBUK];
    __shared__ int lpre[NBUK];
    int b = blockIdx.x, t = threadIdx.x;
    for (int i = t; i < NBUK; i += 256) {
        lh[i] = 0;
        lpre[i] = bbase[i] + histg[(size_t)b * NBUK + i];
    }
    __syncthreads();
    int base = b * EPB;
    int end = base + EPB; if (end > N_EDGES) end = N_EDGES;
    for (int i = base + t; i < end; i += 256) {
        unsigned p = pdata[i];
        int k = (p & 0xFFFFu) >> NB_SHIFT;
        int pos = atomicAdd(&lh[k], 1);
        sdata[lpre[k] + pos] = p;
    }
}

// Fused CSR build per bucket (csr stored as ushort: src < 65536).
__global__ __launch_bounds__(256) void k_build(const unsigned int* __restrict__ sdata,
                                               const int* __restrict__ bbase,
                                               const int* __restrict__ btot,
                                               float* __restrict__ dinv,
                                               int* __restrict__ offs,
                                               unsigned short* __restrict__ csr) {
    __shared__ int lc[NODES_PER_B][8];
    int b = blockIdx.x, t = threadIdx.x;
    for (int i = t; i < NODES_PER_B * 8; i += 256) ((int*)lc)[i] = 0;
    __syncthreads();
    int s0 = bbase[b], n = btot[b];
    const unsigned int* sd = sdata + s0;
    for (int e = t; e < n; e += 256) {
        unsigned p = sd[e];
        atomicAdd(&lc[p & (NODES_PER_B - 1)][(p >> 16) >> 13], 1);
    }
    __syncthreads();
    if (t < NODES_PER_B) {
        int cnts[NCH];
        int deg = 0;
#pragma unroll
        for (int c = 0; c < NCH; c++) { cnts[c] = lc[t][c]; deg += cnts[c]; }
        int x = deg;
#pragma unroll
        for (int o = 1; o < 64; o <<= 1) {
            int y = __shfl_up(x, o, 64);
            if (t >= o) x += y;
        }
        int nodestart = s0 + x - deg;
        int node = b * NODES_PER_B + t;
        if (node < N_NODES) {
            offs[node] = nodestart;
            dinv[node] = rsqrtf((float)(deg + 1));
        }
        int run = nodestart;
#pragma unroll
        for (int c = 0; c < NCH; c++) { lc[t][c] = run; run += cnts[c]; }
    }
    if (b == 0 && t == 255) offs[N_NODES] = N_EDGES;
    __syncthreads();
    for (int e = t; e < n; e += 256) {
        unsigned p = sd[e];
        int src = (int)(p >> 16);
        int pos = atomicAdd(&lc[p & (NODES_PER_B - 1)][src >> 13], 1);
        csr[pos] = (unsigned short)src;
    }
}

// ---------------- W convert+transpose (both weights in one launch) ----------
__global__ void k_cvtw(const float* __restrict__ W1, const float* __restrict__ W2,
                       unsigned short* __restrict__ Wth1, unsigned short* __restrict__ Wtl1,
                       unsigned short* __restrict__ Wth2, unsigned short* __restrict__ Wtl2) {
    int gi = blockIdx.x * 256 + threadIdx.x;
    int which = gi >= 128 * 128;
    int i = which ? gi - 128 * 128 : gi;
    const float* W = which ? W2 : W1;
    unsigned short* Wth = which ? Wth2 : Wth1;
    unsigned short* Wtl = which ? Wtl2 : Wtl1;
    int k = i >> 7, j = i & 127;
    float w = W[i];
    unsigned short h = f2bf(w);
    float lo = w - bf2f(h);
    Wth[j * 128 + k] = h;
    Wtl[j * 128 + k] = f2bf(lo);
}

// ---------------- MFMA GEMM: Hbs[n] = bf16(dinv[n] * (X[n] @ W)) ----
__global__ __launch_bounds__(256) void k_gemm_mfma(const float* __restrict__ X,
                                                   const unsigned short* __restrict__ Wth,
                                                   const unsigned short* __restrict__ Wtl,
                                                   const float* __restrict__ dinv,
                                                   unsigned short* __restrict__ Hb,
                                                   int nrows) {
    __shared__ bf16x8 wh[2048];   // [n=128][k8=16] 16B slots, swizzled
    __shared__ bf16x8 wl[2048];
    int t = threadIdx.x;
    for (int i = t; i < 2048; i += 256) {
        int n = i >> 4;
        int slot = i ^ (n & 7);
        wh[slot] = ((const bf16x8*)Wth)[i];
        wl[slot] = ((const bf16x8*)Wtl)[i];
    }
    __syncthreads();
    int w = t >> 6, l = t & 63;
    int lrow = l & 15, lk = l >> 4;
    int arow = blockIdx.x * 64 + w * 16 + lrow;
    int rr = (arow < nrows) ? arow : nrows - 1;
    const float* xrow = X + (size_t)rr * 128;
    f32x4 acc[8];
#pragma unroll
    for (int nt = 0; nt < 8; nt++) acc[nt] = (f32x4){0.f, 0.f, 0.f, 0.f};
#pragma unroll
    for (int kk = 0; kk < 4; kk++) {
        int k = kk * 32 + lk * 8;
        float4 x0 = *(const float4*)(xrow + k);
        float4 x1 = *(const float4*)(xrow + k + 4);
        float xv[8] = {x0.x, x0.y, x0.z, x0.w, x1.x, x1.y, x1.z, x1.w};
        union { bf16x8 v; unsigned short s[8]; } ah, al;
#pragma unroll
        for (int i = 0; i < 8; i++) {
            unsigned u = __float_as_uint(xv[i]);
            unsigned short hi = (unsigned short)(u >> 16);   // trunc split
            ah.s[i] = hi;
            float lo = xv[i] - __uint_as_float((unsigned)hi << 16);
            al.s[i] = (unsigned short)(__float_as_uint(lo) >> 16);
        }
#pragma unroll
        for (int nt = 0; nt < 8; nt++) {
            int n = nt * 16 + lrow;
            int slot = (n * 16 + kk * 4 + lk) ^ (n & 7);
            bf16x8 bh = wh[slot];
            bf16x8 bl = wl[slot];
            acc[nt] = __builtin_amdgcn_mfma_f32_16x16x32_bf16(ah.v, bh, acc[nt], 0, 0, 0);
            acc[nt] = __builtin_amdgcn_mfma_f32_16x16x32_bf16(ah.v, bl, acc[nt], 0, 0, 0);
            acc[nt] = __builtin_amdgcn_mfma_f32_16x16x32_bf16(al.v, bh, acc[nt], 0, 0, 0);
        }
    }
    int obase = blockIdx.x * 64 + w * 16 + lk * 4;
#pragma unroll
    for (int r = 0; r < 4; r++) {
        int orow = obase + r;
        if (orow < nrows) {
            float di = dinv[orow];
            unsigned short* dst = Hb + (size_t)orow * 128 + lrow;
#pragma unroll
            for (int nt = 0; nt < 8; nt++) dst[nt * 16] = f2bf(di * acc[nt][r]);
        }
    }
}

// ---------------- GCN aggregate: quarter-wave, ILP-8, AND/SHL converts ------
// out[n] = relu(dinv[n]*(Hbs[n] + sum_e Hbs[s]) + b);  Hbs[v] = bf16(dinv[v]*H[v])
__device__ inline void rowadd(float* acc, u32x4 w) {
#pragma unroll
    for (int i = 0; i < 4; i++) {
        acc[2 * i]     += __uint_as_float(w[i] << 16);
        acc[2 * i + 1] += __uint_as_float(w[i] & 0xFFFF0000u);
    }
}

__global__ __launch_bounds__(256) void k_agg(const unsigned short* __restrict__ Hbs,
                                             const float* __restrict__ dinv,
                                             const int* __restrict__ offs,
                                             const unsigned short* __restrict__ csr,
                                             const float* __restrict__ b,
                                             float* __restrict__ out) {
    int wave = (blockIdx.x * blockDim.x + threadIdx.x) >> 6;
    int lane = threadIdx.x & 63;
    if (wave >= N_NODES) return;
    int n = wave;
    int qr = lane >> 4;   // quarter 0..3: edge subgroup
    int l = lane & 15;    // 16B col group (8 bf16)
    const u32x4* hp = (const u32x4*)Hbs;
    float acc[8];
#pragma unroll
    for (int i = 0; i < 8; i++) acc[i] = 0.f;
    if (qr == 0) rowadd(acc, hp[(size_t)n * 16 + l]);
    int e0 = offs[n], e1 = offs[n + 1];
    int j = e0 + qr;
    for (; j + 28 < e1; j += 32) {
        int s[8];
#pragma unroll
        for (int u = 0; u < 8; u++) s[u] = csr[j + 4 * u];
        u32x4 a[8];
#pragma unroll
        for (int u = 0; u < 8; u++) a[u] = hp[(size_t)s[u] * 16 + l];
#pragma unroll
        for (int u = 0; u < 8; u++) rowadd(acc, a[u]);
    }
    for (; j + 12 < e1; j += 16) {
        int s[4];
#pragma unroll
        for (int u = 0; u < 4; u++) s[u] = csr[j + 4 * u];
        u32x4 a[4];
#pragma unroll
        for (int u = 0; u < 4; u++) a[u] = hp[(size_t)s[u] * 16 + l];
#pragma unroll
        for (int u = 0; u < 4; u++) rowadd(acc, a[u]);
    }
    for (; j < e1; j += 4) {
        rowadd(acc, hp[(size_t)csr[j] * 16 + l]);
    }
#pragma unroll
    for (int i = 0; i < 8; i++) {
        acc[i] += __shfl_xor(acc[i], 16, 64);
        acc[i] += __shfl_xor(acc[i], 32, 64);
    }
    if (qr == 0) {
        float di = dinv[n];
        float4 b0 = *(const float4*)(b + l * 8);
        float4 b1 = *(const float4*)(b + l * 8 + 4);
        float4 o0, o1;
        o0.x = fmaxf(fmaf(di, acc[0], b0.x), 0.f);
        o0.y = fmaxf(fmaf(di, acc[1], b0.y), 0.f);
        o0.z = fmaxf(fmaf(di, acc[2], b0.z), 0.f);
        o0.w = fmaxf(fmaf(di, acc[3], b0.w), 0.f);
        o1.x = fmaxf(fmaf(di, acc[4], b1.x), 0.f);
        o1.y = fmaxf(fmaf(di, acc[5], b1.y), 0.f);
        o1.z = fmaxf(fmaf(di, acc[6], b1.z), 0.f);
        o1.w = fmaxf(fmaf(di, acc[7], b1.w), 0.f);
        float* dst = out + (size_t)n * 128 + l * 8;
        *(float4*)dst = o0;
        *(float4*)(dst + 4) = o1;
    }
}

// ---------------- LSTM gates GEMM-NT ----------------
__global__ __launch_bounds__(256) void k_gates(const float* __restrict__ qstar,
                                               const float* __restrict__ h,
                                               const float* __restrict__ Wih,
                                               const float* __restrict__ Whh,
                                               const float* __restrict__ bih,
                                               const float* __restrict__ bhh,
                                               float* __restrict__ gates) {
    __shared__ float As[64][33];
    __shared__ float Bs[64][33];
    int t = threadIdx.x;
    int tx = t & 15, ty = t >> 4;
    int gb = blockIdx.y * 64;
    int jb = blockIdx.x * 64;
    float acc[4][4];
#pragma unroll
    for (int i = 0; i < 4; i++)
#pragma unroll
        for (int j = 0; j < 4; j++) acc[i][j] = 0.f;
    for (int k0 = 0; k0 < 384; k0 += 32) {
        for (int i = t; i < 64 * 8; i += 256) {
            int r = i >> 3, c4 = i & 7;
            int k = k0 + c4 * 4;
            const float* srcA = (k < 256) ? (qstar + (size_t)(gb + r) * 256 + k)
                                          : (h + (size_t)(gb + r) * 128 + (k - 256));
            float4 va = *(const float4*)srcA;
            As[r][c4 * 4 + 0] = va.x; As[r][c4 * 4 + 1] = va.y;
            As[r][c4 * 4 + 2] = va.z; As[r][c4 * 4 + 3] = va.w;
            const float* srcB = (k < 256) ? (Wih + (size_t)(jb + r) * 256 + k)
                                          : (Whh + (size_t)(jb + r) * 128 + (k - 256));
            float4 vb = *(const float4*)srcB;
            Bs[r][c4 * 4 + 0] = vb.x; Bs[r][c4 * 4 + 1] = vb.y;
            Bs[r][c4 * 4 + 2] = vb.z; Bs[r][c4 * 4 + 3] = vb.w;
        }
        __syncthreads();
#pragma unroll 8
        for (int kk = 0; kk < 32; kk++) {
            float a[4], b[4];
#pragma unroll
            for (int i = 0; i < 4; i++) a[i] = As[ty * 4 + i][kk];
#pragma unroll
            for (int i = 0; i < 4; i++) b[i] = Bs[tx * 4 + i][kk];
#pragma unroll
            for (int i = 0; i < 4; i++)
#pragma unroll
                for (int j = 0; j < 4; j++) acc[i][j] = fmaf(a[i], b[j], acc[i][j]);
        }
        __syncthreads();
    }
#pragma unroll
    for (int j = 0; j < 4; j++) {
        int jj = jb + tx * 4 + j;
        float bias = bih[jj] + bhh[jj];
#pragma unroll
        for (int i = 0; i < 4; i++) {
            gates[(size_t)(gb + ty * 4 + i) * 512 + jj] = acc[i][j] + bias;
        }
    }
}

// ---------------- attention with fused LSTM elementwise ----------------
__global__ __launch_bounds__(256) void k_attn(const float* __restrict__ X,
                                              const int* __restrict__ goff,
                                              const float* __restrict__ gates,
                                              const float* __restrict__ bih,
                                              const float* __restrict__ bhh,
                                              float* __restrict__ h,
                                              float* __restrict__ c,
                                              float* __restrict__ eg,
                                              float* __restrict__ qstar,
                                              int first) {
    int b = blockIdx.x;
    int t = threadIdx.x;
    int wv = t >> 6, l = t & 63;
    int n0 = goff[b], n1 = goff[b + 1];
    int cnt = n1 - n0;
    __shared__ float rows[MAXR][128];
    __shared__ float q[128];
    __shared__ float ebuf[MAXR];
    __shared__ float red[256];
    __shared__ float wm[4];
    __shared__ float ws[4];
    if (t < 128) {
        float iv, fv, gv, ov;
        if (first) {
            iv = bih[t] + bhh[t];
            fv = bih[128 + t] + bhh[128 + t];
            gv = bih[256 + t] + bhh[256 + t];
            ov = bih[384 + t] + bhh[384 + t];
        } else {
            const float* g = gates + (size_t)b * 512;
            iv = g[t]; fv = g[128 + t]; gv = g[256 + t]; ov = g[384 + t];
        }
        float si = 1.f / (1.f + expf(-iv));
        float sf = 1.f / (1.f + expf(-fv));
        float so = 1.f / (1.f + expf(-ov));
        float tg = tanhf(gv);
        float cold = first ? 0.f : c[b * 128 + t];
        float cn = sf * cold + si * tg;
        float hn = so * tanhf(cn);
        c[b * 128 + t] = cn;
        h[b * 128 + t] = hn;
        q[t] = hn;
    }
    if (cnt <= MAXR) {
        for (int i = t; i < cnt * 32; i += 256) {
            int r = i >> 5, c4 = i & 31;
            ((float4*)rows[r])[c4] = ((const float4*)(X + (size_t)(n0 + r) * 128))[c4];
        }
        __syncthreads();
        const float2* qp = (const float2*)q;
        float2 q2 = qp[l];
        float mloc = -INFINITY;
        for (int n = wv; n < cnt; n += 4) {
            const float2* xp = (const float2*)rows[n];
            float2 x2 = xp[l];
            float p = x2.x * q2.x + x2.y * q2.y;
#pragma unroll
            for (int o = 32; o > 0; o >>= 1) p += __shfl_xor(p, o, 64);
            if (l == 0) ebuf[n] = p;
            mloc = fmaxf(mloc, p);
        }
        if (l == 0) wm[wv] = mloc;
        __syncthreads();
        float m = fmaxf(fmaxf(wm[0], wm[1]), fmaxf(wm[2], wm[3]));
        if (isinf(m)) m = 0.f;
        float s = 0.f;
        for (int n = t; n < cnt; n += 256) {
            float z = expf(ebuf[n] - m);
            ebuf[n] = z;
            s += z;
        }
#pragma unroll
        for (int o = 32; o > 0; o >>= 1) s += __shfl_xor(s, o, 64);
        if (l == 0) ws[wv] = s;
        __syncthreads();
        float denom = ws[0] + ws[1] + ws[2] + ws[3];
        float inv = (denom > 0.f) ? 1.f / denom : 0.f;
        int g = t >> 7, col = t & 127;
        float acc = 0.f;
        for (int n = g; n < cnt; n += 2) {
            acc = fmaf(ebuf[n] * inv, rows[n][col], acc);
        }
        red[t] = acc;
        __syncthreads();
        if (t < 128) {
            float r = red[t] + red[t + 128];
            qstar[b * 256 + t] = q[t];
            qstar[b * 256 + 128 + t] = r;
        }
    } else {
        __syncthreads();
        const float2* qp = (const float2*)q;
        float2 q2 = qp[l];
        float mloc = -INFINITY;
        for (int n = n0 + wv; n < n1; n += 4) {
            const float2* xp = (const float2*)(X + (size_t)n * 128);
            float2 x2 = xp[l];
            float p = x2.x * q2.x + x2.y * q2.y;
#pragma unroll
            for (int o = 32; o > 0; o >>= 1) p += __shfl_xor(p, o, 64);
            if (l == 0) eg[n] = p;
            mloc = fmaxf(mloc, p);
        }
        if (l == 0) wm[wv] = mloc;
        __syncthreads();
        float m = fmaxf(fmaxf(wm[0], wm[1]), fmaxf(wm[2], wm[3]));
        if (isinf(m)) m = 0.f;
        float s = 0.f;
        for (int n = n0 + t; n < n1; n += 256) {
            float z = expf(eg[n] - m);
            eg[n] = z;
            s += z;
        }
#pragma unroll
        for (int o = 32; o > 0; o >>= 1) s += __shfl_xor(s, o, 64);
        if (l == 0) ws[wv] = s;
        __syncthreads();
        float denom = ws[0] + ws[1] + ws[2] + ws[3];
        float inv = (denom > 0.f) ? 1.f / denom : 0.f;
        int g = t >> 7, col = t & 127;
        float acc = 0.f;
        for (int n = n0 + g; n < n1; n += 2) {
            acc = fmaf(eg[n] * inv, X[(size_t)n * 128 + col], acc);
        }
        red[t] = acc;
        __syncthreads();
        if (t < 128) {
            float r = red[t] + red[t + 128];
            qstar[b * 256 + t] = q[t];
            qstar[b * 256 + 128 + t] = r;
        }
    }
}

// ---------------- final MLP head ----------------
__global__ __launch_bounds__(128) void k_mlp(const float* __restrict__ qstar,
                                             const float* __restrict__ Wl1,
                                             const float* __restrict__ bl1,
                                             const float* __restrict__ Wl2,
                                             const float* __restrict__ bl2,
                                             float* __restrict__ out) {
    int b = blockIdx.x, t = threadIdx.x;
    __shared__ float qs[256];
    __shared__ float hid[128];
    qs[t] = qstar[b * 256 + t];
    qs[128 + t] = qstar[b * 256 + 128 + t];
    __syncthreads();
    float acc = bl1[t];
#pragma unroll 4
    for (int k = 0; k < 256; k++) acc = fmaf(qs[k], Wl1[k * 128 + t], acc);
    hid[t] = fmaxf(acc, 0.f);
    __syncthreads();
    if (t < NUM_CLASSES) {
        float o = bl2[t];
#pragma unroll 4
        for (int k = 0; k < 128; k++) o = fmaf(hid[k], Wl2[k * 10 + t], o);
        out[b * 10 + t] = o;
    }
}

// ---------------- host ----------------

extern "C" void kernel_launch(void* const* d_in, const int* in_sizes, int n_in,
                              void* d_out, int out_size, void* d_ws, size_t ws_size,
                              hipStream_t stream) {
    const float* x    = (const float*)d_in[0];
    const void*  eidx = d_in[1];
    const void*  batr = d_in[2];
    const float* W1   = (const float*)d_in[3];
    const float* b1   = (const float*)d_in[4];
    const float* W2   = (const float*)d_in[5];
    const float* b2   = (const float*)d_in[6];
    const float* Wih  = (const float*)d_in[7];
    const float* Whh  = (const float*)d_in[8];
    const float* bih  = (const float*)d_in[9];
    const float* bhh  = (const float*)d_in[10];
    const float* Wl1  = (const float*)d_in[11];
    const float* bl1  = (const float*)d_in[12];
    const float* Wl2  = (const float*)d_in[13];
    const float* bl2  = (const float*)d_in[14];
    float* out = (float*)d_out;

    char* ws = (char*)d_ws;
    size_t off = 0;
    auto alloc = [&](size_t bytes) {
        size_t r = off;
        off = (off + bytes + 255) & ~(size_t)255;
        return r;
    };
    float* A        = (float*)(ws + alloc((size_t)N_NODES * 128 * 4));
    unsigned short* csr = (unsigned short*)(ws + alloc((size_t)N_EDGES * 2));
    unsigned int* edgebuf = (unsigned int*)(ws + alloc((size_t)2 * N_EDGES * 4));  // pdata+sdata; later Hbs
    int*   histg    = (int*)(ws + alloc((size_t)NBLK * NBUK * 4));
    int*   btot     = (int*)(ws + alloc((size_t)NBUK * 4));
    int*   bbase    = (int*)(ws + alloc((size_t)(NBUK + 1) * 4));
    int*   offs     = (int*)(ws + alloc((size_t)(N_NODES + 1) * 4));
    float* dinv     = (float*)(ws + alloc((size_t)N_NODES * 4));
    float* e        = (float*)(ws + alloc((size_t)N_NODES * 4));
    int*   goff     = (int*)(ws + alloc((size_t)(NUM_GRAPHS + 1) * 4));
    float* state    = (float*)(ws + alloc((size_t)(NUM_GRAPHS * 128 * 2 + NUM_GRAPHS * 256) * 4));
    float* gates    = (float*)(ws + alloc((size_t)NUM_GRAPHS * 512 * 4));
    unsigned short* Wth1 = (unsigned short*)(ws + alloc((size_t)128 * 128 * 2));
    unsigned short* Wtl1 = (unsigned short*)(ws + alloc((size_t)128 * 128 * 2));
    unsigned short* Wth2 = (unsigned short*)(ws + alloc((size_t)128 * 128 * 2));
    unsigned short* Wtl2 = (unsigned short*)(ws + alloc((size_t)128 * 128 * 2));
    int*   flag     = (int*)(ws + alloc(4));
    if (off > ws_size) return;

    unsigned int* pdata = edgebuf;
    unsigned int* sdata = edgebuf + N_EDGES;
    unsigned short* Hbs = (unsigned short*)edgebuf;

    float* h_lstm = state;
    float* c_lstm = state + NUM_GRAPHS * 128;
    float* qstar  = state + NUM_GRAPHS * 256;

    const int B = 256;
    hipMemsetAsync(flag, 0, 4, stream);
    k_detect<<<(4096 + B - 1) / B, B, 0, stream>>>((const int*)eidx, flag, 4096);
    k_goff<<<(N_NODES + B - 1) / B, B, 0, stream>>>(batr, flag, goff, N_NODES, NUM_GRAPHS);
    // CSR build
    k_pack<<<NBLK, 256, 0, stream>>>(eidx, flag, pdata, histg);
    k_colscan<<<NBUK, 256, 0, stream>>>(histg, btot);
    k_scan<<<1, 1024, 0, stream>>>(btot, bbase, NBUK);
    k_place<<<NBLK, 256, 0, stream>>>(pdata, histg, bbase, sdata);
    k_build<<<NBUK, 256, 0, stream>>>(sdata, bbase, btot, dinv, offs, csr);
    // weight conversion (both in one launch)
    k_cvtw<<<128, 256, 0, stream>>>(W1, W2, Wth1, Wtl1, Wth2, Wtl2);
    // GCN conv 1
    k_gemm_mfma<<<(N_NODES + 63) / 64, 256, 0, stream>>>(x, Wth1, Wtl1, dinv, Hbs, N_NODES);
    k_agg<<<(N_NODES + 3) / 4, 256, 0, stream>>>(Hbs, dinv, offs, csr, b1, A);
    // GCN conv 2
    k_gemm_mfma<<<(N_NODES + 63) / 64, 256, 0, stream>>>(A, Wth2, Wtl2, dinv, Hbs, N_NODES);
    k_agg<<<(N_NODES + 3) / 4, 256, 0, stream>>>(Hbs, dinv, offs, csr, b2, A);
    // Set2Set (lstm elementwise fused into attn)
    for (int s = 0; s < STEPS; s++) {
        if (s > 0) {
            dim3 gg(8, 8);
            k_gates<<<gg, 256, 0, stream>>>(qstar, h_lstm, Wih, Whh, bih, bhh, gates);
        }
        k_attn<<<NUM_GRAPHS, 256, 0, stream>>>(A, goff, gates, bih, bhh,
                                               h_lstm, c_lstm, e, qstar, s == 0);
    }
    k_mlp<<<NUM_GRAPHS, 128, 0, stream>>>(qstar, Wl1, bl1, Wl2, bl2, out);
}

// Round 13
// 318.580 us; speedup vs baseline: 1.7716x; 1.0987x over previous
//
#include <hip/hip_runtime.h>
#include <hip/hip_bf16.h>
#include <math.h>

#define N_NODES 50000
#define N_EDGES 1600000
#define NUM_GRAPHS 512
#define HIDDEN 128
#define NUM_CLASSES 10
#define STEPS 3

#define NB_SHIFT 6                      // 64 nodes per bucket
#define NODES_PER_B (1 << NB_SHIFT)
#define NBUK ((N_NODES + NODES_PER_B - 1) / NODES_PER_B)   // 782
#define EPB 8192                        // edges per block in the sort
#define NBLK ((N_EDGES + EPB - 1) / EPB)                   // 196
#define MAXR 144                        // attn LDS row cap (max graph ~132)
#define NCH 7                           // src chunks of 8192 nodes

typedef __attribute__((ext_vector_type(8))) short bf16x8;
typedef __attribute__((ext_vector_type(4))) unsigned int u32x4;
typedef __attribute__((ext_vector_type(4))) float f32x4;

__device__ inline float bf2f(unsigned short h) {
    union { unsigned int u; float f; } v; v.u = ((unsigned int)h) << 16; return v.f;
}
__device__ inline unsigned short f2bf(float f) {
    union { float f; unsigned int u; } v; v.f = f;
    unsigned int r = (v.u + 0x7FFFu + ((v.u >> 16) & 1u)) >> 16;
    return (unsigned short)r;
}

// ---------------- utility kernels ----------------

__global__ void k_detect(const int* p, int* flag, int npairs) {
    int i = blockIdx.x * blockDim.x + threadIdx.x;
    if (i < npairs) {
        int v = p[2 * i + 1];
        if (v != 0) atomicOr(flag, 1);
    }
}

__global__ void k_goff(const void* batr, const int* flag, int* goff, int n, int ng) {
    int i = blockIdx.x * blockDim.x + threadIdx.x;
    if (i >= n) return;
    bool is32 = (*flag != 0);
    int b = is32 ? ((const int*)batr)[i] : (int)((const long long*)batr)[i];
    int prev = (i == 0) ? -1
             : (is32 ? ((const int*)batr)[i - 1] : (int)((const long long*)batr)[i - 1]);
    for (int g = prev + 1; g <= b; g++) goff[g] = i;
    if (i == n - 1) {
        for (int g = b + 1; g <= ng; g++) goff[g] = n;
    }
}

// Sort pass 1: pack edges + per-block LDS bucket histogram (512 threads).
__global__ __launch_bounds__(512) void k_pack(const void* eidx, const int* flag,
                                              unsigned int* __restrict__ pdata,
                                              int* __restrict__ histg) {
    __shared__ int lh[NBUK];
    int b = blockIdx.x, t = threadIdx.x;
    for (int i = t; i < NBUK; i += 512) lh[i] = 0;
    __syncthreads();
    int base = b * EPB;
    int end = base + EPB; if (end > N_EDGES) end = N_EDGES;
    bool is32 = (*flag != 0);
    for (int i = base + t; i < end; i += 512) {
        int src, dst;
        if (is32) {
            const int* p = (const int*)eidx;
            src = p[i]; dst = p[N_EDGES + i];
        } else {
            const long long* p = (const long long*)eidx;
            src = (int)p[i]; dst = (int)p[N_EDGES + i];
        }
        pdata[i] = ((unsigned)src << 16) | (unsigned)dst;
        atomicAdd(&lh[dst >> NB_SHIFT], 1);
    }
    __syncthreads();
    for (int i = t; i < NBUK; i += 512) histg[(size_t)b * NBUK + i] = lh[i];
}

// Sort pass 2: per-bucket exclusive scan across blocks.
__global__ __launch_bounds__(256) void k_colscan(int* __restrict__ histg,
                                                 int* __restrict__ btot) {
    __shared__ int wsum[4];
    int k = blockIdx.x, t = threadIdx.x;
    int wid = t >> 6, lane = t & 63;
    int v = (t < NBLK) ? histg[(size_t)t * NBUK + k] : 0;
    int x = v;
#pragma unroll
    for (int o = 1; o < 64; o <<= 1) {
        int y = __shfl_up(x, o, 64);
        if (lane >= o) x += y;
    }
    if (lane == 63) wsum[wid] = x;
    __syncthreads();
    int add = 0;
    for (int w = 0; w < wid; w++) add += wsum[w];
    if (t < NBLK) histg[(size_t)t * NBUK + k] = add + x - v;
    if (t == NBLK - 1) btot[k] = add + x;
}

__global__ __launch_bounds__(1024) void k_scan(const int* cnt, int* offs, int n) {
    __shared__ int wsum[16];
    __shared__ int carry_sh;
    int t = threadIdx.x, wid = t >> 6, lane = t & 63;
    if (t == 0) { carry_sh = 0; offs[0] = 0; }
    __syncthreads();
    for (int base = 0; base < n; base += 1024) {
        int i = base + t;
        int v = (i < n) ? cnt[i] : 0;
        int x = v;
#pragma unroll
        for (int o = 1; o < 64; o <<= 1) {
            int y = __shfl_up(x, o, 64);
            if (lane >= o) x += y;
        }
        if (lane == 63) wsum[wid] = x;
        __syncthreads();
        if (wid == 0 && lane < 16) {
            int w = wsum[lane];
#pragma unroll
            for (int o = 1; o < 16; o <<= 1) {
                int y = __shfl_up(w, o, 16);
                if (lane >= o) w += y;
            }
            wsum[lane] = w;
        }
        __syncthreads();
        int add = carry_sh + (wid > 0 ? wsum[wid - 1] : 0);
        if (i < n) offs[i + 1] = add + x;
        __syncthreads();
        if (t == 0) carry_sh += wsum[15];
        __syncthreads();
    }
}

// Sort pass 3: place packed edges into bucket-contiguous segments (512 threads).
__global__ __launch_bounds__(512) void k_place(const unsigned int* __restrict__ pdata,
                                               const int* __restrict__ histg,
                                               const int* __restrict__ bbase,
                                               unsigned int* __restrict__ sdata) {
    __shared__ int lh[NBUK];
    __shared__ int lpre[NBUK];
    int b = blockIdx.x, t = threadIdx.x;
    for (int i = t; i < NBUK; i += 512) {
        lh[i] = 0;
        lpre[i] = bbase[i] + histg[(size_t)b * NBUK + i];
    }
    __syncthreads();
    int base = b * EPB;
    int end = base + EPB; if (end > N_EDGES) end = N_EDGES;
    for (int i = base + t; i < end; i += 512) {
        unsigned p = pdata[i];
        int k = (p & 0xFFFFu) >> NB_SHIFT;
        int pos = atomicAdd(&lh[k], 1);
        sdata[lpre[k] + pos] = p;
    }
}

// Fused CSR build per bucket (csr stored as ushort: src < 65536).
__global__ __launch_bounds__(256) void k_build(const unsigned int* __restrict__ sdata,
                                               const int* __restrict__ bbase,
                                               const int* __restrict__ btot,
                                               float* __restrict__ dinv,
                                               int* __restrict__ offs,
                                               unsigned short* __restrict__ csr) {
    __shared__ int lc[NODES_PER_B][8];
    int b = blockIdx.x, t = threadIdx.x;
    for (int i = t; i < NODES_PER_B * 8; i += 256) ((int*)lc)[i] = 0;
    __syncthreads();
    int s0 = bbase[b], n = btot[b];
    const unsigned int* sd = sdata + s0;
    for (int e = t; e < n; e += 256) {
        unsigned p = sd[e];
        atomicAdd(&lc[p & (NODES_PER_B - 1)][(p >> 16) >> 13], 1);
    }
    __syncthreads();
    if (t < NODES_PER_B) {
        int cnts[NCH];
        int deg = 0;
#pragma unroll
        for (int c = 0; c < NCH; c++) { cnts[c] = lc[t][c]; deg += cnts[c]; }
        int x = deg;
#pragma unroll
        for (int o = 1; o < 64; o <<= 1) {
            int y = __shfl_up(x, o, 64);
            if (t >= o) x += y;
        }
        int nodestart = s0 + x - deg;
        int node = b * NODES_PER_B + t;
        if (node < N_NODES) {
            offs[node] = nodestart;
            dinv[node] = rsqrtf((float)(deg + 1));
        }
        int run = nodestart;
#pragma unroll
        for (int c = 0; c < NCH; c++) { lc[t][c] = run; run += cnts[c]; }
    }
    if (b == 0 && t == 255) offs[N_NODES] = N_EDGES;
    __syncthreads();
    for (int e = t; e < n; e += 256) {
        unsigned p = sd[e];
        int src = (int)(p >> 16);
        int pos = atomicAdd(&lc[p & (NODES_PER_B - 1)][src >> 13], 1);
        csr[pos] = (unsigned short)src;
    }
}

// ---------------- W convert+transpose (both weights in one launch) ----------
__global__ void k_cvtw(const float* __restrict__ W1, const float* __restrict__ W2,
                       unsigned short* __restrict__ Wth1, unsigned short* __restrict__ Wtl1,
                       unsigned short* __restrict__ Wth2, unsigned short* __restrict__ Wtl2) {
    int gi = blockIdx.x * 256 + threadIdx.x;
    int which = gi >= 128 * 128;
    int i = which ? gi - 128 * 128 : gi;
    const float* W = which ? W2 : W1;
    unsigned short* Wth = which ? Wth2 : Wth1;
    unsigned short* Wtl = which ? Wtl2 : Wtl1;
    int k = i >> 7, j = i & 127;
    float w = W[i];
    unsigned short h = f2bf(w);
    float lo = w - bf2f(h);
    Wth[j * 128 + k] = h;
    Wtl[j * 128 + k] = f2bf(lo);
}

// ---------------- MFMA GEMM: Hbs[n] = bf16(dinv[n] * (X[n] @ W)) ----
__global__ __launch_bounds__(256) void k_gemm_mfma(const float* __restrict__ X,
                                                   const unsigned short* __restrict__ Wth,
                                                   const unsigned short* __restrict__ Wtl,
                                                   const float* __restrict__ dinv,
                                                   unsigned short* __restrict__ Hb,
                                                   int nrows) {
    __shared__ bf16x8 wh[2048];   // [n=128][k8=16] 16B slots, swizzled
    __shared__ bf16x8 wl[2048];
    int t = threadIdx.x;
    for (int i = t; i < 2048; i += 256) {
        int n = i >> 4;
        int slot = i ^ (n & 7);
        wh[slot] = ((const bf16x8*)Wth)[i];
        wl[slot] = ((const bf16x8*)Wtl)[i];
    }
    __syncthreads();
    int w = t >> 6, l = t & 63;
    int lrow = l & 15, lk = l >> 4;
    int arow = blockIdx.x * 64 + w * 16 + lrow;
    int rr = (arow < nrows) ? arow : nrows - 1;
    const float* xrow = X + (size_t)rr * 128;
    f32x4 acc[8];
#pragma unroll
    for (int nt = 0; nt < 8; nt++) acc[nt] = (f32x4){0.f, 0.f, 0.f, 0.f};
#pragma unroll
    for (int kk = 0; kk < 4; kk++) {
        int k = kk * 32 + lk * 8;
        float4 x0 = *(const float4*)(xrow + k);
        float4 x1 = *(const float4*)(xrow + k + 4);
        float xv[8] = {x0.x, x0.y, x0.z, x0.w, x1.x, x1.y, x1.z, x1.w};
        union { bf16x8 v; unsigned short s[8]; } ah, al;
#pragma unroll
        for (int i = 0; i < 8; i++) {
            unsigned u = __float_as_uint(xv[i]);
            unsigned short hi = (unsigned short)(u >> 16);   // trunc split
            ah.s[i] = hi;
            float lo = xv[i] - __uint_as_float((unsigned)hi << 16);
            al.s[i] = (unsigned short)(__float_as_uint(lo) >> 16);
        }
#pragma unroll
        for (int nt = 0; nt < 8; nt++) {
            int n = nt * 16 + lrow;
            int slot = (n * 16 + kk * 4 + lk) ^ (n & 7);
            bf16x8 bh = wh[slot];
            bf16x8 bl = wl[slot];
            acc[nt] = __builtin_amdgcn_mfma_f32_16x16x32_bf16(ah.v, bh, acc[nt], 0, 0, 0);
            acc[nt] = __builtin_amdgcn_mfma_f32_16x16x32_bf16(ah.v, bl, acc[nt], 0, 0, 0);
            acc[nt] = __builtin_amdgcn_mfma_f32_16x16x32_bf16(al.v, bh, acc[nt], 0, 0, 0);
        }
    }
    int obase = blockIdx.x * 64 + w * 16 + lk * 4;
#pragma unroll
    for (int r = 0; r < 4; r++) {
        int orow = obase + r;
        if (orow < nrows) {
            float di = dinv[orow];
            unsigned short* dst = Hb + (size_t)orow * 128 + lrow;
#pragma unroll
            for (int nt = 0; nt < 8; nt++) dst[nt * 16] = f2bf(di * acc[nt][r]);
        }
    }
}

// ---------------- GCN aggregate: quarter-wave, ILP-8, AND/SHL converts ------
__device__ inline void rowadd(float* acc, u32x4 w) {
#pragma unroll
    for (int i = 0; i < 4; i++) {
        acc[2 * i]     += __uint_as_float(w[i] << 16);
        acc[2 * i + 1] += __uint_as_float(w[i] & 0xFFFF0000u);
    }
}

__global__ __launch_bounds__(256) void k_agg(const unsigned short* __restrict__ Hbs,
                                             const float* __restrict__ dinv,
                                             const int* __restrict__ offs,
                                             const unsigned short* __restrict__ csr,
                                             const float* __restrict__ b,
                                             float* __restrict__ out) {
    int wave = (blockIdx.x * blockDim.x + threadIdx.x) >> 6;
    int lane = threadIdx.x & 63;
    if (wave >= N_NODES) return;
    int n = wave;
    int qr = lane >> 4;   // quarter 0..3: edge subgroup
    int l = lane & 15;    // 16B col group (8 bf16)
    const u32x4* hp = (const u32x4*)Hbs;
    float acc[8];
#pragma unroll
    for (int i = 0; i < 8; i++) acc[i] = 0.f;
    if (qr == 0) rowadd(acc, hp[(size_t)n * 16 + l]);
    int e0 = offs[n], e1 = offs[n + 1];
    int j = e0 + qr;
    for (; j + 28 < e1; j += 32) {
        int s[8];
#pragma unroll
        for (int u = 0; u < 8; u++) s[u] = csr[j + 4 * u];
        u32x4 a[8];
#pragma unroll
        for (int u = 0; u < 8; u++) a[u] = hp[(size_t)s[u] * 16 + l];
#pragma unroll
        for (int u = 0; u < 8; u++) rowadd(acc, a[u]);
    }
    for (; j + 12 < e1; j += 16) {
        int s[4];
#pragma unroll
        for (int u = 0; u < 4; u++) s[u] = csr[j + 4 * u];
        u32x4 a[4];
#pragma unroll
        for (int u = 0; u < 4; u++) a[u] = hp[(size_t)s[u] * 16 + l];
#pragma unroll
        for (int u = 0; u < 4; u++) rowadd(acc, a[u]);
    }
    for (; j < e1; j += 4) {
        rowadd(acc, hp[(size_t)csr[j] * 16 + l]);
    }
#pragma unroll
    for (int i = 0; i < 8; i++) {
        acc[i] += __shfl_xor(acc[i], 16, 64);
        acc[i] += __shfl_xor(acc[i], 32, 64);
    }
    if (qr == 0) {
        float di = dinv[n];
        float4 b0 = *(const float4*)(b + l * 8);
        float4 b1 = *(const float4*)(b + l * 8 + 4);
        float4 o0, o1;
        o0.x = fmaxf(fmaf(di, acc[0], b0.x), 0.f);
        o0.y = fmaxf(fmaf(di, acc[1], b0.y), 0.f);
        o0.z = fmaxf(fmaf(di, acc[2], b0.z), 0.f);
        o0.w = fmaxf(fmaf(di, acc[3], b0.w), 0.f);
        o1.x = fmaxf(fmaf(di, acc[4], b1.x), 0.f);
        o1.y = fmaxf(fmaf(di, acc[5], b1.y), 0.f);
        o1.z = fmaxf(fmaf(di, acc[6], b1.z), 0.f);
        o1.w = fmaxf(fmaf(di, acc[7], b1.w), 0.f);
        float* dst = out + (size_t)n * 128 + l * 8;
        *(float4*)dst = o0;
        *(float4*)(dst + 4) = o1;
    }
}

// ---------------- LSTM gates GEMM-NT (32-graph x 64-gate tiles, 128 blocks) --
__global__ __launch_bounds__(256) void k_gates(const float* __restrict__ qstar,
                                               const float* __restrict__ h,
                                               const float* __restrict__ Wih,
                                               const float* __restrict__ Whh,
                                               const float* __restrict__ bih,
                                               const float* __restrict__ bhh,
                                               float* __restrict__ gates) {
    __shared__ float As[32][33];
    __shared__ float Bs[64][33];
    int t = threadIdx.x;
    int tx = t & 15, ty = t >> 4;   // tx: gate group (4), ty: row 0..15 (+16)
    int gb = blockIdx.y * 32;
    int jb = blockIdx.x * 64;
    float acc[2][4];
#pragma unroll
    for (int i = 0; i < 2; i++)
#pragma unroll
        for (int j = 0; j < 4; j++) acc[i][j] = 0.f;
    for (int k0 = 0; k0 < 384; k0 += 32) {
        {   // stage A: 32 rows x 32 k = 256 float4, one per thread
            int r = t >> 3, c4 = t & 7;
            int k = k0 + c4 * 4;
            const float* srcA = (k < 256) ? (qstar + (size_t)(gb + r) * 256 + k)
                                          : (h + (size_t)(gb + r) * 128 + (k - 256));
            float4 va = *(const float4*)srcA;
            As[r][c4 * 4 + 0] = va.x; As[r][c4 * 4 + 1] = va.y;
            As[r][c4 * 4 + 2] = va.z; As[r][c4 * 4 + 3] = va.w;
        }
        for (int i = t; i < 512; i += 256) {   // stage B: 64 rows x 32 k
            int r = i >> 3, c4 = i & 7;
            int k = k0 + c4 * 4;
            const float* srcB = (k < 256) ? (Wih + (size_t)(jb + r) * 256 + k)
                                          : (Whh + (size_t)(jb + r) * 128 + (k - 256));
            float4 vb = *(const float4*)srcB;
            Bs[r][c4 * 4 + 0] = vb.x; Bs[r][c4 * 4 + 1] = vb.y;
            Bs[r][c4 * 4 + 2] = vb.z; Bs[r][c4 * 4 + 3] = vb.w;
        }
        __syncthreads();
#pragma unroll 8
        for (int kk = 0; kk < 32; kk++) {
            float a0 = As[ty][kk], a1 = As[ty + 16][kk];
            float bv[4];
#pragma unroll
            for (int j = 0; j < 4; j++) bv[j] = Bs[tx * 4 + j][kk];
#pragma unroll
            for (int j = 0; j < 4; j++) {
                acc[0][j] = fmaf(a0, bv[j], acc[0][j]);
                acc[1][j] = fmaf(a1, bv[j], acc[1][j]);
            }
        }
        __syncthreads();
    }
#pragma unroll
    for (int j = 0; j < 4; j++) {
        int jj = jb + tx * 4 + j;
        float bias = bih[jj] + bhh[jj];
        gates[(size_t)(gb + ty) * 512 + jj] = acc[0][j] + bias;
        gates[(size_t)(gb + ty + 16) * 512 + jj] = acc[1][j] + bias;
    }
}

// ---------------- attention with fused LSTM elementwise (+MLP on last step) --
__global__ __launch_bounds__(256) void k_attn(const float* __restrict__ X,
                                              const int* __restrict__ goff,
                                              const float* __restrict__ gates,
                                              const float* __restrict__ bih,
                                              const float* __restrict__ bhh,
                                              float* __restrict__ h,
                                              float* __restrict__ c,
                                              float* __restrict__ eg,
                                              float* __restrict__ qstar,
                                              const float* __restrict__ Wl1,
                                              const float* __restrict__ bl1,
                                              const float* __restrict__ Wl2,
                                              const float* __restrict__ bl2,
                                              float* __restrict__ out,
                                              int first, int last) {
    int b = blockIdx.x;
    int t = threadIdx.x;
    int wv = t >> 6, l = t & 63;
    int n0 = goff[b], n1 = goff[b + 1];
    int cnt = n1 - n0;
    __shared__ float rows[MAXR][128];
    __shared__ float q[128];
    __shared__ float ebuf[MAXR];
    __shared__ float red[256];
    __shared__ float wm[4];
    __shared__ float ws[4];
    __shared__ float qs2[256];
    __shared__ float hid[128];
    if (t < 128) {
        float iv, fv, gv, ov;
        if (first) {
            iv = bih[t] + bhh[t];
            fv = bih[128 + t] + bhh[128 + t];
            gv = bih[256 + t] + bhh[256 + t];
            ov = bih[384 + t] + bhh[384 + t];
        } else {
            const float* g = gates + (size_t)b * 512;
            iv = g[t]; fv = g[128 + t]; gv = g[256 + t]; ov = g[384 + t];
        }
        float si = 1.f / (1.f + expf(-iv));
        float sf = 1.f / (1.f + expf(-fv));
        float so = 1.f / (1.f + expf(-ov));
        float tg = tanhf(gv);
        float cold = first ? 0.f : c[b * 128 + t];
        float cn = sf * cold + si * tg;
        float hn = so * tanhf(cn);
        c[b * 128 + t] = cn;
        h[b * 128 + t] = hn;
        q[t] = hn;
    }
    if (cnt <= MAXR) {
        for (int i = t; i < cnt * 32; i += 256) {
            int r = i >> 5, c4 = i & 31;
            ((float4*)rows[r])[c4] = ((const float4*)(X + (size_t)(n0 + r) * 128))[c4];
        }
        __syncthreads();
        const float2* qp = (const float2*)q;
        float2 q2 = qp[l];
        float mloc = -INFINITY;
        for (int n = wv; n < cnt; n += 4) {
            const float2* xp = (const float2*)rows[n];
            float2 x2 = xp[l];
            float p = x2.x * q2.x + x2.y * q2.y;
#pragma unroll
            for (int o = 32; o > 0; o >>= 1) p += __shfl_xor(p, o, 64);
            if (l == 0) ebuf[n] = p;
            mloc = fmaxf(mloc, p);
        }
        if (l == 0) wm[wv] = mloc;
        __syncthreads();
        float m = fmaxf(fmaxf(wm[0], wm[1]), fmaxf(wm[2], wm[3]));
        if (isinf(m)) m = 0.f;
        float s = 0.f;
        for (int n = t; n < cnt; n += 256) {
            float z = expf(ebuf[n] - m);
            ebuf[n] = z;
            s += z;
        }
#pragma unroll
        for (int o = 32; o > 0; o >>= 1) s += __shfl_xor(s, o, 64);
        if (l == 0) ws[wv] = s;
        __syncthreads();
        float denom = ws[0] + ws[1] + ws[2] + ws[3];
        float inv = (denom > 0.f) ? 1.f / denom : 0.f;
        int g = t >> 7, col = t & 127;
        float acc = 0.f;
        for (int n = g; n < cnt; n += 2) {
            acc = fmaf(ebuf[n] * inv, rows[n][col], acc);
        }
        red[t] = acc;
        __syncthreads();
    } else {
        __syncthreads();
        const float2* qp = (const float2*)q;
        float2 q2 = qp[l];
        float mloc = -INFINITY;
        for (int n = n0 + wv; n < n1; n += 4) {
            const float2* xp = (const float2*)(X + (size_t)n * 128);
            float2 x2 = xp[l];
            float p = x2.x * q2.x + x2.y * q2.y;
#pragma unroll
            for (int o = 32; o > 0; o >>= 1) p += __shfl_xor(p, o, 64);
            if (l == 0) eg[n] = p;
            mloc = fmaxf(mloc, p);
        }
        if (l == 0) wm[wv] = mloc;
        __syncthreads();
        float m = fmaxf(fmaxf(wm[0], wm[1]), fmaxf(wm[2], wm[3]));
        if (isinf(m)) m = 0.f;
        float s = 0.f;
        for (int n = n0 + t; n < n1; n += 256) {
            float z = expf(eg[n] - m);
            eg[n] = z;
            s += z;
        }
#pragma unroll
        for (int o = 32; o > 0; o >>= 1) s += __shfl_xor(s, o, 64);
        if (l == 0) ws[wv] = s;
        __syncthreads();
        float denom = ws[0] + ws[1] + ws[2] + ws[3];
        float inv = (denom > 0.f) ? 1.f / denom : 0.f;
        int g = t >> 7, col = t & 127;
        float acc = 0.f;
        for (int n = n0 + g; n < n1; n += 2) {
            acc = fmaf(eg[n] * inv, X[(size_t)n * 128 + col], acc);
        }
        red[t] = acc;
        __syncthreads();
    }
    if (!last) {
        if (t < 128) {
            float r = red[t] + red[t + 128];
            qstar[b * 256 + t] = q[t];
            qstar[b * 256 + 128 + t] = r;
        }
    } else {
        // fused MLP head: out[b] = relu([q,r] @ Wl1 + bl1) @ Wl2 + bl2
        if (t < 128) {
            qs2[t] = q[t];
            qs2[128 + t] = red[t] + red[t + 128];
        }
        __syncthreads();
        if (t < 128) {
            float acc2 = bl1[t];
#pragma unroll 4
            for (int k = 0; k < 256; k++) acc2 = fmaf(qs2[k], Wl1[k * 128 + t], acc2);
            hid[t] = fmaxf(acc2, 0.f);
        }
        __syncthreads();
        if (t < NUM_CLASSES) {
            float o = bl2[t];
#pragma unroll 4
            for (int k = 0; k < 128; k++) o = fmaf(hid[k], Wl2[k * 10 + t], o);
            out[b * 10 + t] = o;
        }
    }
}

// ---------------- host ----------------

extern "C" void kernel_launch(void* const* d_in, const int* in_sizes, int n_in,
                              void* d_out, int out_size, void* d_ws, size_t ws_size,
                              hipStream_t stream) {
    const float* x    = (const float*)d_in[0];
    const void*  eidx = d_in[1];
    const void*  batr = d_in[2];
    const float* W1   = (const float*)d_in[3];
    const float* b1   = (const float*)d_in[4];
    const float* W2   = (const float*)d_in[5];
    const float* b2   = (const float*)d_in[6];
    const float* Wih  = (const float*)d_in[7];
    const float* Whh  = (const float*)d_in[8];
    const float* bih  = (const float*)d_in[9];
    const float* bhh  = (const float*)d_in[10];
    const float* Wl1  = (const float*)d_in[11];
    const float* bl1  = (const float*)d_in[12];
    const float* Wl2  = (const float*)d_in[13];
    const float* bl2  = (const float*)d_in[14];
    float* out = (float*)d_out;

    char* ws = (char*)d_ws;
    size_t off = 0;
    auto alloc = [&](size_t bytes) {
        size_t r = off;
        off = (off + bytes + 255) & ~(size_t)255;
        return r;
    };
    float* A        = (float*)(ws + alloc((size_t)N_NODES * 128 * 4));
    unsigned short* csr = (unsigned short*)(ws + alloc((size_t)N_EDGES * 2));
    unsigned int* edgebuf = (unsigned int*)(ws + alloc((size_t)2 * N_EDGES * 4));  // pdata+sdata; later Hbs
    int*   histg    = (int*)(ws + alloc((size_t)NBLK * NBUK * 4));
    int*   btot     = (int*)(ws + alloc((size_t)NBUK * 4));
    int*   bbase    = (int*)(ws + alloc((size_t)(NBUK + 1) * 4));
    int*   offs     = (int*)(ws + alloc((size_t)(N_NODES + 1) * 4));
    float* dinv     = (float*)(ws + alloc((size_t)N_NODES * 4));
    float* e        = (float*)(ws + alloc((size_t)N_NODES * 4));
    int*   goff     = (int*)(ws + alloc((size_t)(NUM_GRAPHS + 1) * 4));
    float* state    = (float*)(ws + alloc((size_t)(NUM_GRAPHS * 128 * 2 + NUM_GRAPHS * 256) * 4));
    float* gates    = (float*)(ws + alloc((size_t)NUM_GRAPHS * 512 * 4));
    unsigned short* Wth1 = (unsigned short*)(ws + alloc((size_t)128 * 128 * 2));
    unsigned short* Wtl1 = (unsigned short*)(ws + alloc((size_t)128 * 128 * 2));
    unsigned short* Wth2 = (unsigned short*)(ws + alloc((size_t)128 * 128 * 2));
    unsigned short* Wtl2 = (unsigned short*)(ws + alloc((size_t)128 * 128 * 2));
    int*   flag     = (int*)(ws + alloc(4));
    if (off > ws_size) return;

    unsigned int* pdata = edgebuf;
    unsigned int* sdata = edgebuf + N_EDGES;
    unsigned short* Hbs = (unsigned short*)edgebuf;

    float* h_lstm = state;
    float* c_lstm = state + NUM_GRAPHS * 128;
    float* qstar  = state + NUM_GRAPHS * 256;

    const int B = 256;
    hipMemsetAsync(flag, 0, 4, stream);
    k_detect<<<(4096 + B - 1) / B, B, 0, stream>>>((const int*)eidx, flag, 4096);
    k_goff<<<(N_NODES + B - 1) / B, B, 0, stream>>>(batr, flag, goff, N_NODES, NUM_GRAPHS);
    // CSR build
    k_pack<<<NBLK, 512, 0, stream>>>(eidx, flag, pdata, histg);
    k_colscan<<<NBUK, 256, 0, stream>>>(histg, btot);
    k_scan<<<1, 1024, 0, stream>>>(btot, bbase, NBUK);
    k_place<<<NBLK, 512, 0, stream>>>(pdata, histg, bbase, sdata);
    k_build<<<NBUK, 256, 0, stream>>>(sdata, bbase, btot, dinv, offs, csr);
    // weight conversion (both in one launch)
    k_cvtw<<<128, 256, 0, stream>>>(W1, W2, Wth1, Wtl1, Wth2, Wtl2);
    // GCN conv 1
    k_gemm_mfma<<<(N_NODES + 63) / 64, 256, 0, stream>>>(x, Wth1, Wtl1, dinv, Hbs, N_NODES);
    k_agg<<<(N_NODES + 3) / 4, 256, 0, stream>>>(Hbs, dinv, offs, csr, b1, A);
    // GCN conv 2
    k_gemm_mfma<<<(N_NODES + 63) / 64, 256, 0, stream>>>(A, Wth2, Wtl2, dinv, Hbs, N_NODES);
    k_agg<<<(N_NODES + 3) / 4, 256, 0, stream>>>(Hbs, dinv, offs, csr, b2, A);
    // Set2Set (lstm elementwise fused into attn; MLP fused into last attn)
    for (int s = 0; s < STEPS; s++) {
        if (s > 0) {
            dim3 gg(8, 16);
            k_gates<<<gg, 256, 0, stream>>>(qstar, h_lstm, Wih, Whh, bih, bhh, gates);
        }
        k_attn<<<NUM_GRAPHS, 256, 0, stream>>>(A, goff, gates, bih, bhh,
                                               h_lstm, c_lstm, e, qstar,
                                               Wl1, bl1, Wl2, bl2, out,
                                               s == 0, s == STEPS - 1);
    }
}